// Round 1
// 460.574 us; speedup vs baseline: 1.1315x; 1.1315x over previous
//
#include <hip/hip_runtime.h>

// ---------------------------------------------------------------- constants
#define EPSV 1e-5f
constexpr int Bsz = 4, T0 = 512, Dm = 512, TT = 513, NHh = 8, KK = 4;
constexpr int IN = 1024, DHd = 128, NCc = 1000;
constexpr int ROWS = Bsz * TT; // 2052
constexpr int NCH = 9;         // chunks of 64: 8*64 + 1 = 513

// bf16 k-major weight buffer offsets (u16 elements), per transformer block
constexpr size_t WT_UP = 0;                      // [2048][512]
constexpr size_t WT_Q  = WT_UP + 2048 * 512;     // [1024][1024]
constexpr size_t WT_K  = WT_Q + 1024 * 1024;
constexpr size_t WT_V  = WT_K + 1024 * 1024;
constexpr size_t WT_DN = WT_V + 1024 * 1024;     // [512][1024]
constexpr size_t WT_STRIDE = WT_DN + 512 * 1024; // 4,718,592 u16

typedef __attribute__((ext_vector_type(8))) short bf16x8;
typedef __attribute__((ext_vector_type(4))) float f32x4;
typedef __attribute__((ext_vector_type(4))) unsigned short ushort4v;
typedef __attribute__((ext_vector_type(8))) unsigned short ushort8v;
typedef unsigned short u16;

__device__ __forceinline__ float siluf(float x) { return x / (1.f + __expf(-x)); }
__device__ __forceinline__ u16 f2bf(float f) {
    unsigned int u = __float_as_uint(f);
    u = (u + 0x7FFFu + ((u >> 16) & 1u)) >> 16;
    return (u16)u;
}
__device__ __forceinline__ float bfu(u16 u) {
    return __uint_as_float(((unsigned int)u) << 16);
}

// ---------------------------------------------------------------- concat x + cls
__global__ __launch_bounds__(256) void concat_kernel(const float* __restrict__ x,
                                                     const float* __restrict__ cls,
                                                     float* __restrict__ h) {
    int idx = blockIdx.x * 256 + threadIdx.x;
    if (idx >= Bsz * TT * Dm) return;
    int d = idx & (Dm - 1);
    int bt = idx >> 9;
    int t = bt % TT, b = bt / TT;
    h[idx] = (t < T0) ? x[((size_t)(b * T0 + t)) * Dm + d] : cls[d];
}

// ---------------------------------------------------------------- LayerNorm rows of D=512 -> bf16
__global__ __launch_bounds__(256) void ln_kernel(const float* __restrict__ in,
                                                 const float* __restrict__ s,
                                                 const float* __restrict__ bb,
                                                 u16* __restrict__ out16) {
    int row = blockIdx.x, tid = threadIdx.x;
    const float* r = in + (size_t)row * Dm;
    __shared__ float s1[4], s2[4];
    float x0 = r[tid], x1 = r[tid + 256];
    float sum = x0 + x1, sq = x0 * x0 + x1 * x1;
#pragma unroll
    for (int o = 32; o > 0; o >>= 1) { sum += __shfl_xor(sum, o); sq += __shfl_xor(sq, o); }
    if ((tid & 63) == 0) { s1[tid >> 6] = sum; s2[tid >> 6] = sq; }
    __syncthreads();
    sum = s1[0] + s1[1] + s1[2] + s1[3];
    sq  = s2[0] + s2[1] + s2[2] + s2[3];
    float mu = sum / Dm, var = sq / Dm - mu * mu, inv = rsqrtf(var + EPSV);
    out16[(size_t)row * Dm + tid]       = f2bf((x0 - mu) * inv * s[tid] + bb[tid]);
    out16[(size_t)row * Dm + tid + 256] = f2bf((x1 - mu) * inv * s[tid + 256] + bb[tid + 256]);
}

// ---------------------------------------------------------------- weight transpose f32 KxN -> bf16 [N][K]
__global__ __launch_bounds__(256) void w_transpose_kernel(const float* __restrict__ wup,
        const float* __restrict__ wq, const float* __restrict__ wk,
        const float* __restrict__ wv, const float* __restrict__ wdn,
        u16* __restrict__ wt) {
    int y = blockIdx.y;             // 0..9
    int blk = y / 5, sel = y - blk * 5;
    int Kd, N; const float* src; size_t doff;
    if (sel == 0)      { Kd = 512;  N = 2048; src = wup + (size_t)blk * 512 * 2048; doff = WT_UP; }
    else if (sel == 1) { Kd = 1024; N = 1024; src = wq  + (size_t)blk * 1024 * 1024; doff = WT_Q; }
    else if (sel == 2) { Kd = 1024; N = 1024; src = wk  + (size_t)blk * 1024 * 1024; doff = WT_K; }
    else if (sel == 3) { Kd = 1024; N = 1024; src = wv  + (size_t)blk * 1024 * 1024; doff = WT_V; }
    else               { Kd = 1024; N = 512;  src = wdn + (size_t)blk * 1024 * 512;  doff = WT_DN; }
    u16* dst = wt + (size_t)blk * WT_STRIDE + doff;
    int ntx = N >> 5;
    int ntiles = ntx * (Kd >> 5);
    int ti = blockIdx.x;
    if (ti >= ntiles) return;
    int tk = ti / ntx, tn = ti - tk * ntx;
    __shared__ u16 s[32][33];
    int tx = threadIdx.x & 31, ty = threadIdx.x >> 5;
#pragma unroll
    for (int i = 0; i < 4; i++) {
        int k = tk * 32 + ty + i * 8;
        s[ty + i * 8][tx] = f2bf(src[(size_t)k * N + tn * 32 + tx]);
    }
    __syncthreads();
#pragma unroll
    for (int i = 0; i < 4; i++) {
        int n = tn * 32 + ty + i * 8;
        dst[(size_t)n * Kd + tk * 32 + tx] = s[tx][ty + i * 8];
    }
}

// ---------------------------------------------------------------- MFMA bf16 GEMM, double-buffered
// A: bf16 MxK (lda, u16). Wt: bf16 [N][Kd] k-contiguous. Templated (BM,BN), BK=32.
template<int BM, int BN>
__device__ __forceinline__ void gemm_tile_body(const u16* __restrict__ A, int lda,
                                               const u16* __restrict__ Wt, int Kd,
                                               const float* __restrict__ bias,
                                               const float* __restrict__ resid, int ldr,
                                               float* __restrict__ Cout, int ldc,
                                               int M, float scale, int m0, int n0,
                                               u16 (*As)[BM][40], u16 (*Bs)[BN][40]) {
    constexpr int MT = BM / 32;
    constexpr int NT = BN / 32;
    constexpr int ANV = BM / 64;           // ushort8 A-loads per thread
    constexpr int BNV = BN / 64;           // ushort8 B-loads per thread
    int tid = threadIdx.x;
    int wave = tid >> 6, lane = tid & 63;
    int wm = (wave >> 1) * (BM / 2), wn = (wave & 1) * (BN / 2);
    int lrow = lane & 15, lquad = lane >> 4;

    f32x4 acc[MT][NT];
#pragma unroll
    for (int i = 0; i < MT; i++)
#pragma unroll
        for (int j = 0; j < NT; j++)
#pragma unroll
            for (int r = 0; r < 4; r++) acc[i][j][r] = 0.f;

    int am, ak, bn, bk;
    if (BM == 128) { am = tid >> 1; ak = (tid & 1) * 16; }
    else           { am = tid >> 2; ak = (tid & 3) * 8; }
    if (BN == 128) { bn = tid & 127; bk = (tid >> 7) * 16; }
    else           { bn = tid & 63;  bk = (tid >> 6) * 8; }
    int gm = m0 + am;
    const u16* arow = A + (size_t)(gm < M ? gm : 0) * lda + ak;
    bool avalid = gm < M;
    const u16* wrow = Wt + (size_t)(n0 + bn) * Kd + bk;

    ushort8v areg[ANV];
    ushort8v breg[BNV];

    auto load_tile = [&](int k0) {
        if (avalid) {
#pragma unroll
            for (int i = 0; i < ANV; i++) areg[i] = *(const ushort8v*)(arow + k0 + i * 8);
        } else {
#pragma unroll
            for (int i = 0; i < ANV; i++) areg[i] = (ushort8v){0,0,0,0,0,0,0,0};
        }
#pragma unroll
        for (int i = 0; i < BNV; i++) breg[i] = *(const ushort8v*)(wrow + k0 + i * 8);
    };
    auto store_tile = [&](int buf) {
#pragma unroll
        for (int i = 0; i < ANV; i++)
            *(ushort8v*)&As[buf][am][ak + i * 8] = areg[i];
#pragma unroll
        for (int i = 0; i < BNV; i++)
            *(ushort8v*)&Bs[buf][bn][bk + i * 8] = breg[i];
    };

    load_tile(0);
    store_tile(0);
    __syncthreads();

    int nk = Kd >> 5;
#pragma unroll 1
    for (int it = 0; it < nk; it++) {
        int cur = it & 1;
        bool more = (it + 1 < nk);
        if (more) load_tile((it + 1) << 5);
        bf16x8 afr[MT], bfr[NT];
#pragma unroll
        for (int mt = 0; mt < MT; mt++)
            afr[mt] = *(const bf16x8*)&As[cur][wm + mt * 16 + lrow][lquad * 8];
#pragma unroll
        for (int nt = 0; nt < NT; nt++)
            bfr[nt] = *(const bf16x8*)&Bs[cur][wn + nt * 16 + lrow][lquad * 8];
#pragma unroll
        for (int mt = 0; mt < MT; mt++)
#pragma unroll
            for (int nt = 0; nt < NT; nt++)
                acc[mt][nt] = __builtin_amdgcn_mfma_f32_16x16x32_bf16(
                    afr[mt], bfr[nt], acc[mt][nt], 0, 0, 0);
        if (more) store_tile(cur ^ 1);
        __syncthreads();
    }

#pragma unroll
    for (int mt = 0; mt < MT; mt++) {
#pragma unroll
        for (int r = 0; r < 4; r++) {
            int gmr = m0 + wm + mt * 16 + lquad * 4 + r;
            if (gmr >= M) continue;
#pragma unroll
            for (int nt = 0; nt < NT; nt++) {
                int gn = n0 + wn + nt * 16 + lrow;
                float v = acc[mt][nt][r] * scale;
                if (bias) v += bias[gn];
                if (resid) v += resid[(size_t)gmr * ldr + gn];
                Cout[(size_t)gmr * ldc + gn] = v;
            }
        }
    }
}

template<int BM, int BN>
__global__ __launch_bounds__(256, 2) void gemm_mfma_kernel(const u16* __restrict__ A, int lda,
                                                           const u16* __restrict__ Wt, int Kd,
                                                           const float* __restrict__ bias,
                                                           const float* __restrict__ resid, int ldr,
                                                           float* __restrict__ Cout, int ldc,
                                                           int M, float scale) {
    __shared__ __align__(16) u16 As[2][BM][40];
    __shared__ __align__(16) u16 Bs[2][BN][40];
    gemm_tile_body<BM, BN>(A, lda, Wt, Kd, bias, resid, ldr, Cout, ldc, M, scale,
                           blockIdx.y * BM, blockIdx.x * BN, As, Bs);
}

// q/k/v in ONE dispatch, BN=64: blockIdx.x in [0,48): sel = x>>4, nx = x&15.
__global__ __launch_bounds__(256, 2) void qkv_mfma_kernel(const u16* __restrict__ xc16,
                                                          const u16* __restrict__ xu16,
                                                          const u16* __restrict__ wtblk,
                                                          float* __restrict__ fq,
                                                          float* __restrict__ fk,
                                                          float* __restrict__ fv,
                                                          float kscale) {
    __shared__ __align__(16) u16 As[2][128][40];
    __shared__ __align__(16) u16 Bs[2][64][40];
    int sel = blockIdx.x >> 4, nx = blockIdx.x & 15;
    const u16* A = (sel == 2) ? xu16 : xc16;
    const u16* Wt = wtblk + ((sel == 0) ? WT_Q : (sel == 1) ? WT_K : WT_V);
    float* C = (sel == 0) ? fq : (sel == 1) ? fk : fv;
    float scale = (sel == 1) ? kscale : 1.f;
    gemm_tile_body<128, 64>(A, IN, Wt, IN, nullptr, nullptr, 0, C, IN, ROWS, scale,
                            blockIdx.y * 128, nx * 64, As, Bs);
}

// ---------------------------------------------------------------- causal depthwise conv (K=4) + SiLU
// Emits f32 xc (gates), bf16 xc16 (q/k GEMM A), bf16 xu16 (v GEMM A).
__global__ __launch_bounds__(256) void conv_silu_kernel(const float* __restrict__ up,
                                                        const float* __restrict__ ck,
                                                        const float* __restrict__ cb,
                                                        float* __restrict__ xc,
                                                        u16* __restrict__ xc16,
                                                        u16* __restrict__ xu16) {
    int idx = blockIdx.x * 256 + threadIdx.x;
    if (idx >= ROWS * IN) return;
    int c = idx & (IN - 1);
    int bt = idx >> 10;
    int t = bt % TT, b = bt / TT;
    float cur = up[((size_t)(b * TT + t)) * (2 * IN) + c];
    float acc = cb[c] + cur * ck[c * KK + (KK - 1)];
#pragma unroll
    for (int j = 0; j < KK - 1; j++) {
        int tt = t - (KK - 1) + j;
        if (tt >= 0) acc += up[((size_t)(b * TT + tt)) * (2 * IN) + c] * ck[c * KK + j];
    }
    float s = siluf(acc);
    xc[idx] = s;
    xc16[idx] = f2bf(s);
    xu16[idx] = f2bf(cur);
}

// ---------------------------------------------------------------- gate weight transpose
__global__ __launch_bounds__(256) void gate_w_transpose(const float* __restrict__ wig,
                                                        const float* __restrict__ wfg,
                                                        float* __restrict__ wt) {
    int idx = blockIdx.x * 256 + threadIdx.x;
    int k = idx & 1023;
    int g = (idx >> 10) & 15;
    int blk = idx >> 14;
    const float* w = (g < 8) ? (wig + (size_t)blk * IN * NHh) : (wfg + (size_t)blk * IN * NHh);
    wt[idx] = w[k * NHh + (g & 7)];
}

// ---------------------------------------------------------------- gate projections (coalesced wt)
__global__ __launch_bounds__(256) void gates_kernel(const float* __restrict__ xc,
                                                    const float* __restrict__ wt,
                                                    const float* __restrict__ big,
                                                    const float* __restrict__ bfg,
                                                    float* __restrict__ ip, float* __restrict__ fp) {
    int row = blockIdx.x, tid = threadIdx.x;
    __shared__ float sx[IN];
    *(float4*)&sx[tid * 4] = *(const float4*)(xc + (size_t)row * IN + tid * 4);
    __syncthreads();
    int g = tid >> 4, l = tid & 15;
    const float* wrow = wt + g * IN;
    float acc = 0.f;
#pragma unroll
    for (int j = 0; j < 16; j++) {
        int k = j * 64 + l * 4;
        float4 w4 = *(const float4*)(wrow + k);
        float4 x4 = *(const float4*)&sx[k];
        acc += w4.x * x4.x + w4.y * x4.y + w4.z * x4.z + w4.w * x4.w;
    }
#pragma unroll
    for (int o = 8; o > 0; o >>= 1) acc += __shfl_down(acc, o, 16);
    if (l == 0) {
        if (g < 8) ip[(size_t)row * NHh + g] = acc + big[g];
        else       fp[(size_t)row * NHh + (g - 8)] = acc + bfg[g - 8];
    }
}

// ---------------------------------------------------------------- chunkwise mLSTM
__global__ __launch_bounds__(64) void gate_scan_kernel(const float* __restrict__ ip,
        const float* __restrict__ fp, float* __restrict__ gG, float* __restrict__ gM,
        float* __restrict__ gMb, float* __restrict__ gDec) {
    constexpr int PER = 9;
    int chain = blockIdx.x;
    int b = chain >> 3, h = chain & 7;
    int lane = threadIdx.x;
    int tbase = lane * PER;
    float lcs[PER];
    float gi[PER];
    float csum = 0.f;
#pragma unroll
    for (int i = 0; i < PER; i++) {
        int t = tbase + i;
        float fpv = 0.f, ipv = 0.f;
        if (t < TT) {
            size_t gidx = (size_t)(b * TT + t) * NHh + h;
            fpv = fp[gidx]; ipv = ip[gidx];
        }
        float flv = (fpv >= 0.f) ? -log1pf(__expf(-fpv)) : (fpv - log1pf(__expf(fpv)));
        if (t >= TT) flv = 0.f;
        csum += flv;
        lcs[i] = csum;
        gi[i] = ipv;
    }
    float ps = csum;
#pragma unroll
    for (int o = 1; o < 64; o <<= 1) {
        float v = __shfl_up(ps, o);
        if (lane >= o) ps += v;
    }
    float Fexcl = ps - csum;
    float G[PER];
    float cmax = -1e30f;
#pragma unroll
    for (int i = 0; i < PER; i++) {
        int t = tbase + i;
        G[i] = (t < TT) ? (gi[i] - (Fexcl + lcs[i])) : -1e30f;
        cmax = fmaxf(cmax, G[i]);
        lcs[i] = cmax;
    }
    float pm = cmax;
#pragma unroll
    for (int o = 1; o < 64; o <<= 1) {
        float v = __shfl_up(pm, o);
        if (lane >= o) pm = fmaxf(pm, v);
    }
    float Me = __shfl_up(pm, 1);
    if (lane == 0) Me = -1e30f;
    __shared__ float sMb[NCH];
#pragma unroll
    for (int i = 0; i < PER; i++) {
        int t = tbase + i;
        if (t < TT) {
            float Mt = fmaxf(0.f, fmaxf(Me, lcs[i]));
            gG[chain * TT + t] = G[i];
            gM[chain * TT + t] = Mt;
            if (((t & 63) == 63) || t == TT - 1) sMb[t >> 6] = Mt;
        }
    }
    __syncthreads();
    if (lane < NCH) {
        float Mb = sMb[lane];
        float Mbp = (lane == 0) ? 0.f : sMb[lane - 1];
        gMb[chain * NCH + lane] = Mb;
        gDec[chain * NCH + lane] = __expf(Mbp - Mb);
    }
}

// Kernel B1: per-chunk local state via MFMA. P stored [e][d] (e-major).
// P[e][d] = sum_j (w_j * V[j][e]) * K[j][d]  -- a 128x128x64 bf16 GEMM per block.
// K and w*V are staged TRANSPOSED (j-contiguous) in LDS as bf16 with a column
// swizzle (jc = j ^ ((row>>5)<<4)) so the transposed b16 stores are
// bank-conflict-free (rows 32 apart have identical bank phase at stride 72).
__global__ __launch_bounds__(256, 2) void chunk_state_kernel(const float* __restrict__ kk,
        const float* __restrict__ vv, const float* __restrict__ gG,
        const float* __restrict__ gMb, float* __restrict__ P, float* __restrict__ nP) {
    int c = blockIdx.x, chain = blockIdx.y;
    int b = chain >> 3, h = chain & 7;
    int t0 = c * 64;
    int nvalid = min(64, TT - t0);
    __shared__ __align__(16) u16 sWv[128][72];   // [e][j] = w_j * V[j][e]
    __shared__ __align__(16) u16 sKt[128][72];   // [d][j] = K[j][d]
    __shared__ float sw[64];
    int tid = threadIdx.x;
    if (tid < 64) {
        float Mb = gMb[chain * NCH + c];
        sw[tid] = (tid < nvalid) ? __expf(gG[chain * TT + t0 + tid] - Mb) : 0.f;
    }
    __syncthreads();

    // ---- stage transposed bf16 tiles: thread -> (j = tid>>2, 32 d's)
    {
        int j = tid >> 2, d0 = (tid & 3) * 32;
        bool val = j < nvalid;
        float wj = sw[j];
        size_t gb = ((size_t)(b * TT + t0 + j)) * IN + h * DHd + d0;
#pragma unroll
        for (int i = 0; i < 8; i++) {
            float4 k4 = val ? *(const float4*)(kk + gb + i * 4) : make_float4(0.f, 0.f, 0.f, 0.f);
            float4 v4 = val ? *(const float4*)(vv + gb + i * 4) : make_float4(0.f, 0.f, 0.f, 0.f);
            int dd = d0 + i * 4;                       // dd..dd+3 share dd>>5
            int jc = j ^ (((dd >> 5) & 3) << 4);       // column swizzle
            sKt[dd + 0][jc] = f2bf(k4.x);
            sKt[dd + 1][jc] = f2bf(k4.y);
            sKt[dd + 2][jc] = f2bf(k4.z);
            sKt[dd + 3][jc] = f2bf(k4.w);
            sWv[dd + 0][jc] = f2bf(v4.x * wj);
            sWv[dd + 1][jc] = f2bf(v4.y * wj);
            sWv[dd + 2][jc] = f2bf(v4.z * wj);
            sWv[dd + 3][jc] = f2bf(v4.w * wj);
        }
    }
    __syncthreads();

    // ---- MFMA: 4 waves in 2x2, each 64x64 output, K=64 in 2 steps of 32
    int wave = tid >> 6, lane = tid & 63;
    int lrow = lane & 15, lquad = lane >> 4;
    int wm = (wave >> 1) * 64, wn = (wave & 1) * 64;
    f32x4 acc[4][4];
#pragma unroll
    for (int mt = 0; mt < 4; mt++)
#pragma unroll
        for (int nt = 0; nt < 4; nt++)
#pragma unroll
            for (int r = 0; r < 4; r++) acc[mt][nt][r] = 0.f;

#pragma unroll
    for (int ks = 0; ks < 2; ks++) {
        bf16x8 af[4], bfr[4];
#pragma unroll
        for (int mt = 0; mt < 4; mt++) {
            int r = wm + mt * 16 + lrow;
            int g = (ks * 4 + lquad) ^ (((r >> 5) & 3) << 1);
            af[mt] = *(const bf16x8*)&sWv[r][g * 8];
        }
#pragma unroll
        for (int nt = 0; nt < 4; nt++) {
            int r = wn + nt * 16 + lrow;
            int g = (ks * 4 + lquad) ^ (((r >> 5) & 3) << 1);
            bfr[nt] = *(const bf16x8*)&sKt[r][g * 8];
        }
#pragma unroll
        for (int mt = 0; mt < 4; mt++)
#pragma unroll
            for (int nt = 0; nt < 4; nt++)
                acc[mt][nt] = __builtin_amdgcn_mfma_f32_16x16x32_bf16(
                    af[mt], bfr[nt], acc[mt][nt], 0, 0, 0);
    }

    // ---- store P (C-layout: row=e=lquad*4+r, col=d=lrow)
    float* Pbase = P + (((size_t)(c * 32 + chain)) << 14);
#pragma unroll
    for (int mt = 0; mt < 4; mt++)
#pragma unroll
        for (int r = 0; r < 4; r++) {
            int e = wm + mt * 16 + lquad * 4 + r;
#pragma unroll
            for (int nt = 0; nt < 4; nt++) {
                int d = wn + nt * 16 + lrow;
                Pbase[(size_t)e * 128 + d] = acc[mt][nt][r];
            }
        }

    // ---- nP[d] = sum_j w_j * K[j][d] from staged tile (2 threads per d)
    {
        int d = tid >> 1, jh = (tid & 1) * 32;
        int swz = ((d >> 5) & 3) << 4;
        float an = 0.f;
#pragma unroll
        for (int j = 0; j < 32; j++) {
            int jj = jh + j;
            an += sw[jj] * bfu(sKt[d][jj ^ swz]);
        }
        an += __shfl_xor(an, 1);
        if ((tid & 1) == 0) nP[(size_t)(c * 32 + chain) * 128 + d] = an;
    }
}

// Kernel B2: in-place exclusive combine over chunks.
__global__ __launch_bounds__(256) void chunk_combine_kernel(float* __restrict__ P,
        const float* __restrict__ gDec) {
    int chain = blockIdx.x >> 6;
    int idx = (blockIdx.x & 63) * 256 + threadIdx.x;
    float run = 0.f;
    for (int c = 0; c < NCH; c++) {
        size_t a = (((size_t)(c * 32 + chain)) << 14) + idx;
        float tmp = P[a];
        P[a] = run;
        run = run * gDec[chain * NCH + c] + tmp;
    }
}

__global__ __launch_bounds__(256) void n_combine_kernel(float* __restrict__ nP,
        const float* __restrict__ gDec) {
    int gidx = blockIdx.x * 256 + threadIdx.x;
    int chain = gidx >> 7, d = gidx & 127;
    float run = 0.f;
    for (int c = 0; c < NCH; c++) {
        size_t a = (size_t)(c * 32 + chain) * 128 + d;
        float tmp = nP[a];
        nP[a] = run;
        run = run * gDec[chain * NCH + c] + tmp;
    }
}

// Kernel C: MFMA chunk outputs (shared C-layout accumulator).
__global__ __launch_bounds__(512, 2) void chunk_out_kernel(const float* __restrict__ qq,
        const float* __restrict__ kk, const float* __restrict__ vv,
        const float* __restrict__ gG, const float* __restrict__ gM,
        const float* __restrict__ gMb, const float* __restrict__ P,
        const float* __restrict__ nP, float* __restrict__ hs) {
    int c = blockIdx.x, chain = blockIdx.y;
    int b = chain >> 3, h = chain & 7;
    int t0 = c * 64;
    int nvalid = min(64, TT - t0);
    __shared__ __align__(16) u16 smem[30720];   // 61.4 KB arena
    __shared__ float sG[64], sM[64], sWr[64], sInv[64], sNb[128], sRS[2][64];
    u16* sQ  = smem;            // [64][136] bf16   (phases 0-2)
    u16* sCB = smem + 8704;     // [128][136] bf16  (phase 0)
    u16* sK  = smem + 8704;     // [64][136] bf16   (phase 1, overlays sCB)
    u16* sVt = smem;            // [128][72] bf16   (phase 3, overlays sQ)
    u16* sD  = smem + 26112;    // [64][72] bf16    (phase 1 write, 3 read)
    int tid = threadIdx.x;
    int wave = tid >> 6, lane = tid & 63;
    int lrow = lane & 15, lquad = lane >> 4;
    int mq = wave >> 1, nh = wave & 1;

    float Mbprev = (c > 0) ? gMb[chain * NCH + c - 1] : 0.f;
    if (tid < 64) {
        bool val = tid < nvalid;
        sG[tid] = val ? gG[chain * TT + t0 + tid] : -1e30f;
        float Mv = val ? gM[chain * TT + t0 + tid] : 1e30f;
        sM[tid] = Mv;
        sWr[tid] = val ? __expf(Mbprev - Mv) : 0.f;
    }
    if (tid >= 128 && tid < 256) sNb[tid - 128] = nP[(size_t)(c * 32 + chain) * 128 + (tid - 128)];

    // ---- stage sQ [64][136]
    {
        int lr = tid >> 3, c0 = (tid & 7) * 16;
        bool val = lr < nvalid;
        size_t gb = ((size_t)(b * TT + t0 + lr)) * IN + h * DHd + c0;
#pragma unroll
        for (int i = 0; i < 4; i++) {
            float4 q4 = val ? *(const float4*)(qq + gb + i * 4) : make_float4(0.f,0.f,0.f,0.f);
            ushort4v tq = {f2bf(q4.x), f2bf(q4.y), f2bf(q4.z), f2bf(q4.w)};
            *(ushort4v*)&sQ[lr * 136 + c0 + i * 4] = tq;
        }
    }
    // ---- stage sCB [128][136] from P[e][d]
    {
        const float* CBbase = P + (((size_t)(c * 32 + chain)) << 14);
        int e = tid >> 2, d0 = (tid & 3) * 32;
#pragma unroll
        for (int i = 0; i < 8; i++) {
            float4 c4 = *(const float4*)(CBbase + (size_t)e * 128 + d0 + i * 4);
            ushort4v tc = {f2bf(c4.x), f2bf(c4.y), f2bf(c4.z), f2bf(c4.w)};
            *(ushort4v*)&sCB[e * 136 + d0 + i * 4] = tc;
        }
    }
    __syncthreads();

    // ---- phase 0: inter = Q @ CB, C-layout acc; then scale by wr
    f32x4 acc[4];
#pragma unroll
    for (int tt = 0; tt < 4; tt++)
#pragma unroll
        for (int r = 0; r < 4; r++) acc[tt][r] = 0.f;
#pragma unroll 1
    for (int ks = 0; ks < 4; ks++) {
        bf16x8 af = *(const bf16x8*)&sQ[(mq * 16 + lrow) * 136 + ks * 32 + lquad * 8];
#pragma unroll
        for (int tt = 0; tt < 4; tt++) {
            bf16x8 bf = *(const bf16x8*)&sCB[(nh * 64 + tt * 16 + lrow) * 136 + ks * 32 + lquad * 8];
            acc[tt] = __builtin_amdgcn_mfma_f32_16x16x32_bf16(af, bf, acc[tt], 0, 0, 0);
        }
    }
#pragma unroll
    for (int tt = 0; tt < 4; tt++)
#pragma unroll
        for (int r = 0; r < 4; r++) acc[tt][r] *= sWr[mq * 16 + lquad * 4 + r];
    __syncthreads();

    // ---- stage sK (overlays sCB)
    {
        int lr = tid >> 3, c0 = (tid & 7) * 16;
        bool val = lr < nvalid;
        size_t gb = ((size_t)(b * TT + t0 + lr)) * IN + h * DHd + c0;
#pragma unroll
        for (int i = 0; i < 4; i++) {
            float4 k4 = val ? *(const float4*)(kk + gb + i * 4) : make_float4(0.f,0.f,0.f,0.f);
            ushort4v tk = {f2bf(k4.x), f2bf(k4.y), f2bf(k4.z), f2bf(k4.w)};
            *(ushort4v*)&sK[lr * 136 + c0 + i * 4] = tk;
        }
    }
    __syncthreads();

    // ---- phase 1: S = Q K^T (2 n-tiles/wave), weights, sD bf16, in-reg rowsums
    {
        f32x4 accS[2];
#pragma unroll
        for (int tt = 0; tt < 2; tt++)
#pragma unroll
            for (int r = 0; r < 4; r++) accS[tt][r] = 0.f;
#pragma unroll 1
        for (int ks = 0; ks < 4; ks++) {
            bf16x8 af = *(const bf16x8*)&sQ[(mq * 16 + lrow) * 136 + ks * 32 + lquad * 8];
#pragma unroll
            for (int tt = 0; tt < 2; tt++) {
                bf16x8 bf = *(const bf16x8*)&sK[((nh * 2 + tt) * 16 + lrow) * 136 + ks * 32 + lquad * 8];
                accS[tt] = __builtin_amdgcn_mfma_f32_16x16x32_bf16(af, bf, accS[tt], 0, 0, 0);
            }
        }
        float rsum[4] = {0.f, 0.f, 0.f, 0.f};
#pragma unroll
        for (int tt = 0; tt < 2; tt++) {
            int j = (nh * 2 + tt) * 16 + lrow;
            float Gj = sG[j];
#pragma unroll
            for (int r = 0; r < 4; r++) {
                int t = mq * 16 + lquad * 4 + r;
                float w = (j <= t) ? __expf(Gj - sM[t]) : 0.f;
                float wD = accS[tt][r] * w;
                rsum[r] += wD;
                sD[t * 72 + j] = f2bf(wD);
            }
        }
#pragma unroll
        for (int r = 0; r < 4; r++) {
#pragma unroll
            for (int msk = 1; msk < 16; msk <<= 1) rsum[r] += __shfl_xor(rsum[r], msk);
        }
        if (lrow == 0) {
#pragma unroll
            for (int r = 0; r < 4; r++) sRS[nh][mq * 16 + lquad * 4 + r] = rsum[r];
        }
    }
    __syncthreads();

    // ---- phase 2: denominators (tid<64); qnb from bf16 sQ
    if (tid < 64) {
        float qn = 0.f;
#pragma unroll 1
        for (int d4 = 0; d4 < 32; d4++) {
            ushort4v q4 = *(const ushort4v*)&sQ[tid * 136 + d4 * 4];
            float4 nb = *(const float4*)&sNb[d4 * 4];
            qn += bfu(q4.x) * nb.x + bfu(q4.y) * nb.y + bfu(q4.z) * nb.z + bfu(q4.w) * nb.w;
        }
        float den = sRS[0][tid] + sRS[1][tid] + sWr[tid] * qn;
        sInv[tid] = 1.f / fmaxf(fabsf(den), 1.f);
    }
    __syncthreads();

    // ---- stage sVt [128][72] = V^T bf16 (overlays sQ)
    {
        int e = tid & 127, tg = (tid >> 7) * 16;
#pragma unroll 1
        for (int i = 0; i < 16; i++) {
            int t = tg + i;
            float v = (t < nvalid) ? vv[((size_t)(b * TT + t0 + t)) * IN + h * DHd + e] : 0.f;
            sVt[e * 72 + t] = f2bf(v);
        }
    }
    __syncthreads();

    // ---- phase 3: acc += D @ V
#pragma unroll 1
    for (int ks = 0; ks < 2; ks++) {
        bf16x8 af = *(const bf16x8*)&sD[(mq * 16 + lrow) * 72 + ks * 32 + lquad * 8];
#pragma unroll
        for (int tt = 0; tt < 4; tt++) {
            bf16x8 bf = *(const bf16x8*)&sVt[(nh * 64 + tt * 16 + lrow) * 72 + ks * 32 + lquad * 8];
            acc[tt] = __builtin_amdgcn_mfma_f32_16x16x32_bf16(af, bf, acc[tt], 0, 0, 0);
        }
    }

    // ---- store (C-layout: col=lane&15 -> e, row=quad*4+r -> t)
#pragma unroll
    for (int tt = 0; tt < 4; tt++) {
#pragma unroll
        for (int r = 0; r < 4; r++) {
            int t = mq * 16 + lquad * 4 + r;
            if (t < nvalid) {
                int e = nh * 64 + tt * 16 + lrow;
                hs[((size_t)(b * TT + t0 + t)) * IN + h * DHd + e] = acc[tt][r] * sInv[t];
            }
        }
    }
}

// ---------------------------------------------------------------- per-head norm * hn_s * silu(z) -> bf16
__global__ __launch_bounds__(64) void headnorm_kernel(const float* __restrict__ hs,
                                                      const float* __restrict__ hn,
                                                      const float* __restrict__ up,
                                                      u16* __restrict__ out16) {
    int idx = blockIdx.x;
    int h = idx & 7, bt = idx >> 3;
    int tid = threadIdx.x;
    size_t base = (size_t)bt * IN + h * DHd;
    float x0 = hs[base + tid], x1 = hs[base + 64 + tid];
    float sum = x0 + x1, sq = x0 * x0 + x1 * x1;
#pragma unroll
    for (int o = 32; o > 0; o >>= 1) { sum += __shfl_xor(sum, o); sq += __shfl_xor(sq, o); }
    float mu = sum / DHd, var = sq / DHd - mu * mu, inv = rsqrtf(var + EPSV);
    size_t zb = (size_t)bt * (2 * IN) + IN + h * DHd;
    out16[base + tid]      = f2bf((x0 - mu) * inv * hn[h * DHd + tid]      * siluf(up[zb + tid]));
    out16[base + 64 + tid] = f2bf((x1 - mu) * inv * hn[h * DHd + 64 + tid] * siluf(up[zb + 64 + tid]));
}

// ---------------------------------------------------------------- head: LN+ReLU of cls rows -> vcls
__global__ __launch_bounds__(256) void cls_ln_kernel(const float* __restrict__ hbuf,
                                                     const float* __restrict__ s, const float* __restrict__ bb,
                                                     float* __restrict__ vcls) {
    int b = blockIdx.x, tid = threadIdx.x;
    const float* r = hbuf + ((size_t)b * TT + TT - 1) * Dm;
    __shared__ float s1[4], s2[4];
    float x0 = r[tid], x1 = r[tid + 256];
    float sum = x0 + x1, sq = x0 * x0 + x1 * x1;
#pragma unroll
    for (int o = 32; o > 0; o >>= 1) { sum += __shfl_xor(sum, o); sq += __shfl_xor(sq, o); }
    if ((tid & 63) == 0) { s1[tid >> 6] = sum; s2[tid >> 6] = sq; }
    __syncthreads();
    sum = s1[0] + s1[1] + s1[2] + s1[3];
    sq  = s2[0] + s2[1] + s2[2] + s2[3];
    float mu = sum / Dm, var = sq / Dm - mu * mu, inv = rsqrtf(var + EPSV);
    float n0 = (x0 - mu) * inv * s[tid] + bb[tid];
    float n1 = (x1 - mu) * inv * s[tid + 256] + bb[tid + 256];
    vcls[b * Dm + tid]       = fmaxf(n0, 0.f);
    vcls[b * Dm + tid + 256] = fmaxf(n1, 0.f);
}

// ---------------------------------------------------------------- head: FC
__global__ __launch_bounds__(256) void fc_kernel(const float* __restrict__ vcls,
                                                 const float* __restrict__ fw,
                                                 const float* __restrict__ fb,
                                                 float* __restrict__ out) {
    __shared__ float svc[Bsz][Dm];
    __shared__ float sred[4][256];
    int tid = threadIdx.x;
    int j0 = blockIdx.x * 64;
    {
        const float4* src = (const float4*)vcls;
        float4* dst = (float4*)&svc[0][0];
        dst[tid] = src[tid];
        dst[tid + 256] = src[tid + 256];
    }
    __syncthreads();
    int j = j0 + (tid & 63);
    int chunk = tid >> 6;
    int kbase = chunk * 128;
    float a0 = 0.f, a1 = 0.f, a2 = 0.f, a3 = 0.f;
    if (j < NCc) {
        const float* fwp = fw + (size_t)kbase * NCc + j;
#pragma unroll 4
        for (int kk = 0; kk < 128; kk++) {
            float w = fwp[(size_t)kk * NCc];
            a0 += svc[0][kbase + kk] * w;
            a1 += svc[1][kbase + kk] * w;
            a2 += svc[2][kbase + kk] * w;
            a3 += svc[3][kbase + kk] * w;
        }
    }
    int jl = tid & 63;
    sred[chunk][jl * 4 + 0] = a0;
    sred[chunk][jl * 4 + 1] = a1;
    sred[chunk][jl * 4 + 2] = a2;
    sred[chunk][jl * 4 + 3] = a3;
    __syncthreads();
    if (tid < 64) {
        int jj = j0 + tid;
        if (jj < NCc) {
            float bias = fb[jj];
#pragma unroll
            for (int b = 0; b < Bsz; b++) {
                float v = sred[0][tid * 4 + b] + sred[1][tid * 4 + b]
                        + sred[2][tid * 4 + b] + sred[3][tid * 4 + b];
                out[b * NCc + jj] = v + bias;
            }
        }
    }
}

// ---------------------------------------------------------------- launch
extern "C" void kernel_launch(void* const* d_in, const int* in_sizes, int n_in,
                              void* d_out, int out_size, void* d_ws, size_t ws_size,
                              hipStream_t stream) {
    const float* x      = (const float*)d_in[0];
    const float* cls    = (const float*)d_in[1];
    const float* ln_s   = (const float*)d_in[2];
    const float* ln_b   = (const float*)d_in[3];
    const float* w_up   = (const float*)d_in[4];
    const float* b_up   = (const float*)d_in[5];
    const float* conv_k = (const float*)d_in[6];
    const float* conv_b = (const float*)d_in[7];
    const float* w_q    = (const float*)d_in[8];
    const float* w_k    = (const float*)d_in[9];
    const float* w_v    = (const float*)d_in[10];
    const float* w_ig   = (const float*)d_in[11];
    const float* b_ig   = (const float*)d_in[12];
    const float* w_fg   = (const float*)d_in[13];
    const float* b_fg   = (const float*)d_in[14];
    const float* hn_s   = (const float*)d_in[15];
    const float* w_down = (const float*)d_in[16];
    const float* b_down = (const float*)d_in[17];
    const float* fcls   = (const float*)d_in[18];
    const float* fclb   = (const float*)d_in[19];
    const float* fc_w   = (const float*)d_in[20];
    const float* fc_b   = (const float*)d_in[21];
    float* out = (float*)d_out;

    float* ws = (float*)d_ws;
    size_t off = 0;
    float* f_h  = ws + off; off += (size_t)ROWS * Dm;
    float* f_up = ws + off; off += (size_t)ROWS * 2 * IN;
    float* f_xc = ws + off; off += (size_t)ROWS * IN;
    float* f_q  = ws + off; off += (size_t)ROWS * IN;
    float* f_k  = ws + off; off += (size_t)ROWS * IN;
    float* f_v  = ws + off; off += (size_t)ROWS * IN;
    float* f_hs = ws + off; off += (size_t)ROWS * IN;
    float* f_ip = ws + off; off += (size_t)ROWS * NHh;
    float* f_fp = ws + off; off += (size_t)ROWS * NHh;
    float* g_G  = ws + off; off += 32 * TT;
    float* g_M  = ws + off; off += 32 * TT;
    float* g_Mb = ws + off; off += 32 * NCH;
    float* g_De = ws + off; off += 32 * NCH;
    float* g_P  = ws + off; off += (size_t)NCH * 32 * DHd * DHd;
    float* g_nP = ws + off; off += (size_t)NCH * 32 * DHd;
    float* f_vc = ws + off; off += Bsz * Dm;
    float* g_wt = ws + off; off += 2 * 16 * IN;
    u16* g_Wt  = (u16*)(ws + off); off += (2 * WT_STRIDE + 1) / 2;
    u16* f_xn16 = (u16*)(ws + off); off += ((size_t)ROWS * Dm + 1) / 2;
    u16* f_xc16 = (u16*)(ws + off); off += ((size_t)ROWS * IN + 1) / 2;
    u16* f_xu16 = (u16*)(ws + off); off += ((size_t)ROWS * IN + 1) / 2;
    u16* f_xg16 = (u16*)(ws + off); off += ((size_t)ROWS * IN + 1) / 2;

    const float kscale = 0.08838834764831845f; // DH^-0.5
    const int MB = (ROWS + 127) / 128;         // 17
    const int MB64 = (ROWS + 63) / 64;         // 33

    concat_kernel<<<(ROWS * Dm + 255) / 256, 256, 0, stream>>>(x, cls, f_h);
    gate_w_transpose<<<(2 * 16 * IN + 255) / 256, 256, 0, stream>>>(w_ig, w_fg, g_wt);
    w_transpose_kernel<<<dim3(1024, 10), 256, 0, stream>>>(w_up, w_q, w_k, w_v, w_down, g_Wt);

    for (int blk = 0; blk < 2; blk++) {
        const float* p_ln_s = ln_s + blk * Dm;
        const float* p_ln_b = ln_b + blk * Dm;
        const float* p_bup  = b_up + (size_t)blk * 2 * IN;
        const float* p_ck   = conv_k + (size_t)blk * IN * KK;
        const float* p_cb   = conv_b + (size_t)blk * IN;
        const float* p_big  = b_ig + (size_t)blk * NHh;
        const float* p_bfg  = b_fg + (size_t)blk * NHh;
        const float* p_hns  = hn_s + (size_t)blk * NHh * DHd;
        const float* p_bd   = b_down + (size_t)blk * Dm;
        const u16*   p_wt   = g_Wt + (size_t)blk * WT_STRIDE;

        ln_kernel<<<ROWS, 256, 0, stream>>>(f_h, p_ln_s, p_ln_b, f_xn16);

        gemm_mfma_kernel<128, 64><<<dim3(2 * IN / 64, MB), 256, 0, stream>>>(
            f_xn16, Dm, p_wt + WT_UP, Dm, p_bup, nullptr, 0, f_up, 2 * IN, ROWS, 1.f);

        conv_silu_kernel<<<(ROWS * IN + 255) / 256, 256, 0, stream>>>(
            f_up, p_ck, p_cb, f_xc, f_xc16, f_xu16);

        qkv_mfma_kernel<<<dim3(48, MB), 256, 0, stream>>>(
            f_xc16, f_xu16, p_wt, f_q, f_k, f_v, kscale);

        gates_kernel<<<ROWS, 256, 0, stream>>>(f_xc, g_wt + blk * 16 * IN, p_big, p_bfg,
                                               f_ip, f_fp);

        // chunkwise-parallel mLSTM
        gate_scan_kernel<<<32, 64, 0, stream>>>(f_ip, f_fp, g_G, g_M, g_Mb, g_De);
        chunk_state_kernel<<<dim3(NCH, 32), 256, 0, stream>>>(f_k, f_v, g_G, g_Mb, g_P, g_nP);
        chunk_combine_kernel<<<32 * 64, 256, 0, stream>>>(g_P, g_De);
        n_combine_kernel<<<16, 256, 0, stream>>>(g_nP, g_De);
        chunk_out_kernel<<<dim3(NCH, 32), 512, 0, stream>>>(f_q, f_k, f_v, g_G, g_M, g_Mb,
                                                            g_P, g_nP, f_hs);

        headnorm_kernel<<<ROWS * NHh, 64, 0, stream>>>(f_hs, p_hns, f_up, f_xg16);

        gemm_mfma_kernel<64, 64><<<dim3(Dm / 64, MB64), 256, 0, stream>>>(
            f_xg16, IN, p_wt + WT_DN, IN, p_bd, f_h, Dm, f_h, Dm, ROWS, 1.f);
    }

    cls_ln_kernel<<<Bsz, 256, 0, stream>>>(f_h, fcls, fclb, f_vc);
    fc_kernel<<<(NCc + 63) / 64, 256, 0, stream>>>(f_vc, fc_w, fc_b, out);
}

// Round 2
// 451.645 us; speedup vs baseline: 1.1539x; 1.0198x over previous
//
#include <hip/hip_runtime.h>

// ---------------------------------------------------------------- constants
#define EPSV 1e-5f
constexpr int Bsz = 4, T0 = 512, Dm = 512, TT = 513, NHh = 8, KK = 4;
constexpr int IN = 1024, DHd = 128, NCc = 1000;
constexpr int ROWS = Bsz * TT; // 2052
constexpr int MPAD = 2176;     // 17*128 padded staging rows for gload GEMMs
constexpr int NCH = 9;         // chunks of 64: 8*64 + 1 = 513

// bf16 k-major weight buffer offsets (u16 elements), per transformer block
constexpr size_t WT_UP = 0;                      // [2048][512]
constexpr size_t WT_Q  = WT_UP + 2048 * 512;     // [1024][1024]
constexpr size_t WT_K  = WT_Q + 1024 * 1024;
constexpr size_t WT_V  = WT_K + 1024 * 1024;
constexpr size_t WT_DN = WT_V + 1024 * 1024;     // [512][1024]
constexpr size_t WT_STRIDE = WT_DN + 512 * 1024; // 4,718,592 u16

typedef __attribute__((ext_vector_type(8))) short bf16x8;
typedef __attribute__((ext_vector_type(4))) float f32x4;
typedef __attribute__((ext_vector_type(4))) unsigned short ushort4v;
typedef __attribute__((ext_vector_type(8))) unsigned short ushort8v;
typedef unsigned short u16;

__device__ __forceinline__ float siluf(float x) { return x / (1.f + __expf(-x)); }
__device__ __forceinline__ u16 f2bf(float f) {
    unsigned int u = __float_as_uint(f);
    u = (u + 0x7FFFu + ((u >> 16) & 1u)) >> 16;
    return (u16)u;
}
__device__ __forceinline__ float bfu(u16 u) {
    return __uint_as_float(((unsigned int)u) << 16);
}
// async global->LDS, 16 bytes per lane; LDS dest is wave-uniform base + lane*16
__device__ __forceinline__ void gload16(const u16* g, u16* l) {
    __builtin_amdgcn_global_load_lds(
        (const __attribute__((address_space(1))) void*)g,
        (__attribute__((address_space(3))) void*)l, 16, 0, 0);
}

// ---------------------------------------------------------------- concat x + cls
__global__ __launch_bounds__(256) void concat_kernel(const float* __restrict__ x,
                                                     const float* __restrict__ cls,
                                                     float* __restrict__ h) {
    int idx = blockIdx.x * 256 + threadIdx.x;
    if (idx >= Bsz * TT * Dm) return;
    int d = idx & (Dm - 1);
    int bt = idx >> 9;
    int t = bt % TT, b = bt / TT;
    h[idx] = (t < T0) ? x[((size_t)(b * T0 + t)) * Dm + d] : cls[d];
}

// ---------------------------------------------------------------- LayerNorm rows of D=512 -> bf16
__global__ __launch_bounds__(256) void ln_kernel(const float* __restrict__ in,
                                                 const float* __restrict__ s,
                                                 const float* __restrict__ bb,
                                                 u16* __restrict__ out16) {
    int row = blockIdx.x, tid = threadIdx.x;
    const float* r = in + (size_t)row * Dm;
    __shared__ float s1[4], s2[4];
    float x0 = r[tid], x1 = r[tid + 256];
    float sum = x0 + x1, sq = x0 * x0 + x1 * x1;
#pragma unroll
    for (int o = 32; o > 0; o >>= 1) { sum += __shfl_xor(sum, o); sq += __shfl_xor(sq, o); }
    if ((tid & 63) == 0) { s1[tid >> 6] = sum; s2[tid >> 6] = sq; }
    __syncthreads();
    sum = s1[0] + s1[1] + s1[2] + s1[3];
    sq  = s2[0] + s2[1] + s2[2] + s2[3];
    float mu = sum / Dm, var = sq / Dm - mu * mu, inv = rsqrtf(var + EPSV);
    out16[(size_t)row * Dm + tid]       = f2bf((x0 - mu) * inv * s[tid] + bb[tid]);
    out16[(size_t)row * Dm + tid + 256] = f2bf((x1 - mu) * inv * s[tid + 256] + bb[tid + 256]);
}

// ---------------------------------------------------------------- weight transpose f32 KxN -> bf16 [N][K]
__global__ __launch_bounds__(256) void w_transpose_kernel(const float* __restrict__ wup,
        const float* __restrict__ wq, const float* __restrict__ wk,
        const float* __restrict__ wv, const float* __restrict__ wdn,
        u16* __restrict__ wt) {
    int y = blockIdx.y;             // 0..9
    int blk = y / 5, sel = y - blk * 5;
    int Kd, N; const float* src; size_t doff;
    if (sel == 0)      { Kd = 512;  N = 2048; src = wup + (size_t)blk * 512 * 2048; doff = WT_UP; }
    else if (sel == 1) { Kd = 1024; N = 1024; src = wq  + (size_t)blk * 1024 * 1024; doff = WT_Q; }
    else if (sel == 2) { Kd = 1024; N = 1024; src = wk  + (size_t)blk * 1024 * 1024; doff = WT_K; }
    else if (sel == 3) { Kd = 1024; N = 1024; src = wv  + (size_t)blk * 1024 * 1024; doff = WT_V; }
    else               { Kd = 1024; N = 512;  src = wdn + (size_t)blk * 1024 * 512;  doff = WT_DN; }
    u16* dst = wt + (size_t)blk * WT_STRIDE + doff;
    int ntx = N >> 5;
    int ntiles = ntx * (Kd >> 5);
    int ti = blockIdx.x;
    if (ti >= ntiles) return;
    int tk = ti / ntx, tn = ti - tk * ntx;
    __shared__ u16 s[32][33];
    int tx = threadIdx.x & 31, ty = threadIdx.x >> 5;
#pragma unroll
    for (int i = 0; i < 4; i++) {
        int k = tk * 32 + ty + i * 8;
        s[ty + i * 8][tx] = f2bf(src[(size_t)k * N + tn * 32 + tx]);
    }
    __syncthreads();
#pragma unroll
    for (int i = 0; i < 4; i++) {
        int n = tn * 32 + ty + i * 8;
        dst[(size_t)n * Kd + tk * 32 + tx] = s[tx][ty + i * 8];
    }
}

// ---------------------------------------------------------------- legacy MFMA GEMM (down-proj)
template<int BM, int BN>
__device__ __forceinline__ void gemm_tile_body(const u16* __restrict__ A, int lda,
                                               const u16* __restrict__ Wt, int Kd,
                                               const float* __restrict__ bias,
                                               const float* __restrict__ resid, int ldr,
                                               float* __restrict__ Cout, int ldc,
                                               int M, float scale, int m0, int n0,
                                               u16 (*As)[BM][40], u16 (*Bs)[BN][40]) {
    constexpr int MT = BM / 32;
    constexpr int NT = BN / 32;
    constexpr int ANV = BM / 64;           // ushort8 A-loads per thread
    constexpr int BNV = BN / 64;           // ushort8 B-loads per thread
    int tid = threadIdx.x;
    int wave = tid >> 6, lane = tid & 63;
    int wm = (wave >> 1) * (BM / 2), wn = (wave & 1) * (BN / 2);
    int lrow = lane & 15, lquad = lane >> 4;

    f32x4 acc[MT][NT];
#pragma unroll
    for (int i = 0; i < MT; i++)
#pragma unroll
        for (int j = 0; j < NT; j++)
#pragma unroll
            for (int r = 0; r < 4; r++) acc[i][j][r] = 0.f;

    int am, ak, bn, bk;
    if (BM == 128) { am = tid >> 1; ak = (tid & 1) * 16; }
    else           { am = tid >> 2; ak = (tid & 3) * 8; }
    if (BN == 128) { bn = tid & 127; bk = (tid >> 7) * 16; }
    else           { bn = tid & 63;  bk = (tid >> 6) * 8; }
    int gm = m0 + am;
    const u16* arow = A + (size_t)(gm < M ? gm : 0) * lda + ak;
    bool avalid = gm < M;
    const u16* wrow = Wt + (size_t)(n0 + bn) * Kd + bk;

    ushort8v areg[ANV];
    ushort8v breg[BNV];

    auto load_tile = [&](int k0) {
        if (avalid) {
#pragma unroll
            for (int i = 0; i < ANV; i++) areg[i] = *(const ushort8v*)(arow + k0 + i * 8);
        } else {
#pragma unroll
            for (int i = 0; i < ANV; i++) areg[i] = (ushort8v){0,0,0,0,0,0,0,0};
        }
#pragma unroll
        for (int i = 0; i < BNV; i++) breg[i] = *(const ushort8v*)(wrow + k0 + i * 8);
    };
    auto store_tile = [&](int buf) {
#pragma unroll
        for (int i = 0; i < ANV; i++)
            *(ushort8v*)&As[buf][am][ak + i * 8] = areg[i];
#pragma unroll
        for (int i = 0; i < BNV; i++)
            *(ushort8v*)&Bs[buf][bn][bk + i * 8] = breg[i];
    };

    load_tile(0);
    store_tile(0);
    __syncthreads();

    int nk = Kd >> 5;
#pragma unroll 1
    for (int it = 0; it < nk; it++) {
        int cur = it & 1;
        bool more = (it + 1 < nk);
        if (more) load_tile((it + 1) << 5);
        bf16x8 afr[MT], bfr[NT];
#pragma unroll
        for (int mt = 0; mt < MT; mt++)
            afr[mt] = *(const bf16x8*)&As[cur][wm + mt * 16 + lrow][lquad * 8];
#pragma unroll
        for (int nt = 0; nt < NT; nt++)
            bfr[nt] = *(const bf16x8*)&Bs[cur][wn + nt * 16 + lrow][lquad * 8];
#pragma unroll
        for (int mt = 0; mt < MT; mt++)
#pragma unroll
            for (int nt = 0; nt < NT; nt++)
                acc[mt][nt] = __builtin_amdgcn_mfma_f32_16x16x32_bf16(
                    afr[mt], bfr[nt], acc[mt][nt], 0, 0, 0);
        if (more) store_tile(cur ^ 1);
        __syncthreads();
    }

#pragma unroll
    for (int mt = 0; mt < MT; mt++) {
#pragma unroll
        for (int r = 0; r < 4; r++) {
            int gmr = m0 + wm + mt * 16 + lquad * 4 + r;
            if (gmr >= M) continue;
#pragma unroll
            for (int nt = 0; nt < NT; nt++) {
                int gn = n0 + wn + nt * 16 + lrow;
                float v = acc[mt][nt][r] * scale;
                if (bias) v += bias[gn];
                if (resid) v += resid[(size_t)gmr * ldr + gn];
                Cout[(size_t)gmr * ldc + gn] = v;
            }
        }
    }
}

template<int BM, int BN>
__global__ __launch_bounds__(256, 2) void gemm_mfma_kernel(const u16* __restrict__ A, int lda,
                                                           const u16* __restrict__ Wt, int Kd,
                                                           const float* __restrict__ bias,
                                                           const float* __restrict__ resid, int ldr,
                                                           float* __restrict__ Cout, int ldc,
                                                           int M, float scale) {
    __shared__ __align__(16) u16 As[2][BM][40];
    __shared__ __align__(16) u16 Bs[2][BN][40];
    gemm_tile_body<BM, BN>(A, lda, Wt, Kd, bias, resid, ldr, Cout, ldc, M, scale,
                           blockIdx.y * BM, blockIdx.x * BN, As, Bs);
}

// ---------------------------------------------------------------- m97-style 128x128 gload GEMM
// A staged rows must be readable up to MPAD (pad rows = garbage, outputs guarded).
// LDS: linear [128][32] bf16 tiles; global_load_lds 16B/lane, wave-uniform LDS base.
__device__ __forceinline__ void gemm128_body(const u16* __restrict__ A, int lda,
                                             const u16* __restrict__ Wt, int Kd,
                                             const float* __restrict__ bias,
                                             float* __restrict__ Cout, int ldc,
                                             int M, float scale, int m0, int n0,
                                             u16* As, u16* Bs) {
    int tid = threadIdx.x;
    int wave = tid >> 6, lane = tid & 63;
    int lrow = lane & 15, lquad = lane >> 4;
    int wm = (wave >> 1) * 64, wn = (wave & 1) * 64;

    // staging addresses: issue i covers rows i*64 + wave*16 + lane/4, k (lane&3)*8
    const u16* ag0 = A + (size_t)(m0 + wave * 16 + (lane >> 2)) * lda + (lane & 3) * 8;
    const u16* ag1 = ag0 + (size_t)64 * lda;
    const u16* bg0 = Wt + (size_t)(n0 + wave * 16 + (lane >> 2)) * Kd + (lane & 3) * 8;
    const u16* bg1 = bg0 + (size_t)64 * Kd;
    u16* la0 = As + wave * 512;          // 1KB per wave-issue
    u16* la1 = As + 2048 + wave * 512;
    u16* lb0 = Bs + wave * 512;
    u16* lb1 = Bs + 2048 + wave * 512;

    f32x4 acc[4][4];
#pragma unroll
    for (int i = 0; i < 4; i++)
#pragma unroll
        for (int j = 0; j < 4; j++)
#pragma unroll
            for (int r = 0; r < 4; r++) acc[i][j][r] = 0.f;

    int nk = Kd >> 5;
#pragma unroll 1
    for (int it = 0; it < nk; it++) {
        int k0 = it << 5;
        gload16(ag0 + k0, la0);
        gload16(ag1 + k0, la1);
        gload16(bg0 + k0, lb0);
        gload16(bg1 + k0, lb1);
        __syncthreads();                 // drains vmcnt: tiles resident
        bf16x8 afr[4], bfr[4];
#pragma unroll
        for (int mt = 0; mt < 4; mt++)
            afr[mt] = *(const bf16x8*)&As[(wm + mt * 16 + lrow) * 32 + lquad * 8];
#pragma unroll
        for (int nt = 0; nt < 4; nt++)
            bfr[nt] = *(const bf16x8*)&Bs[(wn + nt * 16 + lrow) * 32 + lquad * 8];
#pragma unroll
        for (int mt = 0; mt < 4; mt++)
#pragma unroll
            for (int nt = 0; nt < 4; nt++)
                acc[mt][nt] = __builtin_amdgcn_mfma_f32_16x16x32_bf16(
                    afr[mt], bfr[nt], acc[mt][nt], 0, 0, 0);
        __syncthreads();                 // all reads done before next overwrite
    }

#pragma unroll
    for (int mt = 0; mt < 4; mt++) {
#pragma unroll
        for (int r = 0; r < 4; r++) {
            int gmr = m0 + wm + mt * 16 + lquad * 4 + r;
            if (gmr >= M) continue;
#pragma unroll
            for (int nt = 0; nt < 4; nt++) {
                int gn = n0 + wn + nt * 16 + lrow;
                float v = acc[mt][nt][r] * scale;
                if (bias) v += bias[gn];
                Cout[(size_t)gmr * ldc + gn] = v;
            }
        }
    }
}

__global__ __launch_bounds__(256, 2) void up_gl_kernel(const u16* __restrict__ A,
        const u16* __restrict__ Wt, const float* __restrict__ bias, float* __restrict__ C) {
    __shared__ __align__(16) u16 As[128 * 32];
    __shared__ __align__(16) u16 Bs[128 * 32];
    gemm128_body(A, Dm, Wt, Dm, bias, C, 2 * IN, ROWS, 1.f,
                 blockIdx.y * 128, blockIdx.x * 128, As, Bs);
}

// q/k/v in ONE dispatch, BN=128: blockIdx.x in [0,24): sel = x>>3, nx = x&7.
__global__ __launch_bounds__(256, 2) void qkv_gl_kernel(const u16* __restrict__ xc16,
                                                        const u16* __restrict__ xu16,
                                                        const u16* __restrict__ wtblk,
                                                        float* __restrict__ fq,
                                                        float* __restrict__ fk,
                                                        float* __restrict__ fv,
                                                        float kscale) {
    __shared__ __align__(16) u16 As[128 * 32];
    __shared__ __align__(16) u16 Bs[128 * 32];
    int sel = blockIdx.x >> 3, nx = blockIdx.x & 7;
    const u16* A = (sel == 2) ? xu16 : xc16;
    const u16* Wt = wtblk + ((sel == 0) ? WT_Q : (sel == 1) ? WT_K : WT_V);
    float* C = (sel == 0) ? fq : (sel == 1) ? fk : fv;
    float scale = (sel == 1) ? kscale : 1.f;
    gemm128_body(A, IN, Wt, IN, nullptr, C, IN, ROWS, scale,
                 blockIdx.y * 128, nx * 128, As, Bs);
}

// ---------------------------------------------------------------- causal depthwise conv (K=4) + SiLU
// Emits f32 xc (gates), bf16 xc16 (q/k GEMM A), bf16 xu16 (v GEMM A).
__global__ __launch_bounds__(256) void conv_silu_kernel(const float* __restrict__ up,
                                                        const float* __restrict__ ck,
                                                        const float* __restrict__ cb,
                                                        float* __restrict__ xc,
                                                        u16* __restrict__ xc16,
                                                        u16* __restrict__ xu16) {
    int idx = blockIdx.x * 256 + threadIdx.x;
    if (idx >= ROWS * IN) return;
    int c = idx & (IN - 1);
    int bt = idx >> 10;
    int t = bt % TT, b = bt / TT;
    float cur = up[((size_t)(b * TT + t)) * (2 * IN) + c];
    float acc = cb[c] + cur * ck[c * KK + (KK - 1)];
#pragma unroll
    for (int j = 0; j < KK - 1; j++) {
        int tt = t - (KK - 1) + j;
        if (tt >= 0) acc += up[((size_t)(b * TT + tt)) * (2 * IN) + c] * ck[c * KK + j];
    }
    float s = siluf(acc);
    xc[idx] = s;
    xc16[idx] = f2bf(s);
    xu16[idx] = f2bf(cur);
}

// ---------------------------------------------------------------- gate weight transpose
__global__ __launch_bounds__(256) void gate_w_transpose(const float* __restrict__ wig,
                                                        const float* __restrict__ wfg,
                                                        float* __restrict__ wt) {
    int idx = blockIdx.x * 256 + threadIdx.x;
    int k = idx & 1023;
    int g = (idx >> 10) & 15;
    int blk = idx >> 14;
    const float* w = (g < 8) ? (wig + (size_t)blk * IN * NHh) : (wfg + (size_t)blk * IN * NHh);
    wt[idx] = w[k * NHh + (g & 7)];
}

// ---------------------------------------------------------------- gate projections (coalesced wt)
__global__ __launch_bounds__(256) void gates_kernel(const float* __restrict__ xc,
                                                    const float* __restrict__ wt,
                                                    const float* __restrict__ big,
                                                    const float* __restrict__ bfg,
                                                    float* __restrict__ ip, float* __restrict__ fp) {
    int row = blockIdx.x, tid = threadIdx.x;
    __shared__ float sx[IN];
    *(float4*)&sx[tid * 4] = *(const float4*)(xc + (size_t)row * IN + tid * 4);
    __syncthreads();
    int g = tid >> 4, l = tid & 15;
    const float* wrow = wt + g * IN;
    float acc = 0.f;
#pragma unroll
    for (int j = 0; j < 16; j++) {
        int k = j * 64 + l * 4;
        float4 w4 = *(const float4*)(wrow + k);
        float4 x4 = *(const float4*)&sx[k];
        acc += w4.x * x4.x + w4.y * x4.y + w4.z * x4.z + w4.w * x4.w;
    }
#pragma unroll
    for (int o = 8; o > 0; o >>= 1) acc += __shfl_down(acc, o, 16);
    if (l == 0) {
        if (g < 8) ip[(size_t)row * NHh + g] = acc + big[g];
        else       fp[(size_t)row * NHh + (g - 8)] = acc + bfg[g - 8];
    }
}

// ---------------------------------------------------------------- chunkwise mLSTM
__global__ __launch_bounds__(64) void gate_scan_kernel(const float* __restrict__ ip,
        const float* __restrict__ fp, float* __restrict__ gG, float* __restrict__ gM,
        float* __restrict__ gMb, float* __restrict__ gDec) {
    constexpr int PER = 9;
    int chain = blockIdx.x;
    int b = chain >> 3, h = chain & 7;
    int lane = threadIdx.x;
    int tbase = lane * PER;
    float lcs[PER];
    float gi[PER];
    float csum = 0.f;
#pragma unroll
    for (int i = 0; i < PER; i++) {
        int t = tbase + i;
        float fpv = 0.f, ipv = 0.f;
        if (t < TT) {
            size_t gidx = (size_t)(b * TT + t) * NHh + h;
            fpv = fp[gidx]; ipv = ip[gidx];
        }
        float flv = (fpv >= 0.f) ? -log1pf(__expf(-fpv)) : (fpv - log1pf(__expf(fpv)));
        if (t >= TT) flv = 0.f;
        csum += flv;
        lcs[i] = csum;
        gi[i] = ipv;
    }
    float ps = csum;
#pragma unroll
    for (int o = 1; o < 64; o <<= 1) {
        float v = __shfl_up(ps, o);
        if (lane >= o) ps += v;
    }
    float Fexcl = ps - csum;
    float G[PER];
    float cmax = -1e30f;
#pragma unroll
    for (int i = 0; i < PER; i++) {
        int t = tbase + i;
        G[i] = (t < TT) ? (gi[i] - (Fexcl + lcs[i])) : -1e30f;
        cmax = fmaxf(cmax, G[i]);
        lcs[i] = cmax;
    }
    float pm = cmax;
#pragma unroll
    for (int o = 1; o < 64; o <<= 1) {
        float v = __shfl_up(pm, o);
        if (lane >= o) pm = fmaxf(pm, v);
    }
    float Me = __shfl_up(pm, 1);
    if (lane == 0) Me = -1e30f;
    __shared__ float sMb[NCH];
#pragma unroll
    for (int i = 0; i < PER; i++) {
        int t = tbase + i;
        if (t < TT) {
            float Mt = fmaxf(0.f, fmaxf(Me, lcs[i]));
            gG[chain * TT + t] = G[i];
            gM[chain * TT + t] = Mt;
            if (((t & 63) == 63) || t == TT - 1) sMb[t >> 6] = Mt;
        }
    }
    __syncthreads();
    if (lane < NCH) {
        float Mb = sMb[lane];
        float Mbp = (lane == 0) ? 0.f : sMb[lane - 1];
        gMb[chain * NCH + lane] = Mb;
        gDec[chain * NCH + lane] = __expf(Mbp - Mb);
    }
}

// Kernel B1: per-chunk local state via MFMA. P stored [e][d] (e-major).
__global__ __launch_bounds__(256, 2) void chunk_state_kernel(const float* __restrict__ kk,
        const float* __restrict__ vv, const float* __restrict__ gG,
        const float* __restrict__ gMb, float* __restrict__ P, float* __restrict__ nP) {
    int c = blockIdx.x, chain = blockIdx.y;
    int b = chain >> 3, h = chain & 7;
    int t0 = c * 64;
    int nvalid = min(64, TT - t0);
    __shared__ __align__(16) u16 sWv[128][72];   // [e][j] = w_j * V[j][e]
    __shared__ __align__(16) u16 sKt[128][72];   // [d][j] = K[j][d]
    __shared__ float sw[64];
    int tid = threadIdx.x;
    if (tid < 64) {
        float Mb = gMb[chain * NCH + c];
        sw[tid] = (tid < nvalid) ? __expf(gG[chain * TT + t0 + tid] - Mb) : 0.f;
    }
    __syncthreads();

    // ---- stage transposed bf16 tiles: thread -> (j = tid>>2, 32 d's)
    {
        int j = tid >> 2, d0 = (tid & 3) * 32;
        bool val = j < nvalid;
        float wj = sw[j];
        size_t gb = ((size_t)(b * TT + t0 + j)) * IN + h * DHd + d0;
#pragma unroll
        for (int i = 0; i < 8; i++) {
            float4 k4 = val ? *(const float4*)(kk + gb + i * 4) : make_float4(0.f, 0.f, 0.f, 0.f);
            float4 v4 = val ? *(const float4*)(vv + gb + i * 4) : make_float4(0.f, 0.f, 0.f, 0.f);
            int dd = d0 + i * 4;                       // dd..dd+3 share dd>>5
            int jc = j ^ (((dd >> 5) & 3) << 4);       // column swizzle
            sKt[dd + 0][jc] = f2bf(k4.x);
            sKt[dd + 1][jc] = f2bf(k4.y);
            sKt[dd + 2][jc] = f2bf(k4.z);
            sKt[dd + 3][jc] = f2bf(k4.w);
            sWv[dd + 0][jc] = f2bf(v4.x * wj);
            sWv[dd + 1][jc] = f2bf(v4.y * wj);
            sWv[dd + 2][jc] = f2bf(v4.z * wj);
            sWv[dd + 3][jc] = f2bf(v4.w * wj);
        }
    }
    __syncthreads();

    // ---- MFMA: 4 waves in 2x2, each 64x64 output, K=64 in 2 steps of 32
    int wave = tid >> 6, lane = tid & 63;
    int lrow = lane & 15, lquad = lane >> 4;
    int wm = (wave >> 1) * 64, wn = (wave & 1) * 64;
    f32x4 acc[4][4];
#pragma unroll
    for (int mt = 0; mt < 4; mt++)
#pragma unroll
        for (int nt = 0; nt < 4; nt++)
#pragma unroll
            for (int r = 0; r < 4; r++) acc[mt][nt][r] = 0.f;

#pragma unroll
    for (int ks = 0; ks < 2; ks++) {
        bf16x8 af[4], bfr[4];
#pragma unroll
        for (int mt = 0; mt < 4; mt++) {
            int r = wm + mt * 16 + lrow;
            int g = (ks * 4 + lquad) ^ (((r >> 5) & 3) << 1);
            af[mt] = *(const bf16x8*)&sWv[r][g * 8];
        }
#pragma unroll
        for (int nt = 0; nt < 4; nt++) {
            int r = wn + nt * 16 + lrow;
            int g = (ks * 4 + lquad) ^ (((r >> 5) & 3) << 1);
            bfr[nt] = *(const bf16x8*)&sKt[r][g * 8];
        }
#pragma unroll
        for (int mt = 0; mt < 4; mt++)
#pragma unroll
            for (int nt = 0; nt < 4; nt++)
                acc[mt][nt] = __builtin_amdgcn_mfma_f32_16x16x32_bf16(
                    af[mt], bfr[nt], acc[mt][nt], 0, 0, 0);
    }

    // ---- store P (C-layout: row=e=lquad*4+r, col=d=lrow)
    float* Pbase = P + (((size_t)(c * 32 + chain)) << 14);
#pragma unroll
    for (int mt = 0; mt < 4; mt++)
#pragma unroll
        for (int r = 0; r < 4; r++) {
            int e = wm + mt * 16 + lquad * 4 + r;
#pragma unroll
            for (int nt = 0; nt < 4; nt++) {
                int d = wn + nt * 16 + lrow;
                Pbase[(size_t)e * 128 + d] = acc[mt][nt][r];
            }
        }

    // ---- nP[d] = sum_j w_j * K[j][d] from staged tile (2 threads per d)
    {
        int d = tid >> 1, jh = (tid & 1) * 32;
        int swz = ((d >> 5) & 3) << 4;
        float an = 0.f;
#pragma unroll
        for (int j = 0; j < 32; j++) {
            int jj = jh + j;
            an += sw[jj] * bfu(sKt[d][jj ^ swz]);
        }
        an += __shfl_xor(an, 1);
        if ((tid & 1) == 0) nP[(size_t)(c * 32 + chain) * 128 + d] = an;
    }
}

// Kernel B2: in-place exclusive combine over chunks.
__global__ __launch_bounds__(256) void chunk_combine_kernel(float* __restrict__ P,
        const float* __restrict__ gDec) {
    int chain = blockIdx.x >> 6;
    int idx = (blockIdx.x & 63) * 256 + threadIdx.x;
    float run = 0.f;
    for (int c = 0; c < NCH; c++) {
        size_t a = (((size_t)(c * 32 + chain)) << 14) + idx;
        float tmp = P[a];
        P[a] = run;
        run = run * gDec[chain * NCH + c] + tmp;
    }
}

__global__ __launch_bounds__(256) void n_combine_kernel(float* __restrict__ nP,
        const float* __restrict__ gDec) {
    int gidx = blockIdx.x * 256 + threadIdx.x;
    int chain = gidx >> 7, d = gidx & 127;
    float run = 0.f;
    for (int c = 0; c < NCH; c++) {
        size_t a = (size_t)(c * 32 + chain) * 128 + d;
        float tmp = nP[a];
        nP[a] = run;
        run = run * gDec[chain * NCH + c] + tmp;
    }
}

// Kernel C: MFMA chunk outputs (shared C-layout accumulator).
__global__ __launch_bounds__(512, 2) void chunk_out_kernel(const float* __restrict__ qq,
        const float* __restrict__ kk, const float* __restrict__ vv,
        const float* __restrict__ gG, const float* __restrict__ gM,
        const float* __restrict__ gMb, const float* __restrict__ P,
        const float* __restrict__ nP, float* __restrict__ hs) {
    int c = blockIdx.x, chain = blockIdx.y;
    int b = chain >> 3, h = chain & 7;
    int t0 = c * 64;
    int nvalid = min(64, TT - t0);
    __shared__ __align__(16) u16 smem[30720];   // 61.4 KB arena
    __shared__ float sG[64], sM[64], sWr[64], sInv[64], sNb[128], sRS[2][64];
    u16* sQ  = smem;            // [64][136] bf16   (phases 0-2)
    u16* sCB = smem + 8704;     // [128][136] bf16  (phase 0)
    u16* sK  = smem + 8704;     // [64][136] bf16   (phase 1, overlays sCB)
    u16* sVt = smem;            // [128][72] bf16   (phase 3, overlays sQ)
    u16* sD  = smem + 26112;    // [64][72] bf16    (phase 1 write, 3 read)
    int tid = threadIdx.x;
    int wave = tid >> 6, lane = tid & 63;
    int lrow = lane & 15, lquad = lane >> 4;
    int mq = wave >> 1, nh = wave & 1;

    float Mbprev = (c > 0) ? gMb[chain * NCH + c - 1] : 0.f;
    if (tid < 64) {
        bool val = tid < nvalid;
        sG[tid] = val ? gG[chain * TT + t0 + tid] : -1e30f;
        float Mv = val ? gM[chain * TT + t0 + tid] : 1e30f;
        sM[tid] = Mv;
        sWr[tid] = val ? __expf(Mbprev - Mv) : 0.f;
    }
    if (tid >= 128 && tid < 256) sNb[tid - 128] = nP[(size_t)(c * 32 + chain) * 128 + (tid - 128)];

    // ---- stage sQ [64][136]
    {
        int lr = tid >> 3, c0 = (tid & 7) * 16;
        bool val = lr < nvalid;
        size_t gb = ((size_t)(b * TT + t0 + lr)) * IN + h * DHd + c0;
#pragma unroll
        for (int i = 0; i < 4; i++) {
            float4 q4 = val ? *(const float4*)(qq + gb + i * 4) : make_float4(0.f,0.f,0.f,0.f);
            ushort4v tq = {f2bf(q4.x), f2bf(q4.y), f2bf(q4.z), f2bf(q4.w)};
            *(ushort4v*)&sQ[lr * 136 + c0 + i * 4] = tq;
        }
    }
    // ---- stage sCB [128][136] from P[e][d]
    {
        const float* CBbase = P + (((size_t)(c * 32 + chain)) << 14);
        int e = tid >> 2, d0 = (tid & 3) * 32;
#pragma unroll
        for (int i = 0; i < 8; i++) {
            float4 c4 = *(const float4*)(CBbase + (size_t)e * 128 + d0 + i * 4);
            ushort4v tc = {f2bf(c4.x), f2bf(c4.y), f2bf(c4.z), f2bf(c4.w)};
            *(ushort4v*)&sCB[e * 136 + d0 + i * 4] = tc;
        }
    }
    __syncthreads();

    // ---- phase 0: inter = Q @ CB, C-layout acc; then scale by wr
    f32x4 acc[4];
#pragma unroll
    for (int tt = 0; tt < 4; tt++)
#pragma unroll
        for (int r = 0; r < 4; r++) acc[tt][r] = 0.f;
#pragma unroll 1
    for (int ks = 0; ks < 4; ks++) {
        bf16x8 af = *(const bf16x8*)&sQ[(mq * 16 + lrow) * 136 + ks * 32 + lquad * 8];
#pragma unroll
        for (int tt = 0; tt < 4; tt++) {
            bf16x8 bf = *(const bf16x8*)&sCB[(nh * 64 + tt * 16 + lrow) * 136 + ks * 32 + lquad * 8];
            acc[tt] = __builtin_amdgcn_mfma_f32_16x16x32_bf16(af, bf, acc[tt], 0, 0, 0);
        }
    }
#pragma unroll
    for (int tt = 0; tt < 4; tt++)
#pragma unroll
        for (int r = 0; r < 4; r++) acc[tt][r] *= sWr[mq * 16 + lquad * 4 + r];
    __syncthreads();

    // ---- stage sK (overlays sCB)
    {
        int lr = tid >> 3, c0 = (tid & 7) * 16;
        bool val = lr < nvalid;
        size_t gb = ((size_t)(b * TT + t0 + lr)) * IN + h * DHd + c0;
#pragma unroll
        for (int i = 0; i < 4; i++) {
            float4 k4 = val ? *(const float4*)(kk + gb + i * 4) : make_float4(0.f,0.f,0.f,0.f);
            ushort4v tk = {f2bf(k4.x), f2bf(k4.y), f2bf(k4.z), f2bf(k4.w)};
            *(ushort4v*)&sK[lr * 136 + c0 + i * 4] = tk;
        }
    }
    __syncthreads();

    // ---- phase 1: S = Q K^T (2 n-tiles/wave), weights, sD bf16, in-reg rowsums
    {
        f32x4 accS[2];
#pragma unroll
        for (int tt = 0; tt < 2; tt++)
#pragma unroll
            for (int r = 0; r < 4; r++) accS[tt][r] = 0.f;
#pragma unroll 1
        for (int ks = 0; ks < 4; ks++) {
            bf16x8 af = *(const bf16x8*)&sQ[(mq * 16 + lrow) * 136 + ks * 32 + lquad * 8];
#pragma unroll
            for (int tt = 0; tt < 2; tt++) {
                bf16x8 bf = *(const bf16x8*)&sK[((nh * 2 + tt) * 16 + lrow) * 136 + ks * 32 + lquad * 8];
                accS[tt] = __builtin_amdgcn_mfma_f32_16x16x32_bf16(af, bf, accS[tt], 0, 0, 0);
            }
        }
        float rsum[4] = {0.f, 0.f, 0.f, 0.f};
#pragma unroll
        for (int tt = 0; tt < 2; tt++) {
            int j = (nh * 2 + tt) * 16 + lrow;
            float Gj = sG[j];
#pragma unroll
            for (int r = 0; r < 4; r++) {
                int t = mq * 16 + lquad * 4 + r;
                float w = (j <= t) ? __expf(Gj - sM[t]) : 0.f;
                float wD = accS[tt][r] * w;
                rsum[r] += wD;
                sD[t * 72 + j] = f2bf(wD);
            }
        }
#pragma unroll
        for (int r = 0; r < 4; r++) {
#pragma unroll
            for (int msk = 1; msk < 16; msk <<= 1) rsum[r] += __shfl_xor(rsum[r], msk);
        }
        if (lrow == 0) {
#pragma unroll
            for (int r = 0; r < 4; r++) sRS[nh][mq * 16 + lquad * 4 + r] = rsum[r];
        }
    }
    __syncthreads();

    // ---- phase 2: denominators (tid<64); qnb from bf16 sQ
    if (tid < 64) {
        float qn = 0.f;
#pragma unroll 1
        for (int d4 = 0; d4 < 32; d4++) {
            ushort4v q4 = *(const ushort4v*)&sQ[tid * 136 + d4 * 4];
            float4 nb = *(const float4*)&sNb[d4 * 4];
            qn += bfu(q4.x) * nb.x + bfu(q4.y) * nb.y + bfu(q4.z) * nb.z + bfu(q4.w) * nb.w;
        }
        float den = sRS[0][tid] + sRS[1][tid] + sWr[tid] * qn;
        sInv[tid] = 1.f / fmaxf(fabsf(den), 1.f);
    }
    __syncthreads();

    // ---- stage sVt [128][72] = V^T bf16 (overlays sQ)
    {
        int e = tid & 127, tg = (tid >> 7) * 16;
#pragma unroll 1
        for (int i = 0; i < 16; i++) {
            int t = tg + i;
            float v = (t < nvalid) ? vv[((size_t)(b * TT + t0 + t)) * IN + h * DHd + e] : 0.f;
            sVt[e * 72 + t] = f2bf(v);
        }
    }
    __syncthreads();

    // ---- phase 3: acc += D @ V
#pragma unroll 1
    for (int ks = 0; ks < 2; ks++) {
        bf16x8 af = *(const bf16x8*)&sD[(mq * 16 + lrow) * 72 + ks * 32 + lquad * 8];
#pragma unroll
        for (int tt = 0; tt < 4; tt++) {
            bf16x8 bf = *(const bf16x8*)&sVt[(nh * 64 + tt * 16 + lrow) * 72 + ks * 32 + lquad * 8];
            acc[tt] = __builtin_amdgcn_mfma_f32_16x16x32_bf16(af, bf, acc[tt], 0, 0, 0);
        }
    }

    // ---- store (C-layout: col=lane&15 -> e, row=quad*4+r -> t)
#pragma unroll
    for (int tt = 0; tt < 4; tt++) {
#pragma unroll
        for (int r = 0; r < 4; r++) {
            int t = mq * 16 + lquad * 4 + r;
            if (t < nvalid) {
                int e = nh * 64 + tt * 16 + lrow;
                hs[((size_t)(b * TT + t0 + t)) * IN + h * DHd + e] = acc[tt][r] * sInv[t];
            }
        }
    }
}

// ---------------------------------------------------------------- per-head norm * hn_s * silu(z) -> bf16
__global__ __launch_bounds__(64) void headnorm_kernel(const float* __restrict__ hs,
                                                      const float* __restrict__ hn,
                                                      const float* __restrict__ up,
                                                      u16* __restrict__ out16) {
    int idx = blockIdx.x;
    int h = idx & 7, bt = idx >> 3;
    int tid = threadIdx.x;
    size_t base = (size_t)bt * IN + h * DHd;
    float x0 = hs[base + tid], x1 = hs[base + 64 + tid];
    float sum = x0 + x1, sq = x0 * x0 + x1 * x1;
#pragma unroll
    for (int o = 32; o > 0; o >>= 1) { sum += __shfl_xor(sum, o); sq += __shfl_xor(sq, o); }
    float mu = sum / DHd, var = sq / DHd - mu * mu, inv = rsqrtf(var + EPSV);
    size_t zb = (size_t)bt * (2 * IN) + IN + h * DHd;
    out16[base + tid]      = f2bf((x0 - mu) * inv * hn[h * DHd + tid]      * siluf(up[zb + tid]));
    out16[base + 64 + tid] = f2bf((x1 - mu) * inv * hn[h * DHd + 64 + tid] * siluf(up[zb + 64 + tid]));
}

// ---------------------------------------------------------------- head: LN+ReLU of cls rows -> vcls
__global__ __launch_bounds__(256) void cls_ln_kernel(const float* __restrict__ hbuf,
                                                     const float* __restrict__ s, const float* __restrict__ bb,
                                                     float* __restrict__ vcls) {
    int b = blockIdx.x, tid = threadIdx.x;
    const float* r = hbuf + ((size_t)b * TT + TT - 1) * Dm;
    __shared__ float s1[4], s2[4];
    float x0 = r[tid], x1 = r[tid + 256];
    float sum = x0 + x1, sq = x0 * x0 + x1 * x1;
#pragma unroll
    for (int o = 32; o > 0; o >>= 1) { sum += __shfl_xor(sum, o); sq += __shfl_xor(sq, o); }
    if ((tid & 63) == 0) { s1[tid >> 6] = sum; s2[tid >> 6] = sq; }
    __syncthreads();
    sum = s1[0] + s1[1] + s1[2] + s1[3];
    sq  = s2[0] + s2[1] + s2[2] + s2[3];
    float mu = sum / Dm, var = sq / Dm - mu * mu, inv = rsqrtf(var + EPSV);
    float n0 = (x0 - mu) * inv * s[tid] + bb[tid];
    float n1 = (x1 - mu) * inv * s[tid + 256] + bb[tid + 256];
    vcls[b * Dm + tid]       = fmaxf(n0, 0.f);
    vcls[b * Dm + tid + 256] = fmaxf(n1, 0.f);
}

// ---------------------------------------------------------------- head: FC
__global__ __launch_bounds__(256) void fc_kernel(const float* __restrict__ vcls,
                                                 const float* __restrict__ fw,
                                                 const float* __restrict__ fb,
                                                 float* __restrict__ out) {
    __shared__ float svc[Bsz][Dm];
    __shared__ float sred[4][256];
    int tid = threadIdx.x;
    int j0 = blockIdx.x * 64;
    {
        const float4* src = (const float4*)vcls;
        float4* dst = (float4*)&svc[0][0];
        dst[tid] = src[tid];
        dst[tid + 256] = src[tid + 256];
    }
    __syncthreads();
    int j = j0 + (tid & 63);
    int chunk = tid >> 6;
    int kbase = chunk * 128;
    float a0 = 0.f, a1 = 0.f, a2 = 0.f, a3 = 0.f;
    if (j < NCc) {
        const float* fwp = fw + (size_t)kbase * NCc + j;
#pragma unroll 4
        for (int kk = 0; kk < 128; kk++) {
            float w = fwp[(size_t)kk * NCc];
            a0 += svc[0][kbase + kk] * w;
            a1 += svc[1][kbase + kk] * w;
            a2 += svc[2][kbase + kk] * w;
            a3 += svc[3][kbase + kk] * w;
        }
    }
    int jl = tid & 63;
    sred[chunk][jl * 4 + 0] = a0;
    sred[chunk][jl * 4 + 1] = a1;
    sred[chunk][jl * 4 + 2] = a2;
    sred[chunk][jl * 4 + 3] = a3;
    __syncthreads();
    if (tid < 64) {
        int jj = j0 + tid;
        if (jj < NCc) {
            float bias = fb[jj];
#pragma unroll
            for (int b = 0; b < Bsz; b++) {
                float v = sred[0][tid * 4 + b] + sred[1][tid * 4 + b]
                        + sred[2][tid * 4 + b] + sred[3][tid * 4 + b];
                out[b * NCc + jj] = v + bias;
            }
        }
    }
}

// ---------------------------------------------------------------- launch
extern "C" void kernel_launch(void* const* d_in, const int* in_sizes, int n_in,
                              void* d_out, int out_size, void* d_ws, size_t ws_size,
                              hipStream_t stream) {
    const float* x      = (const float*)d_in[0];
    const float* cls    = (const float*)d_in[1];
    const float* ln_s   = (const float*)d_in[2];
    const float* ln_b   = (const float*)d_in[3];
    const float* w_up   = (const float*)d_in[4];
    const float* b_up   = (const float*)d_in[5];
    const float* conv_k = (const float*)d_in[6];
    const float* conv_b = (const float*)d_in[7];
    const float* w_q    = (const float*)d_in[8];
    const float* w_k    = (const float*)d_in[9];
    const float* w_v    = (const float*)d_in[10];
    const float* w_ig   = (const float*)d_in[11];
    const float* b_ig   = (const float*)d_in[12];
    const float* w_fg   = (const float*)d_in[13];
    const float* b_fg   = (const float*)d_in[14];
    const float* hn_s   = (const float*)d_in[15];
    const float* w_down = (const float*)d_in[16];
    const float* b_down = (const float*)d_in[17];
    const float* fcls   = (const float*)d_in[18];
    const float* fclb   = (const float*)d_in[19];
    const float* fc_w   = (const float*)d_in[20];
    const float* fc_b   = (const float*)d_in[21];
    float* out = (float*)d_out;

    float* ws = (float*)d_ws;
    size_t off = 0;
    float* f_h  = ws + off; off += (size_t)ROWS * Dm;
    float* f_up = ws + off; off += (size_t)ROWS * 2 * IN;
    float* f_xc = ws + off; off += (size_t)ROWS * IN;
    float* f_q  = ws + off; off += (size_t)ROWS * IN;
    float* f_k  = ws + off; off += (size_t)ROWS * IN;
    float* f_v  = ws + off; off += (size_t)ROWS * IN;
    float* f_hs = ws + off; off += (size_t)ROWS * IN;
    float* f_ip = ws + off; off += (size_t)ROWS * NHh;
    float* f_fp = ws + off; off += (size_t)ROWS * NHh;
    float* g_G  = ws + off; off += 32 * TT;
    float* g_M  = ws + off; off += 32 * TT;
    float* g_Mb = ws + off; off += 32 * NCH;
    float* g_De = ws + off; off += 32 * NCH;
    float* g_P  = ws + off; off += (size_t)NCH * 32 * DHd * DHd;
    float* g_nP = ws + off; off += (size_t)NCH * 32 * DHd;
    float* f_vc = ws + off; off += Bsz * Dm;
    float* g_wt = ws + off; off += 2 * 16 * IN;
    u16* g_Wt  = (u16*)(ws + off); off += (2 * WT_STRIDE + 1) / 2;
    // padded bf16 staging (MPAD rows; pad rows read as garbage, outputs guarded)
    u16* f_xn16 = (u16*)(ws + off); off += ((size_t)MPAD * Dm) / 2;
    u16* f_xc16 = (u16*)(ws + off); off += ((size_t)MPAD * IN) / 2;
    u16* f_xu16 = (u16*)(ws + off); off += ((size_t)MPAD * IN) / 2;
    u16* f_xg16 = (u16*)(ws + off); off += ((size_t)ROWS * IN + 1) / 2;

    const float kscale = 0.08838834764831845f; // DH^-0.5
    const int MB = (ROWS + 127) / 128;         // 17
    const int MB64 = (ROWS + 63) / 64;         // 33

    concat_kernel<<<(ROWS * Dm + 255) / 256, 256, 0, stream>>>(x, cls, f_h);
    gate_w_transpose<<<(2 * 16 * IN + 255) / 256, 256, 0, stream>>>(w_ig, w_fg, g_wt);
    w_transpose_kernel<<<dim3(1024, 10), 256, 0, stream>>>(w_up, w_q, w_k, w_v, w_down, g_Wt);

    for (int blk = 0; blk < 2; blk++) {
        const float* p_ln_s = ln_s + blk * Dm;
        const float* p_ln_b = ln_b + blk * Dm;
        const float* p_bup  = b_up + (size_t)blk * 2 * IN;
        const float* p_ck   = conv_k + (size_t)blk * IN * KK;
        const float* p_cb   = conv_b + (size_t)blk * IN;
        const float* p_big  = b_ig + (size_t)blk * NHh;
        const float* p_bfg  = b_fg + (size_t)blk * NHh;
        const float* p_hns  = hn_s + (size_t)blk * NHh * DHd;
        const float* p_bd   = b_down + (size_t)blk * Dm;
        const u16*   p_wt   = g_Wt + (size_t)blk * WT_STRIDE;

        ln_kernel<<<ROWS, 256, 0, stream>>>(f_h, p_ln_s, p_ln_b, f_xn16);

        up_gl_kernel<<<dim3(2 * IN / 128, MB), 256, 0, stream>>>(
            f_xn16, p_wt + WT_UP, p_bup, f_up);

        conv_silu_kernel<<<(ROWS * IN + 255) / 256, 256, 0, stream>>>(
            f_up, p_ck, p_cb, f_xc, f_xc16, f_xu16);

        qkv_gl_kernel<<<dim3(24, MB), 256, 0, stream>>>(
            f_xc16, f_xu16, p_wt, f_q, f_k, f_v, kscale);

        gates_kernel<<<ROWS, 256, 0, stream>>>(f_xc, g_wt + blk * 16 * IN, p_big, p_bfg,
                                               f_ip, f_fp);

        // chunkwise-parallel mLSTM
        gate_scan_kernel<<<32, 64, 0, stream>>>(f_ip, f_fp, g_G, g_M, g_Mb, g_De);
        chunk_state_kernel<<<dim3(NCH, 32), 256, 0, stream>>>(f_k, f_v, g_G, g_Mb, g_P, g_nP);
        chunk_combine_kernel<<<32 * 64, 256, 0, stream>>>(g_P, g_De);
        n_combine_kernel<<<16, 256, 0, stream>>>(g_nP, g_De);
        chunk_out_kernel<<<dim3(NCH, 32), 512, 0, stream>>>(f_q, f_k, f_v, g_G, g_M, g_Mb,
                                                            g_P, g_nP, f_hs);

        headnorm_kernel<<<ROWS * NHh, 64, 0, stream>>>(f_hs, p_hns, f_up, f_xg16);

        gemm_mfma_kernel<64, 64><<<dim3(Dm / 64, MB64), 256, 0, stream>>>(
            f_xg16, IN, p_wt + WT_DN, IN, p_bd, f_h, Dm, f_h, Dm, ROWS, 1.f);
    }

    cls_ln_kernel<<<Bsz, 256, 0, stream>>>(f_h, fcls, fclb, f_vc);
    fc_kernel<<<(NCc + 63) / 64, 256, 0, stream>>>(f_vc, fc_w, fc_b, out);
}

// Round 3
// 435.371 us; speedup vs baseline: 1.1970x; 1.0374x over previous
//
#include <hip/hip_runtime.h>

// ---------------------------------------------------------------- constants
#define EPSV 1e-5f
constexpr int Bsz = 4, T0 = 512, Dm = 512, TT = 513, NHh = 8, KK = 4;
constexpr int IN = 1024, DHd = 128, NCc = 1000;
constexpr int ROWS = Bsz * TT; // 2052
constexpr int MPAD = 2176;     // 17*128 padded staging rows for gload GEMMs
constexpr int NCH = 9;         // chunks of 64: 8*64 + 1 = 513

// bf16 k-major weight buffer offsets (u16 elements), per transformer block
constexpr size_t WT_UP = 0;                      // [2048][512]
constexpr size_t WT_Q  = WT_UP + 2048 * 512;     // [1024][1024]
constexpr size_t WT_K  = WT_Q + 1024 * 1024;
constexpr size_t WT_V  = WT_K + 1024 * 1024;
constexpr size_t WT_DN = WT_V + 1024 * 1024;     // [512][1024]
constexpr size_t WT_STRIDE = WT_DN + 512 * 1024; // 4,718,592 u16

typedef __attribute__((ext_vector_type(8))) short bf16x8;
typedef __attribute__((ext_vector_type(4))) float f32x4;
typedef __attribute__((ext_vector_type(4))) unsigned short ushort4v;
typedef __attribute__((ext_vector_type(8))) unsigned short ushort8v;
typedef unsigned short u16;

__device__ __forceinline__ float siluf(float x) { return x / (1.f + __expf(-x)); }
__device__ __forceinline__ u16 f2bf(float f) {
    unsigned int u = __float_as_uint(f);
    u = (u + 0x7FFFu + ((u >> 16) & 1u)) >> 16;
    return (u16)u;
}
__device__ __forceinline__ float bfu(u16 u) {
    return __uint_as_float(((unsigned int)u) << 16);
}
// async global->LDS, 16 bytes per lane; LDS dest is wave-uniform base + lane*16
__device__ __forceinline__ void gload16(const u16* g, u16* l) {
    __builtin_amdgcn_global_load_lds(
        (const __attribute__((address_space(1))) void*)g,
        (__attribute__((address_space(3))) void*)l, 16, 0, 0);
}

// ---------------------------------------------------------------- concat x + cls
__global__ __launch_bounds__(256) void concat_kernel(const float* __restrict__ x,
                                                     const float* __restrict__ cls,
                                                     float* __restrict__ h) {
    int idx = blockIdx.x * 256 + threadIdx.x;
    if (idx >= Bsz * TT * Dm) return;
    int d = idx & (Dm - 1);
    int bt = idx >> 9;
    int t = bt % TT, b = bt / TT;
    h[idx] = (t < T0) ? x[((size_t)(b * T0 + t)) * Dm + d] : cls[d];
}

// ---------------------------------------------------------------- LayerNorm rows of D=512 -> bf16
__global__ __launch_bounds__(256) void ln_kernel(const float* __restrict__ in,
                                                 const float* __restrict__ s,
                                                 const float* __restrict__ bb,
                                                 u16* __restrict__ out16) {
    int row = blockIdx.x, tid = threadIdx.x;
    const float* r = in + (size_t)row * Dm;
    __shared__ float s1[4], s2[4];
    float x0 = r[tid], x1 = r[tid + 256];
    float sum = x0 + x1, sq = x0 * x0 + x1 * x1;
#pragma unroll
    for (int o = 32; o > 0; o >>= 1) { sum += __shfl_xor(sum, o); sq += __shfl_xor(sq, o); }
    if ((tid & 63) == 0) { s1[tid >> 6] = sum; s2[tid >> 6] = sq; }
    __syncthreads();
    sum = s1[0] + s1[1] + s1[2] + s1[3];
    sq  = s2[0] + s2[1] + s2[2] + s2[3];
    float mu = sum / Dm, var = sq / Dm - mu * mu, inv = rsqrtf(var + EPSV);
    out16[(size_t)row * Dm + tid]       = f2bf((x0 - mu) * inv * s[tid] + bb[tid]);
    out16[(size_t)row * Dm + tid + 256] = f2bf((x1 - mu) * inv * s[tid + 256] + bb[tid + 256]);
}

// ---------------------------------------------------------------- weight transpose f32 KxN -> bf16 [N][K]
__global__ __launch_bounds__(256) void w_transpose_kernel(const float* __restrict__ wup,
        const float* __restrict__ wq, const float* __restrict__ wk,
        const float* __restrict__ wv, const float* __restrict__ wdn,
        u16* __restrict__ wt) {
    int y = blockIdx.y;             // 0..9
    int blk = y / 5, sel = y - blk * 5;
    int Kd, N; const float* src; size_t doff;
    if (sel == 0)      { Kd = 512;  N = 2048; src = wup + (size_t)blk * 512 * 2048; doff = WT_UP; }
    else if (sel == 1) { Kd = 1024; N = 1024; src = wq  + (size_t)blk * 1024 * 1024; doff = WT_Q; }
    else if (sel == 2) { Kd = 1024; N = 1024; src = wk  + (size_t)blk * 1024 * 1024; doff = WT_K; }
    else if (sel == 3) { Kd = 1024; N = 1024; src = wv  + (size_t)blk * 1024 * 1024; doff = WT_V; }
    else               { Kd = 1024; N = 512;  src = wdn + (size_t)blk * 1024 * 512;  doff = WT_DN; }
    u16* dst = wt + (size_t)blk * WT_STRIDE + doff;
    int ntx = N >> 5;
    int ntiles = ntx * (Kd >> 5);
    int ti = blockIdx.x;
    if (ti >= ntiles) return;
    int tk = ti / ntx, tn = ti - tk * ntx;
    __shared__ u16 s[32][33];
    int tx = threadIdx.x & 31, ty = threadIdx.x >> 5;
#pragma unroll
    for (int i = 0; i < 4; i++) {
        int k = tk * 32 + ty + i * 8;
        s[ty + i * 8][tx] = f2bf(src[(size_t)k * N + tn * 32 + tx]);
    }
    __syncthreads();
#pragma unroll
    for (int i = 0; i < 4; i++) {
        int n = tn * 32 + ty + i * 8;
        dst[(size_t)n * Kd + tk * 32 + tx] = s[tx][ty + i * 8];
    }
}

// ---------------------------------------------------------------- legacy MFMA GEMM (down-proj)
template<int BM, int BN>
__device__ __forceinline__ void gemm_tile_body(const u16* __restrict__ A, int lda,
                                               const u16* __restrict__ Wt, int Kd,
                                               const float* __restrict__ bias,
                                               const float* __restrict__ resid, int ldr,
                                               float* __restrict__ Cout, int ldc,
                                               int M, float scale, int m0, int n0,
                                               u16 (*As)[BM][40], u16 (*Bs)[BN][40]) {
    constexpr int MT = BM / 32;
    constexpr int NT = BN / 32;
    constexpr int ANV = BM / 64;           // ushort8 A-loads per thread
    constexpr int BNV = BN / 64;           // ushort8 B-loads per thread
    int tid = threadIdx.x;
    int wave = tid >> 6, lane = tid & 63;
    int wm = (wave >> 1) * (BM / 2), wn = (wave & 1) * (BN / 2);
    int lrow = lane & 15, lquad = lane >> 4;

    f32x4 acc[MT][NT];
#pragma unroll
    for (int i = 0; i < MT; i++)
#pragma unroll
        for (int j = 0; j < NT; j++)
#pragma unroll
            for (int r = 0; r < 4; r++) acc[i][j][r] = 0.f;

    int am, ak, bn, bk;
    if (BM == 128) { am = tid >> 1; ak = (tid & 1) * 16; }
    else           { am = tid >> 2; ak = (tid & 3) * 8; }
    if (BN == 128) { bn = tid & 127; bk = (tid >> 7) * 16; }
    else           { bn = tid & 63;  bk = (tid >> 6) * 8; }
    int gm = m0 + am;
    const u16* arow = A + (size_t)(gm < M ? gm : 0) * lda + ak;
    bool avalid = gm < M;
    const u16* wrow = Wt + (size_t)(n0 + bn) * Kd + bk;

    ushort8v areg[ANV];
    ushort8v breg[BNV];

    auto load_tile = [&](int k0) {
        if (avalid) {
#pragma unroll
            for (int i = 0; i < ANV; i++) areg[i] = *(const ushort8v*)(arow + k0 + i * 8);
        } else {
#pragma unroll
            for (int i = 0; i < ANV; i++) areg[i] = (ushort8v){0,0,0,0,0,0,0,0};
        }
#pragma unroll
        for (int i = 0; i < BNV; i++) breg[i] = *(const ushort8v*)(wrow + k0 + i * 8);
    };
    auto store_tile = [&](int buf) {
#pragma unroll
        for (int i = 0; i < ANV; i++)
            *(ushort8v*)&As[buf][am][ak + i * 8] = areg[i];
#pragma unroll
        for (int i = 0; i < BNV; i++)
            *(ushort8v*)&Bs[buf][bn][bk + i * 8] = breg[i];
    };

    load_tile(0);
    store_tile(0);
    __syncthreads();

    int nk = Kd >> 5;
#pragma unroll 1
    for (int it = 0; it < nk; it++) {
        int cur = it & 1;
        bool more = (it + 1 < nk);
        if (more) load_tile((it + 1) << 5);
        bf16x8 afr[MT], bfr[NT];
#pragma unroll
        for (int mt = 0; mt < MT; mt++)
            afr[mt] = *(const bf16x8*)&As[cur][wm + mt * 16 + lrow][lquad * 8];
#pragma unroll
        for (int nt = 0; nt < NT; nt++)
            bfr[nt] = *(const bf16x8*)&Bs[cur][wn + nt * 16 + lrow][lquad * 8];
#pragma unroll
        for (int mt = 0; mt < MT; mt++)
#pragma unroll
            for (int nt = 0; nt < NT; nt++)
                acc[mt][nt] = __builtin_amdgcn_mfma_f32_16x16x32_bf16(
                    afr[mt], bfr[nt], acc[mt][nt], 0, 0, 0);
        if (more) store_tile(cur ^ 1);
        __syncthreads();
    }

#pragma unroll
    for (int mt = 0; mt < MT; mt++) {
#pragma unroll
        for (int r = 0; r < 4; r++) {
            int gmr = m0 + wm + mt * 16 + lquad * 4 + r;
            if (gmr >= M) continue;
#pragma unroll
            for (int nt = 0; nt < NT; nt++) {
                int gn = n0 + wn + nt * 16 + lrow;
                float v = acc[mt][nt][r] * scale;
                if (bias) v += bias[gn];
                if (resid) v += resid[(size_t)gmr * ldr + gn];
                Cout[(size_t)gmr * ldc + gn] = v;
            }
        }
    }
}

template<int BM, int BN>
__global__ __launch_bounds__(256, 2) void gemm_mfma_kernel(const u16* __restrict__ A, int lda,
                                                           const u16* __restrict__ Wt, int Kd,
                                                           const float* __restrict__ bias,
                                                           const float* __restrict__ resid, int ldr,
                                                           float* __restrict__ Cout, int ldc,
                                                           int M, float scale) {
    __shared__ __align__(16) u16 As[2][BM][40];
    __shared__ __align__(16) u16 Bs[2][BN][40];
    gemm_tile_body<BM, BN>(A, lda, Wt, Kd, bias, resid, ldr, Cout, ldc, M, scale,
                           blockIdx.y * BM, blockIdx.x * BN, As, Bs);
}

// ---------------------------------------------------------------- m97-style 128x128 gload GEMM
__device__ __forceinline__ void gemm128_body(const u16* __restrict__ A, int lda,
                                             const u16* __restrict__ Wt, int Kd,
                                             const float* __restrict__ bias,
                                             float* __restrict__ Cout, int ldc,
                                             int M, float scale, int m0, int n0,
                                             u16* As, u16* Bs) {
    int tid = threadIdx.x;
    int wave = tid >> 6, lane = tid & 63;
    int lrow = lane & 15, lquad = lane >> 4;
    int wm = (wave >> 1) * 64, wn = (wave & 1) * 64;

    const u16* ag0 = A + (size_t)(m0 + wave * 16 + (lane >> 2)) * lda + (lane & 3) * 8;
    const u16* ag1 = ag0 + (size_t)64 * lda;
    const u16* bg0 = Wt + (size_t)(n0 + wave * 16 + (lane >> 2)) * Kd + (lane & 3) * 8;
    const u16* bg1 = bg0 + (size_t)64 * Kd;
    u16* la0 = As + wave * 512;
    u16* la1 = As + 2048 + wave * 512;
    u16* lb0 = Bs + wave * 512;
    u16* lb1 = Bs + 2048 + wave * 512;

    f32x4 acc[4][4];
#pragma unroll
    for (int i = 0; i < 4; i++)
#pragma unroll
        for (int j = 0; j < 4; j++)
#pragma unroll
            for (int r = 0; r < 4; r++) acc[i][j][r] = 0.f;

    int nk = Kd >> 5;
#pragma unroll 1
    for (int it = 0; it < nk; it++) {
        int k0 = it << 5;
        gload16(ag0 + k0, la0);
        gload16(ag1 + k0, la1);
        gload16(bg0 + k0, lb0);
        gload16(bg1 + k0, lb1);
        __syncthreads();
        bf16x8 afr[4], bfr[4];
#pragma unroll
        for (int mt = 0; mt < 4; mt++)
            afr[mt] = *(const bf16x8*)&As[(wm + mt * 16 + lrow) * 32 + lquad * 8];
#pragma unroll
        for (int nt = 0; nt < 4; nt++)
            bfr[nt] = *(const bf16x8*)&Bs[(wn + nt * 16 + lrow) * 32 + lquad * 8];
#pragma unroll
        for (int mt = 0; mt < 4; mt++)
#pragma unroll
            for (int nt = 0; nt < 4; nt++)
                acc[mt][nt] = __builtin_amdgcn_mfma_f32_16x16x32_bf16(
                    afr[mt], bfr[nt], acc[mt][nt], 0, 0, 0);
        __syncthreads();
    }

#pragma unroll
    for (int mt = 0; mt < 4; mt++) {
#pragma unroll
        for (int r = 0; r < 4; r++) {
            int gmr = m0 + wm + mt * 16 + lquad * 4 + r;
            if (gmr >= M) continue;
#pragma unroll
            for (int nt = 0; nt < 4; nt++) {
                int gn = n0 + wn + nt * 16 + lrow;
                float v = acc[mt][nt][r] * scale;
                if (bias) v += bias[gn];
                Cout[(size_t)gmr * ldc + gn] = v;
            }
        }
    }
}

__global__ __launch_bounds__(256, 2) void up_gl_kernel(const u16* __restrict__ A,
        const u16* __restrict__ Wt, const float* __restrict__ bias, float* __restrict__ C) {
    __shared__ __align__(16) u16 As[128 * 32];
    __shared__ __align__(16) u16 Bs[128 * 32];
    gemm128_body(A, Dm, Wt, Dm, bias, C, 2 * IN, ROWS, 1.f,
                 blockIdx.y * 128, blockIdx.x * 128, As, Bs);
}

__global__ __launch_bounds__(256, 2) void qkv_gl_kernel(const u16* __restrict__ xc16,
                                                        const u16* __restrict__ xu16,
                                                        const u16* __restrict__ wtblk,
                                                        float* __restrict__ fq,
                                                        float* __restrict__ fk,
                                                        float* __restrict__ fv,
                                                        float kscale) {
    __shared__ __align__(16) u16 As[128 * 32];
    __shared__ __align__(16) u16 Bs[128 * 32];
    int sel = blockIdx.x >> 3, nx = blockIdx.x & 7;
    const u16* A = (sel == 2) ? xu16 : xc16;
    const u16* Wt = wtblk + ((sel == 0) ? WT_Q : (sel == 1) ? WT_K : WT_V);
    float* C = (sel == 0) ? fq : (sel == 1) ? fk : fv;
    float scale = (sel == 1) ? kscale : 1.f;
    gemm128_body(A, IN, Wt, IN, nullptr, C, IN, ROWS, scale,
                 blockIdx.y * 128, nx * 128, As, Bs);
}

// ---------------------------------------------------------------- fused causal conv + SiLU + gate projections
// One block per row. Conv into LDS, then the 16 gate dot products.
__global__ __launch_bounds__(256) void convgates_kernel(const float* __restrict__ up,
        const float* __restrict__ ck, const float* __restrict__ cb,
        const float* __restrict__ wt, const float* __restrict__ big,
        const float* __restrict__ bfg,
        u16* __restrict__ xc16, u16* __restrict__ xu16,
        float* __restrict__ ip, float* __restrict__ fp) {
    int row = blockIdx.x, tid = threadIdx.x;
    int b = row / TT, t = row - b * TT;
    __shared__ float sx[IN];
    int c0 = tid * 4;
    float4 cur = *(const float4*)(up + (size_t)row * (2 * IN) + c0);
    float a0 = cb[c0 + 0] + cur.x * ck[(c0 + 0) * KK + 3];
    float a1 = cb[c0 + 1] + cur.y * ck[(c0 + 1) * KK + 3];
    float a2 = cb[c0 + 2] + cur.z * ck[(c0 + 2) * KK + 3];
    float a3 = cb[c0 + 3] + cur.w * ck[(c0 + 3) * KK + 3];
#pragma unroll
    for (int j = 0; j < KK - 1; j++) {
        int tt2 = t - (KK - 1) + j;
        if (tt2 >= 0) {
            float4 pv = *(const float4*)(up + ((size_t)(b * TT + tt2)) * (2 * IN) + c0);
            a0 += pv.x * ck[(c0 + 0) * KK + j];
            a1 += pv.y * ck[(c0 + 1) * KK + j];
            a2 += pv.z * ck[(c0 + 2) * KK + j];
            a3 += pv.w * ck[(c0 + 3) * KK + j];
        }
    }
    float s0 = siluf(a0), s1v = siluf(a1), s2v = siluf(a2), s3v = siluf(a3);
    *(float4*)&sx[c0] = make_float4(s0, s1v, s2v, s3v);
    ushort4v xc4 = {f2bf(s0), f2bf(s1v), f2bf(s2v), f2bf(s3v)};
    *(ushort4v*)&xc16[(size_t)row * IN + c0] = xc4;
    ushort4v xu4 = {f2bf(cur.x), f2bf(cur.y), f2bf(cur.z), f2bf(cur.w)};
    *(ushort4v*)&xu16[(size_t)row * IN + c0] = xu4;
    __syncthreads();

    int g = tid >> 4, l = tid & 15;
    const float* wrow = wt + g * IN;
    float acc = 0.f;
#pragma unroll
    for (int j = 0; j < 16; j++) {
        int k = j * 64 + l * 4;
        float4 w4 = *(const float4*)(wrow + k);
        float4 x4 = *(const float4*)&sx[k];
        acc += w4.x * x4.x + w4.y * x4.y + w4.z * x4.z + w4.w * x4.w;
    }
#pragma unroll
    for (int o = 8; o > 0; o >>= 1) acc += __shfl_down(acc, o, 16);
    if (l == 0) {
        if (g < 8) ip[(size_t)row * NHh + g] = acc + big[g];
        else       fp[(size_t)row * NHh + (g - 8)] = acc + bfg[g - 8];
    }
}

// ---------------------------------------------------------------- chunkwise mLSTM
__global__ __launch_bounds__(64) void gate_scan_kernel(const float* __restrict__ ip,
        const float* __restrict__ fp, float* __restrict__ gG, float* __restrict__ gM,
        float* __restrict__ gMb, float* __restrict__ gDec) {
    constexpr int PER = 9;
    int chain = blockIdx.x;
    int b = chain >> 3, h = chain & 7;
    int lane = threadIdx.x;
    int tbase = lane * PER;
    float lcs[PER];
    float gi[PER];
    float csum = 0.f;
#pragma unroll
    for (int i = 0; i < PER; i++) {
        int t = tbase + i;
        float fpv = 0.f, ipv = 0.f;
        if (t < TT) {
            size_t gidx = (size_t)(b * TT + t) * NHh + h;
            fpv = fp[gidx]; ipv = ip[gidx];
        }
        float flv = (fpv >= 0.f) ? -log1pf(__expf(-fpv)) : (fpv - log1pf(__expf(fpv)));
        if (t >= TT) flv = 0.f;
        csum += flv;
        lcs[i] = csum;
        gi[i] = ipv;
    }
    float ps = csum;
#pragma unroll
    for (int o = 1; o < 64; o <<= 1) {
        float v = __shfl_up(ps, o);
        if (lane >= o) ps += v;
    }
    float Fexcl = ps - csum;
    float G[PER];
    float cmax = -1e30f;
#pragma unroll
    for (int i = 0; i < PER; i++) {
        int t = tbase + i;
        G[i] = (t < TT) ? (gi[i] - (Fexcl + lcs[i])) : -1e30f;
        cmax = fmaxf(cmax, G[i]);
        lcs[i] = cmax;
    }
    float pm = cmax;
#pragma unroll
    for (int o = 1; o < 64; o <<= 1) {
        float v = __shfl_up(pm, o);
        if (lane >= o) pm = fmaxf(pm, v);
    }
    float Me = __shfl_up(pm, 1);
    if (lane == 0) Me = -1e30f;
    __shared__ float sMb[NCH];
#pragma unroll
    for (int i = 0; i < PER; i++) {
        int t = tbase + i;
        if (t < TT) {
            float Mt = fmaxf(0.f, fmaxf(Me, lcs[i]));
            gG[chain * TT + t] = G[i];
            gM[chain * TT + t] = Mt;
            if (((t & 63) == 63) || t == TT - 1) sMb[t >> 6] = Mt;
        }
    }
    __syncthreads();
    if (lane < NCH) {
        float Mb = sMb[lane];
        float Mbp = (lane == 0) ? 0.f : sMb[lane - 1];
        gMb[chain * NCH + lane] = Mb;
        gDec[chain * NCH + lane] = __expf(Mbp - Mb);
    }
}

// Kernel B1: per-chunk local state via MFMA. P stored [e][d] (e-major).
__global__ __launch_bounds__(256, 2) void chunk_state_kernel(const float* __restrict__ kk,
        const float* __restrict__ vv, const float* __restrict__ gG,
        const float* __restrict__ gMb, float* __restrict__ P, float* __restrict__ nP) {
    int c = blockIdx.x, chain = blockIdx.y;
    int b = chain >> 3, h = chain & 7;
    int t0 = c * 64;
    int nvalid = min(64, TT - t0);
    __shared__ __align__(16) u16 sWv[128][72];   // [e][j] = w_j * V[j][e]
    __shared__ __align__(16) u16 sKt[128][72];   // [d][j] = K[j][d]
    __shared__ float sw[64];
    int tid = threadIdx.x;
    if (tid < 64) {
        float Mb = gMb[chain * NCH + c];
        sw[tid] = (tid < nvalid) ? __expf(gG[chain * TT + t0 + tid] - Mb) : 0.f;
    }
    __syncthreads();

    {
        int j = tid >> 2, d0 = (tid & 3) * 32;
        bool val = j < nvalid;
        float wj = sw[j];
        size_t gb = ((size_t)(b * TT + t0 + j)) * IN + h * DHd + d0;
#pragma unroll
        for (int i = 0; i < 8; i++) {
            float4 k4 = val ? *(const float4*)(kk + gb + i * 4) : make_float4(0.f, 0.f, 0.f, 0.f);
            float4 v4 = val ? *(const float4*)(vv + gb + i * 4) : make_float4(0.f, 0.f, 0.f, 0.f);
            int dd = d0 + i * 4;
            int jc = j ^ (((dd >> 5) & 3) << 4);       // column swizzle
            sKt[dd + 0][jc] = f2bf(k4.x);
            sKt[dd + 1][jc] = f2bf(k4.y);
            sKt[dd + 2][jc] = f2bf(k4.z);
            sKt[dd + 3][jc] = f2bf(k4.w);
            sWv[dd + 0][jc] = f2bf(v4.x * wj);
            sWv[dd + 1][jc] = f2bf(v4.y * wj);
            sWv[dd + 2][jc] = f2bf(v4.z * wj);
            sWv[dd + 3][jc] = f2bf(v4.w * wj);
        }
    }
    __syncthreads();

    int wave = tid >> 6, lane = tid & 63;
    int lrow = lane & 15, lquad = lane >> 4;
    int wm = (wave >> 1) * 64, wn = (wave & 1) * 64;
    f32x4 acc[4][4];
#pragma unroll
    for (int mt = 0; mt < 4; mt++)
#pragma unroll
        for (int nt = 0; nt < 4; nt++)
#pragma unroll
            for (int r = 0; r < 4; r++) acc[mt][nt][r] = 0.f;

#pragma unroll
    for (int ks = 0; ks < 2; ks++) {
        bf16x8 af[4], bfr[4];
#pragma unroll
        for (int mt = 0; mt < 4; mt++) {
            int r = wm + mt * 16 + lrow;
            int g = (ks * 4 + lquad) ^ (((r >> 5) & 3) << 1);
            af[mt] = *(const bf16x8*)&sWv[r][g * 8];
        }
#pragma unroll
        for (int nt = 0; nt < 4; nt++) {
            int r = wn + nt * 16 + lrow;
            int g = (ks * 4 + lquad) ^ (((r >> 5) & 3) << 1);
            bfr[nt] = *(const bf16x8*)&sKt[r][g * 8];
        }
#pragma unroll
        for (int mt = 0; mt < 4; mt++)
#pragma unroll
            for (int nt = 0; nt < 4; nt++)
                acc[mt][nt] = __builtin_amdgcn_mfma_f32_16x16x32_bf16(
                    af[mt], bfr[nt], acc[mt][nt], 0, 0, 0);
    }

    float* Pbase = P + (((size_t)(c * 32 + chain)) << 14);
#pragma unroll
    for (int mt = 0; mt < 4; mt++)
#pragma unroll
        for (int r = 0; r < 4; r++) {
            int e = wm + mt * 16 + lquad * 4 + r;
#pragma unroll
            for (int nt = 0; nt < 4; nt++) {
                int d = wn + nt * 16 + lrow;
                Pbase[(size_t)e * 128 + d] = acc[mt][nt][r];
            }
        }

    {
        int d = tid >> 1, jh = (tid & 1) * 32;
        int swz = ((d >> 5) & 3) << 4;
        float an = 0.f;
#pragma unroll
        for (int j = 0; j < 32; j++) {
            int jj = jh + j;
            an += sw[jj] * bfu(sKt[d][jj ^ swz]);
        }
        an += __shfl_xor(an, 1);
        if ((tid & 1) == 0) nP[(size_t)(c * 32 + chain) * 128 + d] = an;
    }
}

// Kernel B2: exclusive combine over chunks -> bf16 CB; also nP scan (seg 0 blocks).
__global__ __launch_bounds__(256) void chunk_combine_kernel(const float* __restrict__ P,
        u16* __restrict__ CB, float* __restrict__ nP, const float* __restrict__ gDec) {
    int chain = blockIdx.x >> 6;
    int seg = blockIdx.x & 63;
    int idx = seg * 256 + threadIdx.x;
    float run = 0.f;
    for (int c = 0; c < NCH; c++) {
        size_t a = (((size_t)(c * 32 + chain)) << 14) + idx;
        float tmp = P[a];
        CB[a] = f2bf(run);
        run = run * gDec[chain * NCH + c] + tmp;
    }
    if (seg == 0 && threadIdx.x < 128) {
        int d = threadIdx.x;
        float rn = 0.f;
        for (int c = 0; c < NCH; c++) {
            size_t a = (size_t)(c * 32 + chain) * 128 + d;
            float tmp = nP[a];
            nP[a] = rn;
            rn = rn * gDec[chain * NCH + c] + tmp;
        }
    }
}

// Kernel C: MFMA chunk outputs + fused per-head norm * hn_s * silu(z) -> bf16.
__global__ __launch_bounds__(512, 2) void chunk_out_kernel(const float* __restrict__ qq,
        const float* __restrict__ kk, const float* __restrict__ vv,
        const float* __restrict__ gG, const float* __restrict__ gM,
        const float* __restrict__ gMb, const u16* __restrict__ CB,
        const float* __restrict__ nP, const float* __restrict__ hn,
        const float* __restrict__ up, u16* __restrict__ out16) {
    int c = blockIdx.x, chain = blockIdx.y;
    int b = chain >> 3, h = chain & 7;
    int t0 = c * 64;
    int nvalid = min(64, TT - t0);
    __shared__ __align__(16) u16 smem[30720];   // 61.4 KB arena
    __shared__ float sG[64], sM[64], sWr[64], sInv[64], sNb[128], sRS[2][64];
    u16* sQ  = smem;            // [64][136] bf16   (phases 0-2)
    u16* sCB = smem + 8704;     // [128][136] bf16  (phase 0)
    u16* sK  = smem + 8704;     // [64][136] bf16   (phase 1, overlays sCB)
    u16* sVt = smem;            // [128][72] bf16   (phase 3, overlays sQ)
    u16* sD  = smem + 26112;    // [64][72] bf16    (phase 1 write, 3 read)
    float* hv = (float*)smem;   // [64][132] f32    (epilogue, overlays sQ/sVt)
    int tid = threadIdx.x;
    int wave = tid >> 6, lane = tid & 63;
    int lrow = lane & 15, lquad = lane >> 4;
    int mq = wave >> 1, nh = wave & 1;

    float Mbprev = (c > 0) ? gMb[chain * NCH + c - 1] : 0.f;
    if (tid < 64) {
        bool val = tid < nvalid;
        sG[tid] = val ? gG[chain * TT + t0 + tid] : -1e30f;
        float Mv = val ? gM[chain * TT + t0 + tid] : 1e30f;
        sM[tid] = Mv;
        sWr[tid] = val ? __expf(Mbprev - Mv) : 0.f;
    }
    if (tid >= 128 && tid < 256) sNb[tid - 128] = nP[(size_t)(c * 32 + chain) * 128 + (tid - 128)];

    // ---- stage sQ [64][136]
    {
        int lr = tid >> 3, c0 = (tid & 7) * 16;
        bool val = lr < nvalid;
        size_t gb = ((size_t)(b * TT + t0 + lr)) * IN + h * DHd + c0;
#pragma unroll
        for (int i = 0; i < 4; i++) {
            float4 q4 = val ? *(const float4*)(qq + gb + i * 4) : make_float4(0.f,0.f,0.f,0.f);
            ushort4v tq = {f2bf(q4.x), f2bf(q4.y), f2bf(q4.z), f2bf(q4.w)};
            *(ushort4v*)&sQ[lr * 136 + c0 + i * 4] = tq;
        }
    }
    // ---- stage sCB [128][136] from bf16 CB[e][d]
    {
        const u16* CBbase = CB + (((size_t)(c * 32 + chain)) << 14);
        int e = tid >> 2, d0 = (tid & 3) * 32;
#pragma unroll
        for (int i = 0; i < 4; i++)
            *(ushort8v*)&sCB[e * 136 + d0 + i * 8] =
                *(const ushort8v*)(CBbase + (size_t)e * 128 + d0 + i * 8);
    }
    __syncthreads();

    // ---- phase 0: inter = Q @ CB, C-layout acc; then scale by wr
    f32x4 acc[4];
#pragma unroll
    for (int tt = 0; tt < 4; tt++)
#pragma unroll
        for (int r = 0; r < 4; r++) acc[tt][r] = 0.f;
#pragma unroll 1
    for (int ks = 0; ks < 4; ks++) {
        bf16x8 af = *(const bf16x8*)&sQ[(mq * 16 + lrow) * 136 + ks * 32 + lquad * 8];
#pragma unroll
        for (int tt = 0; tt < 4; tt++) {
            bf16x8 bf = *(const bf16x8*)&sCB[(nh * 64 + tt * 16 + lrow) * 136 + ks * 32 + lquad * 8];
            acc[tt] = __builtin_amdgcn_mfma_f32_16x16x32_bf16(af, bf, acc[tt], 0, 0, 0);
        }
    }
#pragma unroll
    for (int tt = 0; tt < 4; tt++)
#pragma unroll
        for (int r = 0; r < 4; r++) acc[tt][r] *= sWr[mq * 16 + lquad * 4 + r];
    __syncthreads();

    // ---- stage sK (overlays sCB)
    {
        int lr = tid >> 3, c0 = (tid & 7) * 16;
        bool val = lr < nvalid;
        size_t gb = ((size_t)(b * TT + t0 + lr)) * IN + h * DHd + c0;
#pragma unroll
        for (int i = 0; i < 4; i++) {
            float4 k4 = val ? *(const float4*)(kk + gb + i * 4) : make_float4(0.f,0.f,0.f,0.f);
            ushort4v tk = {f2bf(k4.x), f2bf(k4.y), f2bf(k4.z), f2bf(k4.w)};
            *(ushort4v*)&sK[lr * 136 + c0 + i * 4] = tk;
        }
    }
    __syncthreads();

    // ---- phase 1: S = Q K^T (2 n-tiles/wave), weights, sD bf16, in-reg rowsums
    {
        f32x4 accS[2];
#pragma unroll
        for (int tt = 0; tt < 2; tt++)
#pragma unroll
            for (int r = 0; r < 4; r++) accS[tt][r] = 0.f;
#pragma unroll 1
        for (int ks = 0; ks < 4; ks++) {
            bf16x8 af = *(const bf16x8*)&sQ[(mq * 16 + lrow) * 136 + ks * 32 + lquad * 8];
#pragma unroll
            for (int tt = 0; tt < 2; tt++) {
                bf16x8 bf = *(const bf16x8*)&sK[((nh * 2 + tt) * 16 + lrow) * 136 + ks * 32 + lquad * 8];
                accS[tt] = __builtin_amdgcn_mfma_f32_16x16x32_bf16(af, bf, accS[tt], 0, 0, 0);
            }
        }
        float rsum[4] = {0.f, 0.f, 0.f, 0.f};
#pragma unroll
        for (int tt = 0; tt < 2; tt++) {
            int j = (nh * 2 + tt) * 16 + lrow;
            float Gj = sG[j];
#pragma unroll
            for (int r = 0; r < 4; r++) {
                int t = mq * 16 + lquad * 4 + r;
                float w = (j <= t) ? __expf(Gj - sM[t]) : 0.f;
                float wD = accS[tt][r] * w;
                rsum[r] += wD;
                sD[t * 72 + j] = f2bf(wD);
            }
        }
#pragma unroll
        for (int r = 0; r < 4; r++) {
#pragma unroll
            for (int msk = 1; msk < 16; msk <<= 1) rsum[r] += __shfl_xor(rsum[r], msk);
        }
        if (lrow == 0) {
#pragma unroll
            for (int r = 0; r < 4; r++) sRS[nh][mq * 16 + lquad * 4 + r] = rsum[r];
        }
    }
    __syncthreads();

    // ---- phase 2: denominators (tid<64); qnb from bf16 sQ
    if (tid < 64) {
        float qn = 0.f;
#pragma unroll 1
        for (int d4 = 0; d4 < 32; d4++) {
            ushort4v q4 = *(const ushort4v*)&sQ[tid * 136 + d4 * 4];
            float4 nb = *(const float4*)&sNb[d4 * 4];
            qn += bfu(q4.x) * nb.x + bfu(q4.y) * nb.y + bfu(q4.z) * nb.z + bfu(q4.w) * nb.w;
        }
        float den = sRS[0][tid] + sRS[1][tid] + sWr[tid] * qn;
        sInv[tid] = 1.f / fmaxf(fabsf(den), 1.f);
    }
    __syncthreads();

    // ---- stage sVt [128][72] = V^T bf16 (overlays sQ)
    {
        int e = tid & 127, tg = (tid >> 7) * 16;
#pragma unroll 1
        for (int i = 0; i < 16; i++) {
            int t = tg + i;
            float v = (t < nvalid) ? vv[((size_t)(b * TT + t0 + t)) * IN + h * DHd + e] : 0.f;
            sVt[e * 72 + t] = f2bf(v);
        }
    }
    __syncthreads();

    // ---- phase 3: acc += D @ V
#pragma unroll 1
    for (int ks = 0; ks < 2; ks++) {
        bf16x8 af = *(const bf16x8*)&sD[(mq * 16 + lrow) * 72 + ks * 32 + lquad * 8];
#pragma unroll
        for (int tt = 0; tt < 4; tt++) {
            bf16x8 bf = *(const bf16x8*)&sVt[(nh * 64 + tt * 16 + lrow) * 72 + ks * 32 + lquad * 8];
            acc[tt] = __builtin_amdgcn_mfma_f32_16x16x32_bf16(af, bf, acc[tt], 0, 0, 0);
        }
    }

    // ---- epilogue: h rows -> LDS, fused head-norm * hn * silu(z) -> bf16 out
    __syncthreads();   // all waves done reading sVt/sD before overlay
#pragma unroll
    for (int tt = 0; tt < 4; tt++) {
#pragma unroll
        for (int r = 0; r < 4; r++) {
            int t = mq * 16 + lquad * 4 + r;
            int e = nh * 64 + tt * 16 + lrow;
            hv[t * 132 + e] = acc[tt][r] * sInv[t];
        }
    }
    __syncthreads();
    {
        int t = tid >> 3, s = tid & 7;
        float vals[16];
        float sum = 0.f, sq = 0.f;
#pragma unroll
        for (int i = 0; i < 16; i++) {
            float v = hv[t * 132 + s * 16 + i];
            vals[i] = v; sum += v; sq += v * v;
        }
#pragma unroll
        for (int m = 1; m < 8; m <<= 1) { sum += __shfl_xor(sum, m); sq += __shfl_xor(sq, m); }
        float mu = sum / DHd, var = sq / DHd - mu * mu, inv2 = rsqrtf(var + EPSV);
        if (t < nvalid) {
            size_t bt = (size_t)(b * TT + t0 + t);
            const float* zp = up + bt * (2 * IN) + IN + h * DHd + s * 16;
            u16* op = out16 + bt * IN + h * DHd + s * 16;
#pragma unroll
            for (int i = 0; i < 16; i++) {
                float hnv = hn[h * DHd + s * 16 + i];
                op[i] = f2bf((vals[i] - mu) * inv2 * hnv * siluf(zp[i]));
            }
        }
    }
}

// ---------------------------------------------------------------- head: fused cls LN+ReLU + FC
__global__ __launch_bounds__(256) void fc_kernel(const float* __restrict__ hbuf,
                                                 const float* __restrict__ fcls,
                                                 const float* __restrict__ fclb,
                                                 const float* __restrict__ fw,
                                                 const float* __restrict__ fb,
                                                 float* __restrict__ out) {
    __shared__ float svc[Bsz][Dm];
    __shared__ float sred[4][256];
    int tid = threadIdx.x;
    int j0 = blockIdx.x * 64;
    {
        int r = tid >> 6, lane = tid & 63;
        const float* hrow = hbuf + ((size_t)r * TT + TT - 1) * Dm;
        float v[8];
        float sum = 0.f, sq = 0.f;
#pragma unroll
        for (int k = 0; k < 8; k++) {
            v[k] = hrow[lane + k * 64];
            sum += v[k]; sq += v[k] * v[k];
        }
#pragma unroll
        for (int o = 32; o > 0; o >>= 1) { sum += __shfl_xor(sum, o); sq += __shfl_xor(sq, o); }
        float mu = sum / Dm, var = sq / Dm - mu * mu, inv = rsqrtf(var + EPSV);
#pragma unroll
        for (int k = 0; k < 8; k++) {
            int e = lane + k * 64;
            svc[r][e] = fmaxf((v[k] - mu) * inv * fcls[e] + fclb[e], 0.f);
        }
    }
    __syncthreads();
    int j = j0 + (tid & 63);
    int chunk = tid >> 6;
    int kbase = chunk * 128;
    float a0 = 0.f, a1 = 0.f, a2 = 0.f, a3 = 0.f;
    if (j < NCc) {
        const float* fwp = fw + (size_t)kbase * NCc + j;
#pragma unroll 4
        for (int kk = 0; kk < 128; kk++) {
            float w = fwp[(size_t)kk * NCc];
            a0 += svc[0][kbase + kk] * w;
            a1 += svc[1][kbase + kk] * w;
            a2 += svc[2][kbase + kk] * w;
            a3 += svc[3][kbase + kk] * w;
        }
    }
    int jl = tid & 63;
    sred[chunk][jl * 4 + 0] = a0;
    sred[chunk][jl * 4 + 1] = a1;
    sred[chunk][jl * 4 + 2] = a2;
    sred[chunk][jl * 4 + 3] = a3;
    __syncthreads();
    if (tid < 64) {
        int jj = j0 + tid;
        if (jj < NCc) {
            float bias = fb[jj];
#pragma unroll
            for (int b = 0; b < Bsz; b++) {
                float v = sred[0][tid * 4 + b] + sred[1][tid * 4 + b]
                        + sred[2][tid * 4 + b] + sred[3][tid * 4 + b];
                out[b * NCc + jj] = v + bias;
            }
        }
    }
}

// ---------------------------------------------------------------- gate weight transpose
__global__ __launch_bounds__(256) void gate_w_transpose(const float* __restrict__ wig,
                                                        const float* __restrict__ wfg,
                                                        float* __restrict__ wt) {
    int idx = blockIdx.x * 256 + threadIdx.x;
    int k = idx & 1023;
    int g = (idx >> 10) & 15;
    int blk = idx >> 14;
    const float* w = (g < 8) ? (wig + (size_t)blk * IN * NHh) : (wfg + (size_t)blk * IN * NHh);
    wt[idx] = w[k * NHh + (g & 7)];
}

// ---------------------------------------------------------------- launch
extern "C" void kernel_launch(void* const* d_in, const int* in_sizes, int n_in,
                              void* d_out, int out_size, void* d_ws, size_t ws_size,
                              hipStream_t stream) {
    const float* x      = (const float*)d_in[0];
    const float* cls    = (const float*)d_in[1];
    const float* ln_s   = (const float*)d_in[2];
    const float* ln_b   = (const float*)d_in[3];
    const float* w_up   = (const float*)d_in[4];
    const float* b_up   = (const float*)d_in[5];
    const float* conv_k = (const float*)d_in[6];
    const float* conv_b = (const float*)d_in[7];
    const float* w_q    = (const float*)d_in[8];
    const float* w_k    = (const float*)d_in[9];
    const float* w_v    = (const float*)d_in[10];
    const float* w_ig   = (const float*)d_in[11];
    const float* b_ig   = (const float*)d_in[12];
    const float* w_fg   = (const float*)d_in[13];
    const float* b_fg   = (const float*)d_in[14];
    const float* hn_s   = (const float*)d_in[15];
    const float* w_down = (const float*)d_in[16];
    const float* b_down = (const float*)d_in[17];
    const float* fcls   = (const float*)d_in[18];
    const float* fclb   = (const float*)d_in[19];
    const float* fc_w   = (const float*)d_in[20];
    const float* fc_b   = (const float*)d_in[21];
    float* out = (float*)d_out;

    float* ws = (float*)d_ws;
    size_t off = 0;
    float* f_h  = ws + off; off += (size_t)ROWS * Dm;
    float* f_up = ws + off; off += (size_t)ROWS * 2 * IN;
    float* f_q  = ws + off; off += (size_t)ROWS * IN;
    float* f_k  = ws + off; off += (size_t)ROWS * IN;
    float* f_v  = ws + off; off += (size_t)ROWS * IN;
    float* f_ip = ws + off; off += (size_t)ROWS * NHh;
    float* f_fp = ws + off; off += (size_t)ROWS * NHh;
    float* g_G  = ws + off; off += 32 * TT;
    float* g_M  = ws + off; off += 32 * TT;
    float* g_Mb = ws + off; off += 32 * NCH;
    float* g_De = ws + off; off += 32 * NCH;
    float* g_P  = ws + off; off += (size_t)NCH * 32 * DHd * DHd;
    float* g_nP = ws + off; off += (size_t)NCH * 32 * DHd;
    float* g_wt = ws + off; off += 2 * 16 * IN;
    u16* g_CB  = (u16*)(ws + off); off += ((size_t)NCH * 32 * DHd * DHd + 1) / 2;
    u16* g_Wt  = (u16*)(ws + off); off += (2 * WT_STRIDE + 1) / 2;
    // padded bf16 staging (MPAD rows; pad rows read as garbage, outputs guarded)
    u16* f_xn16 = (u16*)(ws + off); off += ((size_t)MPAD * Dm) / 2;
    u16* f_xc16 = (u16*)(ws + off); off += ((size_t)MPAD * IN) / 2;
    u16* f_xu16 = (u16*)(ws + off); off += ((size_t)MPAD * IN) / 2;
    u16* f_xg16 = (u16*)(ws + off); off += ((size_t)ROWS * IN + 1) / 2;

    const float kscale = 0.08838834764831845f; // DH^-0.5
    const int MB = (ROWS + 127) / 128;         // 17
    const int MB64 = (ROWS + 63) / 64;         // 33

    concat_kernel<<<(ROWS * Dm + 255) / 256, 256, 0, stream>>>(x, cls, f_h);
    gate_w_transpose<<<(2 * 16 * IN + 255) / 256, 256, 0, stream>>>(w_ig, w_fg, g_wt);
    w_transpose_kernel<<<dim3(1024, 10), 256, 0, stream>>>(w_up, w_q, w_k, w_v, w_down, g_Wt);

    for (int blk = 0; blk < 2; blk++) {
        const float* p_ln_s = ln_s + blk * Dm;
        const float* p_ln_b = ln_b + blk * Dm;
        const float* p_bup  = b_up + (size_t)blk * 2 * IN;
        const float* p_ck   = conv_k + (size_t)blk * IN * KK;
        const float* p_cb   = conv_b + (size_t)blk * IN;
        const float* p_big  = b_ig + (size_t)blk * NHh;
        const float* p_bfg  = b_fg + (size_t)blk * NHh;
        const float* p_hns  = hn_s + (size_t)blk * NHh * DHd;
        const float* p_bd   = b_down + (size_t)blk * Dm;
        const u16*   p_wt   = g_Wt + (size_t)blk * WT_STRIDE;

        ln_kernel<<<ROWS, 256, 0, stream>>>(f_h, p_ln_s, p_ln_b, f_xn16);

        up_gl_kernel<<<dim3(2 * IN / 128, MB), 256, 0, stream>>>(
            f_xn16, p_wt + WT_UP, p_bup, f_up);

        convgates_kernel<<<ROWS, 256, 0, stream>>>(
            f_up, p_ck, p_cb, g_wt + blk * 16 * IN, p_big, p_bfg,
            f_xc16, f_xu16, f_ip, f_fp);

        qkv_gl_kernel<<<dim3(24, MB), 256, 0, stream>>>(
            f_xc16, f_xu16, p_wt, f_q, f_k, f_v, kscale);

        // chunkwise-parallel mLSTM
        gate_scan_kernel<<<32, 64, 0, stream>>>(f_ip, f_fp, g_G, g_M, g_Mb, g_De);
        chunk_state_kernel<<<dim3(NCH, 32), 256, 0, stream>>>(f_k, f_v, g_G, g_Mb, g_P, g_nP);
        chunk_combine_kernel<<<32 * 64, 256, 0, stream>>>(g_P, g_CB, g_nP, g_De);
        chunk_out_kernel<<<dim3(NCH, 32), 512, 0, stream>>>(f_q, f_k, f_v, g_G, g_M, g_Mb,
                                                            g_CB, g_nP, p_hns, f_up, f_xg16);

        gemm_mfma_kernel<64, 64><<<dim3(Dm / 64, MB64), 256, 0, stream>>>(
            f_xg16, IN, p_wt + WT_DN, IN, p_bd, f_h, Dm, f_h, Dm, ROWS, 1.f);
    }

    fc_kernel<<<(NCc + 63) / 64, 256, 0, stream>>>(f_h, fcls, fclb, fc_w, fc_b, out);
}

// Round 4
// 419.055 us; speedup vs baseline: 1.2436x; 1.0389x over previous
//
#include <hip/hip_runtime.h>

// ---------------------------------------------------------------- constants
#define EPSV 1e-5f
constexpr int Bsz = 4, T0 = 512, Dm = 512, NHh = 8, KK = 4;
constexpr int TT = 513;
constexpr int IN = 1024, DHd = 128, NCc = 1000;
constexpr int ROWS = Bsz * TT; // 2052
constexpr int MPAD = 2176;     // 17*128 padded staging rows for gload GEMMs
constexpr int NCH = 9;         // chunks of 64: 8*64 + 1 = 513

// bf16 k-major weight buffer offsets (u16 elements), per transformer block
constexpr size_t WT_UP = 0;                      // [2048][512]
constexpr size_t WT_Q  = WT_UP + 2048 * 512;     // [1024][1024]
constexpr size_t WT_K  = WT_Q + 1024 * 1024;
constexpr size_t WT_V  = WT_K + 1024 * 1024;
constexpr size_t WT_DN = WT_V + 1024 * 1024;     // [512][1024]
constexpr size_t WT_STRIDE = WT_DN + 512 * 1024; // 4,718,592 u16

typedef __attribute__((ext_vector_type(8))) short bf16x8;
typedef __attribute__((ext_vector_type(4))) float f32x4;
typedef __attribute__((ext_vector_type(4))) unsigned short ushort4v;
typedef __attribute__((ext_vector_type(8))) unsigned short ushort8v;
typedef unsigned short u16;

__device__ __forceinline__ float siluf(float x) { return x / (1.f + __expf(-x)); }
__device__ __forceinline__ u16 f2bf(float f) {
    unsigned int u = __float_as_uint(f);
    u = (u + 0x7FFFu + ((u >> 16) & 1u)) >> 16;
    return (u16)u;
}
__device__ __forceinline__ float bfu(u16 u) {
    return __uint_as_float(((unsigned int)u) << 16);
}
// async global->LDS, 16 bytes per lane; LDS dest is wave-uniform base + lane*16
__device__ __forceinline__ void gload16(const u16* g, u16* l) {
    __builtin_amdgcn_global_load_lds(
        (const __attribute__((address_space(1))) void*)g,
        (__attribute__((address_space(3))) void*)l, 16, 0, 0);
}

// ---------------------------------------------------------------- concat x + cls
__global__ __launch_bounds__(256) void concat_kernel(const float* __restrict__ x,
                                                     const float* __restrict__ cls,
                                                     float* __restrict__ h) {
    int idx = blockIdx.x * 256 + threadIdx.x;
    if (idx >= Bsz * TT * Dm) return;
    int d = idx & (Dm - 1);
    int bt = idx >> 9;
    int t = bt % TT, b = bt / TT;
    h[idx] = (t < T0) ? x[((size_t)(b * T0 + t)) * Dm + d] : cls[d];
}

// ---------------------------------------------------------------- LayerNorm rows of D=512 -> bf16
__global__ __launch_bounds__(256) void ln_kernel(const float* __restrict__ in,
                                                 const float* __restrict__ s,
                                                 const float* __restrict__ bb,
                                                 u16* __restrict__ out16) {
    int row = blockIdx.x, tid = threadIdx.x;
    const float* r = in + (size_t)row * Dm;
    __shared__ float s1[4], s2[4];
    float x0 = r[tid], x1 = r[tid + 256];
    float sum = x0 + x1, sq = x0 * x0 + x1 * x1;
#pragma unroll
    for (int o = 32; o > 0; o >>= 1) { sum += __shfl_xor(sum, o); sq += __shfl_xor(sq, o); }
    if ((tid & 63) == 0) { s1[tid >> 6] = sum; s2[tid >> 6] = sq; }
    __syncthreads();
    sum = s1[0] + s1[1] + s1[2] + s1[3];
    sq  = s2[0] + s2[1] + s2[2] + s2[3];
    float mu = sum / Dm, var = sq / Dm - mu * mu, inv = rsqrtf(var + EPSV);
    out16[(size_t)row * Dm + tid]       = f2bf((x0 - mu) * inv * s[tid] + bb[tid]);
    out16[(size_t)row * Dm + tid + 256] = f2bf((x1 - mu) * inv * s[tid + 256] + bb[tid + 256]);
}

// ---------------------------------------------------------------- weight transpose f32 KxN -> bf16 [N][K]
__global__ __launch_bounds__(256) void w_transpose_kernel(const float* __restrict__ wup,
        const float* __restrict__ wq, const float* __restrict__ wk,
        const float* __restrict__ wv, const float* __restrict__ wdn,
        u16* __restrict__ wt) {
    int y = blockIdx.y;             // 0..9
    int blk = y / 5, sel = y - blk * 5;
    int Kd, N; const float* src; size_t doff;
    if (sel == 0)      { Kd = 512;  N = 2048; src = wup + (size_t)blk * 512 * 2048; doff = WT_UP; }
    else if (sel == 1) { Kd = 1024; N = 1024; src = wq  + (size_t)blk * 1024 * 1024; doff = WT_Q; }
    else if (sel == 2) { Kd = 1024; N = 1024; src = wk  + (size_t)blk * 1024 * 1024; doff = WT_K; }
    else if (sel == 3) { Kd = 1024; N = 1024; src = wv  + (size_t)blk * 1024 * 1024; doff = WT_V; }
    else               { Kd = 1024; N = 512;  src = wdn + (size_t)blk * 1024 * 512;  doff = WT_DN; }
    u16* dst = wt + (size_t)blk * WT_STRIDE + doff;
    int ntx = N >> 5;
    int ntiles = ntx * (Kd >> 5);
    int ti = blockIdx.x;
    if (ti >= ntiles) return;
    int tk = ti / ntx, tn = ti - tk * ntx;
    __shared__ u16 s[32][33];
    int tx = threadIdx.x & 31, ty = threadIdx.x >> 5;
#pragma unroll
    for (int i = 0; i < 4; i++) {
        int k = tk * 32 + ty + i * 8;
        s[ty + i * 8][tx] = f2bf(src[(size_t)k * N + tn * 32 + tx]);
    }
    __syncthreads();
#pragma unroll
    for (int i = 0; i < 4; i++) {
        int n = tn * 32 + ty + i * 8;
        dst[(size_t)n * Kd + tk * 32 + tx] = s[tx][ty + i * 8];
    }
}

// ---------------------------------------------------------------- legacy MFMA GEMM (down-proj)
template<int BM, int BN>
__device__ __forceinline__ void gemm_tile_body(const u16* __restrict__ A, int lda,
                                               const u16* __restrict__ Wt, int Kd,
                                               const float* __restrict__ bias,
                                               const float* __restrict__ resid, int ldr,
                                               float* __restrict__ Cout, int ldc,
                                               int M, float scale, int m0, int n0,
                                               u16 (*As)[BM][40], u16 (*Bs)[BN][40]) {
    constexpr int MT = BM / 32;
    constexpr int NT = BN / 32;
    constexpr int ANV = BM / 64;           // ushort8 A-loads per thread
    constexpr int BNV = BN / 64;           // ushort8 B-loads per thread
    int tid = threadIdx.x;
    int wave = tid >> 6, lane = tid & 63;
    int wm = (wave >> 1) * (BM / 2), wn = (wave & 1) * (BN / 2);
    int lrow = lane & 15, lquad = lane >> 4;

    f32x4 acc[MT][NT];
#pragma unroll
    for (int i = 0; i < MT; i++)
#pragma unroll
        for (int j = 0; j < NT; j++)
#pragma unroll
            for (int r = 0; r < 4; r++) acc[i][j][r] = 0.f;

    int am, ak, bn, bk;
    if (BM == 128) { am = tid >> 1; ak = (tid & 1) * 16; }
    else           { am = tid >> 2; ak = (tid & 3) * 8; }
    if (BN == 128) { bn = tid & 127; bk = (tid >> 7) * 16; }
    else           { bn = tid & 63;  bk = (tid >> 6) * 8; }
    int gm = m0 + am;
    const u16* arow = A + (size_t)(gm < M ? gm : 0) * lda + ak;
    bool avalid = gm < M;
    const u16* wrow = Wt + (size_t)(n0 + bn) * Kd + bk;

    ushort8v areg[ANV];
    ushort8v breg[BNV];

    auto load_tile = [&](int k0) {
        if (avalid) {
#pragma unroll
            for (int i = 0; i < ANV; i++) areg[i] = *(const ushort8v*)(arow + k0 + i * 8);
        } else {
#pragma unroll
            for (int i = 0; i < ANV; i++) areg[i] = (ushort8v){0,0,0,0,0,0,0,0};
        }
#pragma unroll
        for (int i = 0; i < BNV; i++) breg[i] = *(const ushort8v*)(wrow + k0 + i * 8);
    };
    auto store_tile = [&](int buf) {
#pragma unroll
        for (int i = 0; i < ANV; i++)
            *(ushort8v*)&As[buf][am][ak + i * 8] = areg[i];
#pragma unroll
        for (int i = 0; i < BNV; i++)
            *(ushort8v*)&Bs[buf][bn][bk + i * 8] = breg[i];
    };

    load_tile(0);
    store_tile(0);
    __syncthreads();

    int nk = Kd >> 5;
#pragma unroll 1
    for (int it = 0; it < nk; it++) {
        int cur = it & 1;
        bool more = (it + 1 < nk);
        if (more) load_tile((it + 1) << 5);
        bf16x8 afr[MT], bfr[NT];
#pragma unroll
        for (int mt = 0; mt < MT; mt++)
            afr[mt] = *(const bf16x8*)&As[cur][wm + mt * 16 + lrow][lquad * 8];
#pragma unroll
        for (int nt = 0; nt < NT; nt++)
            bfr[nt] = *(const bf16x8*)&Bs[cur][wn + nt * 16 + lrow][lquad * 8];
#pragma unroll
        for (int mt = 0; mt < MT; mt++)
#pragma unroll
            for (int nt = 0; nt < NT; nt++)
                acc[mt][nt] = __builtin_amdgcn_mfma_f32_16x16x32_bf16(
                    afr[mt], bfr[nt], acc[mt][nt], 0, 0, 0);
        if (more) store_tile(cur ^ 1);
        __syncthreads();
    }

#pragma unroll
    for (int mt = 0; mt < MT; mt++) {
#pragma unroll
        for (int r = 0; r < 4; r++) {
            int gmr = m0 + wm + mt * 16 + lquad * 4 + r;
            if (gmr >= M) continue;
#pragma unroll
            for (int nt = 0; nt < NT; nt++) {
                int gn = n0 + wn + nt * 16 + lrow;
                float v = acc[mt][nt][r] * scale;
                if (bias) v += bias[gn];
                if (resid) v += resid[(size_t)gmr * ldr + gn];
                Cout[(size_t)gmr * ldc + gn] = v;
            }
        }
    }
}

template<int BM, int BN>
__global__ __launch_bounds__(256, 2) void gemm_mfma_kernel(const u16* __restrict__ A, int lda,
                                                           const u16* __restrict__ Wt, int Kd,
                                                           const float* __restrict__ bias,
                                                           const float* __restrict__ resid, int ldr,
                                                           float* __restrict__ Cout, int ldc,
                                                           int M, float scale) {
    __shared__ __align__(16) u16 As[2][BM][40];
    __shared__ __align__(16) u16 Bs[2][BN][40];
    gemm_tile_body<BM, BN>(A, lda, Wt, Kd, bias, resid, ldr, Cout, ldc, M, scale,
                           blockIdx.y * BM, blockIdx.x * BN, As, Bs);
}

// ---------------------------------------------------------------- m97-style 128x128 gload GEMM
// T3 minimum 2-phase: prefetch next K-tile BEFORE MFMA; one barrier per tile.
// OUT16: write bf16 output instead of f32.
template<bool OUT16>
__device__ __forceinline__ void gemm128_body(const u16* __restrict__ A, int lda,
                                             const u16* __restrict__ Wt, int Kd,
                                             const float* __restrict__ bias,
                                             void* __restrict__ Cout, int ldc,
                                             int M, float scale, int m0, int n0,
                                             u16* As, u16* Bs) {
    int tid = threadIdx.x;
    int wave = tid >> 6, lane = tid & 63;
    int lrow = lane & 15, lquad = lane >> 4;
    int wm = (wave >> 1) * 64, wn = (wave & 1) * 64;

    const u16* ag0 = A + (size_t)(m0 + wave * 16 + (lane >> 2)) * lda + (lane & 3) * 8;
    const u16* ag1 = ag0 + (size_t)64 * lda;
    const u16* bg0 = Wt + (size_t)(n0 + wave * 16 + (lane >> 2)) * Kd + (lane & 3) * 8;
    const u16* bg1 = bg0 + (size_t)64 * Kd;

    auto stage = [&](int buf, int k0) {
        u16* a = As + buf * 4096 + wave * 512;
        u16* bb = Bs + buf * 4096 + wave * 512;
        gload16(ag0 + k0, a);
        gload16(ag1 + k0, a + 2048);
        gload16(bg0 + k0, bb);
        gload16(bg1 + k0, bb + 2048);
    };

    f32x4 acc[4][4];
#pragma unroll
    for (int i = 0; i < 4; i++)
#pragma unroll
        for (int j = 0; j < 4; j++)
#pragma unroll
            for (int r = 0; r < 4; r++) acc[i][j][r] = 0.f;

    int nk = Kd >> 5;
    stage(0, 0);
    __syncthreads();
#pragma unroll 1
    for (int it = 0; it < nk; it++) {
        int cur = it & 1;
        if (it + 1 < nk) stage(cur ^ 1, (it + 1) << 5);   // prefetch overlaps MFMA
        const u16* Ac = As + cur * 4096;
        const u16* Bc = Bs + cur * 4096;
        bf16x8 afr[4], bfr[4];
#pragma unroll
        for (int mt = 0; mt < 4; mt++)
            afr[mt] = *(const bf16x8*)&Ac[(wm + mt * 16 + lrow) * 32 + lquad * 8];
#pragma unroll
        for (int nt = 0; nt < 4; nt++)
            bfr[nt] = *(const bf16x8*)&Bc[(wn + nt * 16 + lrow) * 32 + lquad * 8];
#pragma unroll
        for (int mt = 0; mt < 4; mt++)
#pragma unroll
            for (int nt = 0; nt < 4; nt++)
                acc[mt][nt] = __builtin_amdgcn_mfma_f32_16x16x32_bf16(
                    afr[mt], bfr[nt], acc[mt][nt], 0, 0, 0);
        __syncthreads();   // drains prefetch vmcnt + read-before-overwrite
    }

#pragma unroll
    for (int mt = 0; mt < 4; mt++) {
#pragma unroll
        for (int r = 0; r < 4; r++) {
            int gmr = m0 + wm + mt * 16 + lquad * 4 + r;
            if (gmr >= M) continue;
#pragma unroll
            for (int nt = 0; nt < 4; nt++) {
                int gn = n0 + wn + nt * 16 + lrow;
                float v = acc[mt][nt][r] * scale;
                if (bias) v += bias[gn];
                if (OUT16) ((u16*)Cout)[(size_t)gmr * ldc + gn] = f2bf(v);
                else       ((float*)Cout)[(size_t)gmr * ldc + gn] = v;
            }
        }
    }
}

__global__ __launch_bounds__(256, 2) void up_gl_kernel(const u16* __restrict__ A,
        const u16* __restrict__ Wt, const float* __restrict__ bias, float* __restrict__ C) {
    __shared__ __align__(16) u16 As[2 * 4096];
    __shared__ __align__(16) u16 Bs[2 * 4096];
    gemm128_body<false>(A, Dm, Wt, Dm, bias, C, 2 * IN, ROWS, 1.f,
                        blockIdx.y * 128, blockIdx.x * 128, As, Bs);
}

// q/k/v in ONE dispatch, bf16 outputs. blockIdx.x in [0,24): sel = x>>3, nx = x&7.
__global__ __launch_bounds__(256, 2) void qkv_gl_kernel(const u16* __restrict__ xc16,
                                                        const u16* __restrict__ xu16,
                                                        const u16* __restrict__ wtblk,
                                                        u16* __restrict__ fq,
                                                        u16* __restrict__ fk,
                                                        u16* __restrict__ fv,
                                                        float kscale) {
    __shared__ __align__(16) u16 As[2 * 4096];
    __shared__ __align__(16) u16 Bs[2 * 4096];
    int sel = blockIdx.x >> 3, nx = blockIdx.x & 7;
    const u16* A = (sel == 2) ? xu16 : xc16;
    const u16* Wt = wtblk + ((sel == 0) ? WT_Q : (sel == 1) ? WT_K : WT_V);
    u16* C = (sel == 0) ? fq : (sel == 1) ? fk : fv;
    float scale = (sel == 1) ? kscale : 1.f;
    gemm128_body<true>(A, IN, Wt, IN, nullptr, C, IN, ROWS, scale,
                       blockIdx.y * 128, nx * 128, As, Bs);
}

// ---------------------------------------------------------------- fused causal conv + SiLU + gate projections
__global__ __launch_bounds__(256) void convgates_kernel(const float* __restrict__ up,
        const float* __restrict__ ck, const float* __restrict__ cb,
        const float* __restrict__ wt, const float* __restrict__ big,
        const float* __restrict__ bfg,
        u16* __restrict__ xc16, u16* __restrict__ xu16,
        float* __restrict__ ip, float* __restrict__ fp) {
    int row = blockIdx.x, tid = threadIdx.x;
    int b = row / TT, t = row - b * TT;
    __shared__ float sx[IN];
    int c0 = tid * 4;
    float4 cur = *(const float4*)(up + (size_t)row * (2 * IN) + c0);
    float a0 = cb[c0 + 0] + cur.x * ck[(c0 + 0) * KK + 3];
    float a1 = cb[c0 + 1] + cur.y * ck[(c0 + 1) * KK + 3];
    float a2 = cb[c0 + 2] + cur.z * ck[(c0 + 2) * KK + 3];
    float a3 = cb[c0 + 3] + cur.w * ck[(c0 + 3) * KK + 3];
#pragma unroll
    for (int j = 0; j < KK - 1; j++) {
        int tt2 = t - (KK - 1) + j;
        if (tt2 >= 0) {
            float4 pv = *(const float4*)(up + ((size_t)(b * TT + tt2)) * (2 * IN) + c0);
            a0 += pv.x * ck[(c0 + 0) * KK + j];
            a1 += pv.y * ck[(c0 + 1) * KK + j];
            a2 += pv.z * ck[(c0 + 2) * KK + j];
            a3 += pv.w * ck[(c0 + 3) * KK + j];
        }
    }
    float s0 = siluf(a0), s1v = siluf(a1), s2v = siluf(a2), s3v = siluf(a3);
    *(float4*)&sx[c0] = make_float4(s0, s1v, s2v, s3v);
    ushort4v xc4 = {f2bf(s0), f2bf(s1v), f2bf(s2v), f2bf(s3v)};
    *(ushort4v*)&xc16[(size_t)row * IN + c0] = xc4;
    ushort4v xu4 = {f2bf(cur.x), f2bf(cur.y), f2bf(cur.z), f2bf(cur.w)};
    *(ushort4v*)&xu16[(size_t)row * IN + c0] = xu4;
    __syncthreads();

    int g = tid >> 4, l = tid & 15;
    const float* wrow = wt + g * IN;
    float acc = 0.f;
#pragma unroll
    for (int j = 0; j < 16; j++) {
        int k = j * 64 + l * 4;
        float4 w4 = *(const float4*)(wrow + k);
        float4 x4 = *(const float4*)&sx[k];
        acc += w4.x * x4.x + w4.y * x4.y + w4.z * x4.z + w4.w * x4.w;
    }
#pragma unroll
    for (int o = 8; o > 0; o >>= 1) acc += __shfl_down(acc, o, 16);
    if (l == 0) {
        if (g < 8) ip[(size_t)row * NHh + g] = acc + big[g];
        else       fp[(size_t)row * NHh + (g - 8)] = acc + bfg[g - 8];
    }
}

// ---------------------------------------------------------------- chunkwise mLSTM
__global__ __launch_bounds__(64) void gate_scan_kernel(const float* __restrict__ ip,
        const float* __restrict__ fp, float* __restrict__ gG, float* __restrict__ gM,
        float* __restrict__ gMb, float* __restrict__ gDec) {
    constexpr int PER = 9;
    int chain = blockIdx.x;
    int b = chain >> 3, h = chain & 7;
    int lane = threadIdx.x;
    int tbase = lane * PER;
    float lcs[PER];
    float gi[PER];
    float csum = 0.f;
#pragma unroll
    for (int i = 0; i < PER; i++) {
        int t = tbase + i;
        float fpv = 0.f, ipv = 0.f;
        if (t < TT) {
            size_t gidx = (size_t)(b * TT + t) * NHh + h;
            fpv = fp[gidx]; ipv = ip[gidx];
        }
        float flv = (fpv >= 0.f) ? -log1pf(__expf(-fpv)) : (fpv - log1pf(__expf(fpv)));
        if (t >= TT) flv = 0.f;
        csum += flv;
        lcs[i] = csum;
        gi[i] = ipv;
    }
    float ps = csum;
#pragma unroll
    for (int o = 1; o < 64; o <<= 1) {
        float v = __shfl_up(ps, o);
        if (lane >= o) ps += v;
    }
    float Fexcl = ps - csum;
    float G[PER];
    float cmax = -1e30f;
#pragma unroll
    for (int i = 0; i < PER; i++) {
        int t = tbase + i;
        G[i] = (t < TT) ? (gi[i] - (Fexcl + lcs[i])) : -1e30f;
        cmax = fmaxf(cmax, G[i]);
        lcs[i] = cmax;
    }
    float pm = cmax;
#pragma unroll
    for (int o = 1; o < 64; o <<= 1) {
        float v = __shfl_up(pm, o);
        if (lane >= o) pm = fmaxf(pm, v);
    }
    float Me = __shfl_up(pm, 1);
    if (lane == 0) Me = -1e30f;
    __shared__ float sMb[NCH];
#pragma unroll
    for (int i = 0; i < PER; i++) {
        int t = tbase + i;
        if (t < TT) {
            float Mt = fmaxf(0.f, fmaxf(Me, lcs[i]));
            gG[chain * TT + t] = G[i];
            gM[chain * TT + t] = Mt;
            if (((t & 63) == 63) || t == TT - 1) sMb[t >> 6] = Mt;
        }
    }
    __syncthreads();
    if (lane < NCH) {
        float Mb = sMb[lane];
        float Mbp = (lane == 0) ? 0.f : sMb[lane - 1];
        gMb[chain * NCH + lane] = Mb;
        gDec[chain * NCH + lane] = __expf(Mbp - Mb);
    }
}

// Kernel B1: per-chunk local state via MFMA. P stored [e][d] (e-major). bf16 K/V inputs.
__global__ __launch_bounds__(256, 2) void chunk_state_kernel(const u16* __restrict__ kk,
        const u16* __restrict__ vv, const float* __restrict__ gG,
        const float* __restrict__ gMb, float* __restrict__ P, float* __restrict__ nP) {
    int c = blockIdx.x, chain = blockIdx.y;
    int b = chain >> 3, h = chain & 7;
    int t0 = c * 64;
    int nvalid = min(64, TT - t0);
    __shared__ __align__(16) u16 sWv[128][72];   // [e][j] = w_j * V[j][e]
    __shared__ __align__(16) u16 sKt[128][72];   // [d][j] = K[j][d]
    __shared__ float sw[64];
    int tid = threadIdx.x;
    if (tid < 64) {
        float Mb = gMb[chain * NCH + c];
        sw[tid] = (tid < nvalid) ? __expf(gG[chain * TT + t0 + tid] - Mb) : 0.f;
    }
    __syncthreads();

    {
        int j = tid >> 2, d0 = (tid & 3) * 32;
        bool val = j < nvalid;
        float wj = sw[j];
        size_t gb = ((size_t)(b * TT + t0 + j)) * IN + h * DHd + d0;
        ushort8v z8 = {0,0,0,0,0,0,0,0};
#pragma unroll
        for (int i = 0; i < 4; i++) {
            ushort8v k8 = val ? *(const ushort8v*)(kk + gb + i * 8) : z8;
            ushort8v v8 = val ? *(const ushort8v*)(vv + gb + i * 8) : z8;
#pragma unroll
            for (int e = 0; e < 8; e++) {
                int dd = d0 + i * 8 + e;
                int jc = j ^ (((dd >> 5) & 3) << 4);       // column swizzle
                sKt[dd][jc] = k8[e];
                sWv[dd][jc] = f2bf(bfu(v8[e]) * wj);
            }
        }
    }
    __syncthreads();

    int wave = tid >> 6, lane = tid & 63;
    int lrow = lane & 15, lquad = lane >> 4;
    int wm = (wave >> 1) * 64, wn = (wave & 1) * 64;
    f32x4 acc[4][4];
#pragma unroll
    for (int mt = 0; mt < 4; mt++)
#pragma unroll
        for (int nt = 0; nt < 4; nt++)
#pragma unroll
            for (int r = 0; r < 4; r++) acc[mt][nt][r] = 0.f;

#pragma unroll
    for (int ks = 0; ks < 2; ks++) {
        bf16x8 af[4], bfr[4];
#pragma unroll
        for (int mt = 0; mt < 4; mt++) {
            int r = wm + mt * 16 + lrow;
            int g = (ks * 4 + lquad) ^ (((r >> 5) & 3) << 1);
            af[mt] = *(const bf16x8*)&sWv[r][g * 8];
        }
#pragma unroll
        for (int nt = 0; nt < 4; nt++) {
            int r = wn + nt * 16 + lrow;
            int g = (ks * 4 + lquad) ^ (((r >> 5) & 3) << 1);
            bfr[nt] = *(const bf16x8*)&sKt[r][g * 8];
        }
#pragma unroll
        for (int mt = 0; mt < 4; mt++)
#pragma unroll
            for (int nt = 0; nt < 4; nt++)
                acc[mt][nt] = __builtin_amdgcn_mfma_f32_16x16x32_bf16(
                    af[mt], bfr[nt], acc[mt][nt], 0, 0, 0);
    }

    float* Pbase = P + (((size_t)(c * 32 + chain)) << 14);
#pragma unroll
    for (int mt = 0; mt < 4; mt++)
#pragma unroll
        for (int r = 0; r < 4; r++) {
            int e = wm + mt * 16 + lquad * 4 + r;
#pragma unroll
            for (int nt = 0; nt < 4; nt++) {
                int d = wn + nt * 16 + lrow;
                Pbase[(size_t)e * 128 + d] = acc[mt][nt][r];
            }
        }

    {
        int d = tid >> 1, jh = (tid & 1) * 32;
        int swz = ((d >> 5) & 3) << 4;
        float an = 0.f;
#pragma unroll
        for (int j = 0; j < 32; j++) {
            int jj = jh + j;
            an += sw[jj] * bfu(sKt[d][jj ^ swz]);
        }
        an += __shfl_xor(an, 1);
        if ((tid & 1) == 0) nP[(size_t)(c * 32 + chain) * 128 + d] = an;
    }
}

// Kernel B2: exclusive combine over chunks -> bf16 CB; also nP scan (seg 0 blocks).
__global__ __launch_bounds__(256) void chunk_combine_kernel(const float* __restrict__ P,
        u16* __restrict__ CB, float* __restrict__ nP, const float* __restrict__ gDec) {
    int chain = blockIdx.x >> 6;
    int seg = blockIdx.x & 63;
    int idx = seg * 256 + threadIdx.x;
    float run = 0.f;
    for (int c = 0; c < NCH; c++) {
        size_t a = (((size_t)(c * 32 + chain)) << 14) + idx;
        float tmp = P[a];
        CB[a] = f2bf(run);
        run = run * gDec[chain * NCH + c] + tmp;
    }
    if (seg == 0 && threadIdx.x < 128) {
        int d = threadIdx.x;
        float rn = 0.f;
        for (int c = 0; c < NCH; c++) {
            size_t a = (size_t)(c * 32 + chain) * 128 + d;
            float tmp = nP[a];
            nP[a] = rn;
            rn = rn * gDec[chain * NCH + c] + tmp;
        }
    }
}

// Kernel C: MFMA chunk outputs + fused per-head norm * hn_s * silu(z) -> bf16.
// q/k/v inputs are bf16.
__global__ __launch_bounds__(512, 2) void chunk_out_kernel(const u16* __restrict__ qq,
        const u16* __restrict__ kk, const u16* __restrict__ vv,
        const float* __restrict__ gG, const float* __restrict__ gM,
        const float* __restrict__ gMb, const u16* __restrict__ CB,
        const float* __restrict__ nP, const float* __restrict__ hn,
        const float* __restrict__ up, u16* __restrict__ out16) {
    int c = blockIdx.x, chain = blockIdx.y;
    int b = chain >> 3, h = chain & 7;
    int t0 = c * 64;
    int nvalid = min(64, TT - t0);
    __shared__ __align__(16) u16 smem[30720];   // 61.4 KB arena
    __shared__ float sG[64], sM[64], sWr[64], sInv[64], sNb[128], sRS[2][64];
    u16* sQ  = smem;            // [64][136] bf16   (phases 0-2)
    u16* sCB = smem + 8704;     // [128][136] bf16  (phase 0)
    u16* sK  = smem + 8704;     // [64][136] bf16   (phase 1, overlays sCB)
    u16* sVt = smem;            // [128][72] bf16   (phase 3, overlays sQ)
    u16* sD  = smem + 26112;    // [64][72] bf16    (phase 1 write, 3 read)
    float* hv = (float*)smem;   // [64][132] f32    (epilogue, overlays sQ/sVt)
    int tid = threadIdx.x;
    int wave = tid >> 6, lane = tid & 63;
    int lrow = lane & 15, lquad = lane >> 4;
    int mq = wave >> 1, nh = wave & 1;

    float Mbprev = (c > 0) ? gMb[chain * NCH + c - 1] : 0.f;
    if (tid < 64) {
        bool val = tid < nvalid;
        sG[tid] = val ? gG[chain * TT + t0 + tid] : -1e30f;
        float Mv = val ? gM[chain * TT + t0 + tid] : 1e30f;
        sM[tid] = Mv;
        sWr[tid] = val ? __expf(Mbprev - Mv) : 0.f;
    }
    if (tid >= 128 && tid < 256) sNb[tid - 128] = nP[(size_t)(c * 32 + chain) * 128 + (tid - 128)];

    ushort8v z8 = {0,0,0,0,0,0,0,0};
    // ---- stage sQ [64][136]
    {
        int lr = tid >> 3, c0 = (tid & 7) * 16;
        bool val = lr < nvalid;
        size_t gb = ((size_t)(b * TT + t0 + lr)) * IN + h * DHd + c0;
#pragma unroll
        for (int i = 0; i < 2; i++)
            *(ushort8v*)&sQ[lr * 136 + c0 + i * 8] =
                val ? *(const ushort8v*)(qq + gb + i * 8) : z8;
    }
    // ---- stage sCB [128][136] from bf16 CB[e][d]
    {
        const u16* CBbase = CB + (((size_t)(c * 32 + chain)) << 14);
        int e = tid >> 2, d0 = (tid & 3) * 32;
#pragma unroll
        for (int i = 0; i < 4; i++)
            *(ushort8v*)&sCB[e * 136 + d0 + i * 8] =
                *(const ushort8v*)(CBbase + (size_t)e * 128 + d0 + i * 8);
    }
    __syncthreads();

    // ---- phase 0: inter = Q @ CB, C-layout acc; then scale by wr
    f32x4 acc[4];
#pragma unroll
    for (int tt = 0; tt < 4; tt++)
#pragma unroll
        for (int r = 0; r < 4; r++) acc[tt][r] = 0.f;
#pragma unroll 1
    for (int ks = 0; ks < 4; ks++) {
        bf16x8 af = *(const bf16x8*)&sQ[(mq * 16 + lrow) * 136 + ks * 32 + lquad * 8];
#pragma unroll
        for (int tt = 0; tt < 4; tt++) {
            bf16x8 bf = *(const bf16x8*)&sCB[(nh * 64 + tt * 16 + lrow) * 136 + ks * 32 + lquad * 8];
            acc[tt] = __builtin_amdgcn_mfma_f32_16x16x32_bf16(af, bf, acc[tt], 0, 0, 0);
        }
    }
#pragma unroll
    for (int tt = 0; tt < 4; tt++)
#pragma unroll
        for (int r = 0; r < 4; r++) acc[tt][r] *= sWr[mq * 16 + lquad * 4 + r];
    __syncthreads();

    // ---- stage sK (overlays sCB)
    {
        int lr = tid >> 3, c0 = (tid & 7) * 16;
        bool val = lr < nvalid;
        size_t gb = ((size_t)(b * TT + t0 + lr)) * IN + h * DHd + c0;
#pragma unroll
        for (int i = 0; i < 2; i++)
            *(ushort8v*)&sK[lr * 136 + c0 + i * 8] =
                val ? *(const ushort8v*)(kk + gb + i * 8) : z8;
    }
    __syncthreads();

    // ---- phase 1: S = Q K^T (2 n-tiles/wave), weights, sD bf16, in-reg rowsums
    {
        f32x4 accS[2];
#pragma unroll
        for (int tt = 0; tt < 2; tt++)
#pragma unroll
            for (int r = 0; r < 4; r++) accS[tt][r] = 0.f;
#pragma unroll 1
        for (int ks = 0; ks < 4; ks++) {
            bf16x8 af = *(const bf16x8*)&sQ[(mq * 16 + lrow) * 136 + ks * 32 + lquad * 8];
#pragma unroll
            for (int tt = 0; tt < 2; tt++) {
                bf16x8 bf = *(const bf16x8*)&sK[((nh * 2 + tt) * 16 + lrow) * 136 + ks * 32 + lquad * 8];
                accS[tt] = __builtin_amdgcn_mfma_f32_16x16x32_bf16(af, bf, accS[tt], 0, 0, 0);
            }
        }
        float rsum[4] = {0.f, 0.f, 0.f, 0.f};
#pragma unroll
        for (int tt = 0; tt < 2; tt++) {
            int j = (nh * 2 + tt) * 16 + lrow;
            float Gj = sG[j];
#pragma unroll
            for (int r = 0; r < 4; r++) {
                int t = mq * 16 + lquad * 4 + r;
                float w = (j <= t) ? __expf(Gj - sM[t]) : 0.f;
                float wD = accS[tt][r] * w;
                rsum[r] += wD;
                sD[t * 72 + j] = f2bf(wD);
            }
        }
#pragma unroll
        for (int r = 0; r < 4; r++) {
#pragma unroll
            for (int msk = 1; msk < 16; msk <<= 1) rsum[r] += __shfl_xor(rsum[r], msk);
        }
        if (lrow == 0) {
#pragma unroll
            for (int r = 0; r < 4; r++) sRS[nh][mq * 16 + lquad * 4 + r] = rsum[r];
        }
    }
    __syncthreads();

    // ---- phase 2: denominators (tid<64); qnb from bf16 sQ
    if (tid < 64) {
        float qn = 0.f;
#pragma unroll 1
        for (int d4 = 0; d4 < 32; d4++) {
            ushort4v q4 = *(const ushort4v*)&sQ[tid * 136 + d4 * 4];
            float4 nb = *(const float4*)&sNb[d4 * 4];
            qn += bfu(q4.x) * nb.x + bfu(q4.y) * nb.y + bfu(q4.z) * nb.z + bfu(q4.w) * nb.w;
        }
        float den = sRS[0][tid] + sRS[1][tid] + sWr[tid] * qn;
        sInv[tid] = 1.f / fmaxf(fabsf(den), 1.f);
    }
    __syncthreads();

    // ---- stage sVt [128][72] = V^T bf16 (overlays sQ)
    {
        int e = tid & 127, tg = (tid >> 7) * 16;
#pragma unroll 1
        for (int i = 0; i < 16; i++) {
            int t = tg + i;
            sVt[e * 72 + t] = (t < nvalid) ? vv[((size_t)(b * TT + t0 + t)) * IN + h * DHd + e]
                                           : (u16)0;
        }
    }
    __syncthreads();

    // ---- phase 3: acc += D @ V
#pragma unroll 1
    for (int ks = 0; ks < 2; ks++) {
        bf16x8 af = *(const bf16x8*)&sD[(mq * 16 + lrow) * 72 + ks * 32 + lquad * 8];
#pragma unroll
        for (int tt = 0; tt < 4; tt++) {
            bf16x8 bf = *(const bf16x8*)&sVt[(nh * 64 + tt * 16 + lrow) * 72 + ks * 32 + lquad * 8];
            acc[tt] = __builtin_amdgcn_mfma_f32_16x16x32_bf16(af, bf, acc[tt], 0, 0, 0);
        }
    }

    // ---- epilogue: h rows -> LDS, fused head-norm * hn * silu(z) -> bf16 out
    __syncthreads();   // all waves done reading sVt/sD before overlay
#pragma unroll
    for (int tt = 0; tt < 4; tt++) {
#pragma unroll
        for (int r = 0; r < 4; r++) {
            int t = mq * 16 + lquad * 4 + r;
            int e = nh * 64 + tt * 16 + lrow;
            hv[t * 132 + e] = acc[tt][r] * sInv[t];
        }
    }
    __syncthreads();
    {
        int t = tid >> 3, s = tid & 7;
        float vals[16];
        float sum = 0.f, sq = 0.f;
#pragma unroll
        for (int i = 0; i < 16; i++) {
            float v = hv[t * 132 + s * 16 + i];
            vals[i] = v; sum += v; sq += v * v;
        }
#pragma unroll
        for (int m = 1; m < 8; m <<= 1) { sum += __shfl_xor(sum, m); sq += __shfl_xor(sq, m); }
        float mu = sum / DHd, var = sq / DHd - mu * mu, inv2 = rsqrtf(var + EPSV);
        if (t < nvalid) {
            size_t bt = (size_t)(b * TT + t0 + t);
            const float* zp = up + bt * (2 * IN) + IN + h * DHd + s * 16;
            u16* op = out16 + bt * IN + h * DHd + s * 16;
#pragma unroll
            for (int i = 0; i < 16; i++) {
                float hnv = hn[h * DHd + s * 16 + i];
                op[i] = f2bf((vals[i] - mu) * inv2 * hnv * siluf(zp[i]));
            }
        }
    }
}

// ---------------------------------------------------------------- head: fused cls LN+ReLU + FC
__global__ __launch_bounds__(256) void fc_kernel(const float* __restrict__ hbuf,
                                                 const float* __restrict__ fcls,
                                                 const float* __restrict__ fclb,
                                                 const float* __restrict__ fw,
                                                 const float* __restrict__ fb,
                                                 float* __restrict__ out) {
    __shared__ float svc[Bsz][Dm];
    __shared__ float sred[4][256];
    int tid = threadIdx.x;
    int j0 = blockIdx.x * 64;
    {
        int r = tid >> 6, lane = tid & 63;
        const float* hrow = hbuf + ((size_t)r * TT + TT - 1) * Dm;
        float v[8];
        float sum = 0.f, sq = 0.f;
#pragma unroll
        for (int k = 0; k < 8; k++) {
            v[k] = hrow[lane + k * 64];
            sum += v[k]; sq += v[k] * v[k];
        }
#pragma unroll
        for (int o = 32; o > 0; o >>= 1) { sum += __shfl_xor(sum, o); sq += __shfl_xor(sq, o); }
        float mu = sum / Dm, var = sq / Dm - mu * mu, inv = rsqrtf(var + EPSV);
#pragma unroll
        for (int k = 0; k < 8; k++) {
            int e = lane + k * 64;
            svc[r][e] = fmaxf((v[k] - mu) * inv * fcls[e] + fclb[e], 0.f);
        }
    }
    __syncthreads();
    int j = j0 + (tid & 63);
    int chunk = tid >> 6;
    int kbase = chunk * 128;
    float a0 = 0.f, a1 = 0.f, a2 = 0.f, a3 = 0.f;
    if (j < NCc) {
        const float* fwp = fw + (size_t)kbase * NCc + j;
#pragma unroll 4
        for (int kk = 0; kk < 128; kk++) {
            float w = fwp[(size_t)kk * NCc];
            a0 += svc[0][kbase + kk] * w;
            a1 += svc[1][kbase + kk] * w;
            a2 += svc[2][kbase + kk] * w;
            a3 += svc[3][kbase + kk] * w;
        }
    }
    int jl = tid & 63;
    sred[chunk][jl * 4 + 0] = a0;
    sred[chunk][jl * 4 + 1] = a1;
    sred[chunk][jl * 4 + 2] = a2;
    sred[chunk][jl * 4 + 3] = a3;
    __syncthreads();
    if (tid < 64) {
        int jj = j0 + tid;
        if (jj < NCc) {
            float bias = fb[jj];
#pragma unroll
            for (int b = 0; b < Bsz; b++) {
                float v = sred[0][tid * 4 + b] + sred[1][tid * 4 + b]
                        + sred[2][tid * 4 + b] + sred[3][tid * 4 + b];
                out[b * NCc + jj] = v + bias;
            }
        }
    }
}

// ---------------------------------------------------------------- gate weight transpose
__global__ __launch_bounds__(256) void gate_w_transpose(const float* __restrict__ wig,
                                                        const float* __restrict__ wfg,
                                                        float* __restrict__ wt) {
    int idx = blockIdx.x * 256 + threadIdx.x;
    int k = idx & 1023;
    int g = (idx >> 10) & 15;
    int blk = idx >> 14;
    const float* w = (g < 8) ? (wig + (size_t)blk * IN * NHh) : (wfg + (size_t)blk * IN * NHh);
    wt[idx] = w[k * NHh + (g & 7)];
}

// ---------------------------------------------------------------- launch
extern "C" void kernel_launch(void* const* d_in, const int* in_sizes, int n_in,
                              void* d_out, int out_size, void* d_ws, size_t ws_size,
                              hipStream_t stream) {
    const float* x      = (const float*)d_in[0];
    const float* cls    = (const float*)d_in[1];
    const float* ln_s   = (const float*)d_in[2];
    const float* ln_b   = (const float*)d_in[3];
    const float* w_up   = (const float*)d_in[4];
    const float* b_up   = (const float*)d_in[5];
    const float* conv_k = (const float*)d_in[6];
    const float* conv_b = (const float*)d_in[7];
    const float* w_q    = (const float*)d_in[8];
    const float* w_k    = (const float*)d_in[9];
    const float* w_v    = (const float*)d_in[10];
    const float* w_ig   = (const float*)d_in[11];
    const float* b_ig   = (const float*)d_in[12];
    const float* w_fg   = (const float*)d_in[13];
    const float* b_fg   = (const float*)d_in[14];
    const float* hn_s   = (const float*)d_in[15];
    const float* w_down = (const float*)d_in[16];
    const float* b_down = (const float*)d_in[17];
    const float* fcls   = (const float*)d_in[18];
    const float* fclb   = (const float*)d_in[19];
    const float* fc_w   = (const float*)d_in[20];
    const float* fc_b   = (const float*)d_in[21];
    float* out = (float*)d_out;

    float* ws = (float*)d_ws;
    size_t off = 0;
    float* f_h  = ws + off; off += (size_t)ROWS * Dm;
    float* f_up = ws + off; off += (size_t)ROWS * 2 * IN;
    float* f_ip = ws + off; off += (size_t)ROWS * NHh;
    float* f_fp = ws + off; off += (size_t)ROWS * NHh;
    float* g_G  = ws + off; off += 32 * TT;
    float* g_M  = ws + off; off += 32 * TT;
    float* g_Mb = ws + off; off += 32 * NCH;
    float* g_De = ws + off; off += 32 * NCH;
    float* g_P  = ws + off; off += (size_t)NCH * 32 * DHd * DHd;
    float* g_nP = ws + off; off += (size_t)NCH * 32 * DHd;
    float* g_wt = ws + off; off += 2 * 16 * IN;
    u16* g_CB  = (u16*)(ws + off); off += ((size_t)NCH * 32 * DHd * DHd + 1) / 2;
    u16* g_Wt  = (u16*)(ws + off); off += (2 * WT_STRIDE + 1) / 2;
    // padded bf16 staging (MPAD rows; pad rows read as garbage, outputs guarded)
    u16* f_xn16 = (u16*)(ws + off); off += ((size_t)MPAD * Dm) / 2;
    u16* f_xc16 = (u16*)(ws + off); off += ((size_t)MPAD * IN) / 2;
    u16* f_xu16 = (u16*)(ws + off); off += ((size_t)MPAD * IN) / 2;
    u16* f_xg16 = (u16*)(ws + off); off += ((size_t)ROWS * IN + 1) / 2;
    u16* f_q16  = (u16*)(ws + off); off += ((size_t)ROWS * IN + 1) / 2;
    u16* f_k16  = (u16*)(ws + off); off += ((size_t)ROWS * IN + 1) / 2;
    u16* f_v16  = (u16*)(ws + off); off += ((size_t)ROWS * IN + 1) / 2;

    const float kscale = 0.08838834764831845f; // DH^-0.5
    const int MB = (ROWS + 127) / 128;         // 17
    const int MB64 = (ROWS + 63) / 64;         // 33

    concat_kernel<<<(ROWS * Dm + 255) / 256, 256, 0, stream>>>(x, cls, f_h);
    gate_w_transpose<<<(2 * 16 * IN + 255) / 256, 256, 0, stream>>>(w_ig, w_fg, g_wt);
    w_transpose_kernel<<<dim3(1024, 10), 256, 0, stream>>>(w_up, w_q, w_k, w_v, w_down, g_Wt);

    for (int blk = 0; blk < 2; blk++) {
        const float* p_ln_s = ln_s + blk * Dm;
        const float* p_ln_b = ln_b + blk * Dm;
        const float* p_bup  = b_up + (size_t)blk * 2 * IN;
        const float* p_ck   = conv_k + (size_t)blk * IN * KK;
        const float* p_cb   = conv_b + (size_t)blk * IN;
        const float* p_big  = b_ig + (size_t)blk * NHh;
        const float* p_bfg  = b_fg + (size_t)blk * NHh;
        const float* p_hns  = hn_s + (size_t)blk * NHh * DHd;
        const float* p_bd   = b_down + (size_t)blk * Dm;
        const u16*   p_wt   = g_Wt + (size_t)blk * WT_STRIDE;

        ln_kernel<<<ROWS, 256, 0, stream>>>(f_h, p_ln_s, p_ln_b, f_xn16);

        up_gl_kernel<<<dim3(2 * IN / 128, MB), 256, 0, stream>>>(
            f_xn16, p_wt + WT_UP, p_bup, f_up);

        convgates_kernel<<<ROWS, 256, 0, stream>>>(
            f_up, p_ck, p_cb, g_wt + blk * 16 * IN, p_big, p_bfg,
            f_xc16, f_xu16, f_ip, f_fp);

        qkv_gl_kernel<<<dim3(24, MB), 256, 0, stream>>>(
            f_xc16, f_xu16, p_wt, f_q16, f_k16, f_v16, kscale);

        // chunkwise-parallel mLSTM
        gate_scan_kernel<<<32, 64, 0, stream>>>(f_ip, f_fp, g_G, g_M, g_Mb, g_De);
        chunk_state_kernel<<<dim3(NCH, 32), 256, 0, stream>>>(f_k16, f_v16, g_G, g_Mb, g_P, g_nP);
        chunk_combine_kernel<<<32 * 64, 256, 0, stream>>>(g_P, g_CB, g_nP, g_De);
        chunk_out_kernel<<<dim3(NCH, 32), 512, 0, stream>>>(f_q16, f_k16, f_v16, g_G, g_M, g_Mb,
                                                            g_CB, g_nP, p_hns, f_up, f_xg16);

        gemm_mfma_kernel<64, 64><<<dim3(Dm / 64, MB64), 256, 0, stream>>>(
            f_xg16, IN, p_wt + WT_DN, IN, p_bd, f_h, Dm, f_h, Dm, ROWS, 1.f);
    }

    fc_kernel<<<(NCc + 63) / 64, 256, 0, stream>>>(f_h, fcls, fclb, fc_w, fc_b, out);
}

// Round 5
// 405.265 us; speedup vs baseline: 1.2859x; 1.0340x over previous
//
#include <hip/hip_runtime.h>

// ---------------------------------------------------------------- constants
#define EPSV 1e-5f
constexpr int Bsz = 4, T0 = 512, Dm = 512, NHh = 8, KK = 4;
constexpr int TT = 513;
constexpr int IN = 1024, DHd = 128, NCc = 1000;
constexpr int ROWS = Bsz * TT; // 2052
constexpr int MPAD = 2176;     // 17*128 padded staging rows for gload GEMMs
constexpr int NCH = 9;         // chunks of 64: 8*64 + 1 = 513

// bf16 k-major weight buffer offsets (u16 elements), per transformer block
constexpr size_t WT_UP = 0;                      // [2048][512]
constexpr size_t WT_Q  = WT_UP + 2048 * 512;     // [1024][1024]
constexpr size_t WT_K  = WT_Q + 1024 * 1024;
constexpr size_t WT_V  = WT_K + 1024 * 1024;
constexpr size_t WT_DN = WT_V + 1024 * 1024;     // [512][1024]
constexpr size_t WT_STRIDE = WT_DN + 512 * 1024; // 4,718,592 u16

typedef __attribute__((ext_vector_type(8))) short bf16x8;
typedef __attribute__((ext_vector_type(4))) float f32x4;
typedef __attribute__((ext_vector_type(4))) unsigned short ushort4v;
typedef __attribute__((ext_vector_type(8))) unsigned short ushort8v;
typedef unsigned short u16;

__device__ __forceinline__ float siluf(float x) { return x / (1.f + __expf(-x)); }
__device__ __forceinline__ u16 f2bf(float f) {
    unsigned int u = __float_as_uint(f);
    u = (u + 0x7FFFu + ((u >> 16) & 1u)) >> 16;
    return (u16)u;
}
__device__ __forceinline__ float bfu(u16 u) {
    return __uint_as_float(((unsigned int)u) << 16);
}
// async global->LDS, 16 bytes per lane; LDS dest is wave-uniform base + lane*16
__device__ __forceinline__ void gload16(const u16* g, u16* l) {
    __builtin_amdgcn_global_load_lds(
        (const __attribute__((address_space(1))) void*)g,
        (__attribute__((address_space(3))) void*)l, 16, 0, 0);
}

// ---------------------------------------------------------------- LayerNorm rows of D=512 -> bf16
// CAT=true: read from x/cls (concat fused), also materialize f_h.
template<bool CAT>
__global__ __launch_bounds__(256) void ln_kernel(const float* __restrict__ in,
                                                 const float* __restrict__ x,
                                                 const float* __restrict__ cls,
                                                 const float* __restrict__ s,
                                                 const float* __restrict__ bb,
                                                 float* __restrict__ hout,
                                                 u16* __restrict__ out16) {
    int row = blockIdx.x, tid = threadIdx.x;
    float x0, x1;
    if (CAT) {
        int b = row / TT, t = row - b * TT;
        const float* src = (t < T0) ? (x + ((size_t)(b * T0 + t)) * Dm) : cls;
        x0 = src[tid]; x1 = src[tid + 256];
        hout[(size_t)row * Dm + tid] = x0;
        hout[(size_t)row * Dm + tid + 256] = x1;
    } else {
        const float* r = in + (size_t)row * Dm;
        x0 = r[tid]; x1 = r[tid + 256];
    }
    __shared__ float s1[4], s2[4];
    float sum = x0 + x1, sq = x0 * x0 + x1 * x1;
#pragma unroll
    for (int o = 32; o > 0; o >>= 1) { sum += __shfl_xor(sum, o); sq += __shfl_xor(sq, o); }
    if ((tid & 63) == 0) { s1[tid >> 6] = sum; s2[tid >> 6] = sq; }
    __syncthreads();
    sum = s1[0] + s1[1] + s1[2] + s1[3];
    sq  = s2[0] + s2[1] + s2[2] + s2[3];
    float mu = sum / Dm, var = sq / Dm - mu * mu, inv = rsqrtf(var + EPSV);
    out16[(size_t)row * Dm + tid]       = f2bf((x0 - mu) * inv * s[tid] + bb[tid]);
    out16[(size_t)row * Dm + tid + 256] = f2bf((x1 - mu) * inv * s[tid + 256] + bb[tid + 256]);
}

// ---------------------------------------------------------------- weight transpose f32 KxN -> bf16 [N][K]
// y in [0,12): 0..9 = matmul weights, 10..11 = gate weight transpose for blk 0/1.
__global__ __launch_bounds__(256) void w_transpose_kernel(const float* __restrict__ wup,
        const float* __restrict__ wq, const float* __restrict__ wk,
        const float* __restrict__ wv, const float* __restrict__ wdn,
        const float* __restrict__ wig, const float* __restrict__ wfg,
        u16* __restrict__ wt, float* __restrict__ gwt) {
    int y = blockIdx.y;
    if (y >= 10) {
        int blk = y - 10;
        int idx = blockIdx.x * 256 + threadIdx.x;
        if (idx < 16 * IN) {
            int k = idx & 1023;
            int g = (idx >> 10) & 15;
            const float* w = (g < 8) ? (wig + (size_t)blk * IN * NHh)
                                     : (wfg + (size_t)blk * IN * NHh);
            gwt[(size_t)blk * 16 * IN + idx] = w[k * NHh + (g & 7)];
        }
        return;
    }
    int blk = y / 5, sel = y - blk * 5;
    int Kd, N; const float* src; size_t doff;
    if (sel == 0)      { Kd = 512;  N = 2048; src = wup + (size_t)blk * 512 * 2048; doff = WT_UP; }
    else if (sel == 1) { Kd = 1024; N = 1024; src = wq  + (size_t)blk * 1024 * 1024; doff = WT_Q; }
    else if (sel == 2) { Kd = 1024; N = 1024; src = wk  + (size_t)blk * 1024 * 1024; doff = WT_K; }
    else if (sel == 3) { Kd = 1024; N = 1024; src = wv  + (size_t)blk * 1024 * 1024; doff = WT_V; }
    else               { Kd = 1024; N = 512;  src = wdn + (size_t)blk * 1024 * 512;  doff = WT_DN; }
    u16* dst = wt + (size_t)blk * WT_STRIDE + doff;
    int ntx = N >> 5;
    int ntiles = ntx * (Kd >> 5);
    int ti = blockIdx.x;
    if (ti >= ntiles) return;
    int tk = ti / ntx, tn = ti - tk * ntx;
    __shared__ u16 s[32][33];
    int tx = threadIdx.x & 31, ty = threadIdx.x >> 5;
#pragma unroll
    for (int i = 0; i < 4; i++) {
        int k = tk * 32 + ty + i * 8;
        s[ty + i * 8][tx] = f2bf(src[(size_t)k * N + tn * 32 + tx]);
    }
    __syncthreads();
#pragma unroll
    for (int i = 0; i < 4; i++) {
        int n = tn * 32 + ty + i * 8;
        dst[(size_t)n * Kd + tk * 32 + tx] = s[tx][ty + i * 8];
    }
}

// ---------------------------------------------------------------- legacy MFMA GEMM (down-proj)
template<int BM, int BN>
__device__ __forceinline__ void gemm_tile_body(const u16* __restrict__ A, int lda,
                                               const u16* __restrict__ Wt, int Kd,
                                               const float* __restrict__ bias,
                                               const float* __restrict__ resid, int ldr,
                                               float* __restrict__ Cout, int ldc,
                                               int M, float scale, int m0, int n0,
                                               u16 (*As)[BM][40], u16 (*Bs)[BN][40]) {
    constexpr int MT = BM / 32;
    constexpr int NT = BN / 32;
    constexpr int ANV = BM / 64;
    constexpr int BNV = BN / 64;
    int tid = threadIdx.x;
    int wave = tid >> 6, lane = tid & 63;
    int wm = (wave >> 1) * (BM / 2), wn = (wave & 1) * (BN / 2);
    int lrow = lane & 15, lquad = lane >> 4;

    f32x4 acc[MT][NT];
#pragma unroll
    for (int i = 0; i < MT; i++)
#pragma unroll
        for (int j = 0; j < NT; j++)
#pragma unroll
            for (int r = 0; r < 4; r++) acc[i][j][r] = 0.f;

    int am, ak, bn, bk;
    if (BM == 128) { am = tid >> 1; ak = (tid & 1) * 16; }
    else           { am = tid >> 2; ak = (tid & 3) * 8; }
    if (BN == 128) { bn = tid & 127; bk = (tid >> 7) * 16; }
    else           { bn = tid & 63;  bk = (tid >> 6) * 8; }
    int gm = m0 + am;
    const u16* arow = A + (size_t)(gm < M ? gm : 0) * lda + ak;
    bool avalid = gm < M;
    const u16* wrow = Wt + (size_t)(n0 + bn) * Kd + bk;

    ushort8v areg[ANV];
    ushort8v breg[BNV];

    auto load_tile = [&](int k0) {
        if (avalid) {
#pragma unroll
            for (int i = 0; i < ANV; i++) areg[i] = *(const ushort8v*)(arow + k0 + i * 8);
        } else {
#pragma unroll
            for (int i = 0; i < ANV; i++) areg[i] = (ushort8v){0,0,0,0,0,0,0,0};
        }
#pragma unroll
        for (int i = 0; i < BNV; i++) breg[i] = *(const ushort8v*)(wrow + k0 + i * 8);
    };
    auto store_tile = [&](int buf) {
#pragma unroll
        for (int i = 0; i < ANV; i++)
            *(ushort8v*)&As[buf][am][ak + i * 8] = areg[i];
#pragma unroll
        for (int i = 0; i < BNV; i++)
            *(ushort8v*)&Bs[buf][bn][bk + i * 8] = breg[i];
    };

    load_tile(0);
    store_tile(0);
    __syncthreads();

    int nk = Kd >> 5;
#pragma unroll 1
    for (int it = 0; it < nk; it++) {
        int cur = it & 1;
        bool more = (it + 1 < nk);
        if (more) load_tile((it + 1) << 5);
        bf16x8 afr[MT], bfr[NT];
#pragma unroll
        for (int mt = 0; mt < MT; mt++)
            afr[mt] = *(const bf16x8*)&As[cur][wm + mt * 16 + lrow][lquad * 8];
#pragma unroll
        for (int nt = 0; nt < NT; nt++)
            bfr[nt] = *(const bf16x8*)&Bs[cur][wn + nt * 16 + lrow][lquad * 8];
#pragma unroll
        for (int mt = 0; mt < MT; mt++)
#pragma unroll
            for (int nt = 0; nt < NT; nt++)
                acc[mt][nt] = __builtin_amdgcn_mfma_f32_16x16x32_bf16(
                    afr[mt], bfr[nt], acc[mt][nt], 0, 0, 0);
        if (more) store_tile(cur ^ 1);
        __syncthreads();
    }

#pragma unroll
    for (int mt = 0; mt < MT; mt++) {
#pragma unroll
        for (int r = 0; r < 4; r++) {
            int gmr = m0 + wm + mt * 16 + lquad * 4 + r;
            if (gmr >= M) continue;
#pragma unroll
            for (int nt = 0; nt < NT; nt++) {
                int gn = n0 + wn + nt * 16 + lrow;
                float v = acc[mt][nt][r] * scale;
                if (bias) v += bias[gn];
                if (resid) v += resid[(size_t)gmr * ldr + gn];
                Cout[(size_t)gmr * ldc + gn] = v;
            }
        }
    }
}

template<int BM, int BN>
__global__ __launch_bounds__(256, 2) void gemm_mfma_kernel(const u16* __restrict__ A, int lda,
                                                           const u16* __restrict__ Wt, int Kd,
                                                           const float* __restrict__ bias,
                                                           const float* __restrict__ resid, int ldr,
                                                           float* __restrict__ Cout, int ldc,
                                                           int M, float scale) {
    __shared__ __align__(16) u16 As[2][BM][40];
    __shared__ __align__(16) u16 Bs[2][BN][40];
    gemm_tile_body<BM, BN>(A, lda, Wt, Kd, bias, resid, ldr, Cout, ldc, M, scale,
                           blockIdx.y * BM, blockIdx.x * BN, As, Bs);
}

// ---------------------------------------------------------------- m97-style 128x128 gload GEMM
template<bool OUT16>
__device__ __forceinline__ void gemm128_body(const u16* __restrict__ A, int lda,
                                             const u16* __restrict__ Wt, int Kd,
                                             const float* __restrict__ bias,
                                             void* __restrict__ Cout, int ldc,
                                             int M, float scale, int m0, int n0,
                                             u16* As, u16* Bs) {
    int tid = threadIdx.x;
    int wave = tid >> 6, lane = tid & 63;
    int lrow = lane & 15, lquad = lane >> 4;
    int wm = (wave >> 1) * 64, wn = (wave & 1) * 64;

    const u16* ag0 = A + (size_t)(m0 + wave * 16 + (lane >> 2)) * lda + (lane & 3) * 8;
    const u16* ag1 = ag0 + (size_t)64 * lda;
    const u16* bg0 = Wt + (size_t)(n0 + wave * 16 + (lane >> 2)) * Kd + (lane & 3) * 8;
    const u16* bg1 = bg0 + (size_t)64 * Kd;

    auto stage = [&](int buf, int k0) {
        u16* a = As + buf * 4096 + wave * 512;
        u16* bb = Bs + buf * 4096 + wave * 512;
        gload16(ag0 + k0, a);
        gload16(ag1 + k0, a + 2048);
        gload16(bg0 + k0, bb);
        gload16(bg1 + k0, bb + 2048);
    };

    f32x4 acc[4][4];
#pragma unroll
    for (int i = 0; i < 4; i++)
#pragma unroll
        for (int j = 0; j < 4; j++)
#pragma unroll
            for (int r = 0; r < 4; r++) acc[i][j][r] = 0.f;

    int nk = Kd >> 5;
    stage(0, 0);
    __syncthreads();
#pragma unroll 1
    for (int it = 0; it < nk; it++) {
        int cur = it & 1;
        if (it + 1 < nk) stage(cur ^ 1, (it + 1) << 5);   // prefetch overlaps MFMA
        const u16* Ac = As + cur * 4096;
        const u16* Bc = Bs + cur * 4096;
        bf16x8 afr[4], bfr[4];
#pragma unroll
        for (int mt = 0; mt < 4; mt++)
            afr[mt] = *(const bf16x8*)&Ac[(wm + mt * 16 + lrow) * 32 + lquad * 8];
#pragma unroll
        for (int nt = 0; nt < 4; nt++)
            bfr[nt] = *(const bf16x8*)&Bc[(wn + nt * 16 + lrow) * 32 + lquad * 8];
#pragma unroll
        for (int mt = 0; mt < 4; mt++)
#pragma unroll
            for (int nt = 0; nt < 4; nt++)
                acc[mt][nt] = __builtin_amdgcn_mfma_f32_16x16x32_bf16(
                    afr[mt], bfr[nt], acc[mt][nt], 0, 0, 0);
        __syncthreads();
    }

#pragma unroll
    for (int mt = 0; mt < 4; mt++) {
#pragma unroll
        for (int r = 0; r < 4; r++) {
            int gmr = m0 + wm + mt * 16 + lquad * 4 + r;
            if (gmr >= M) continue;
#pragma unroll
            for (int nt = 0; nt < 4; nt++) {
                int gn = n0 + wn + nt * 16 + lrow;
                float v = acc[mt][nt][r] * scale;
                if (bias) v += bias[gn];
                if (OUT16) ((u16*)Cout)[(size_t)gmr * ldc + gn] = f2bf(v);
                else       ((float*)Cout)[(size_t)gmr * ldc + gn] = v;
            }
        }
    }
}

__global__ __launch_bounds__(256, 2) void up_gl_kernel(const u16* __restrict__ A,
        const u16* __restrict__ Wt, const float* __restrict__ bias, float* __restrict__ C) {
    __shared__ __align__(16) u16 As[2 * 4096];
    __shared__ __align__(16) u16 Bs[2 * 4096];
    gemm128_body<false>(A, Dm, Wt, Dm, bias, C, 2 * IN, ROWS, 1.f,
                        blockIdx.y * 128, blockIdx.x * 128, As, Bs);
}

__global__ __launch_bounds__(256, 2) void qkv_gl_kernel(const u16* __restrict__ xc16,
                                                        const u16* __restrict__ xu16,
                                                        const u16* __restrict__ wtblk,
                                                        u16* __restrict__ fq,
                                                        u16* __restrict__ fk,
                                                        u16* __restrict__ fv,
                                                        float kscale) {
    __shared__ __align__(16) u16 As[2 * 4096];
    __shared__ __align__(16) u16 Bs[2 * 4096];
    int sel = blockIdx.x >> 3, nx = blockIdx.x & 7;
    const u16* A = (sel == 2) ? xu16 : xc16;
    const u16* Wt = wtblk + ((sel == 0) ? WT_Q : (sel == 1) ? WT_K : WT_V);
    u16* C = (sel == 0) ? fq : (sel == 1) ? fk : fv;
    float scale = (sel == 1) ? kscale : 1.f;
    gemm128_body<true>(A, IN, Wt, IN, nullptr, C, IN, ROWS, scale,
                       blockIdx.y * 128, nx * 128, As, Bs);
}

// ---------------------------------------------------------------- fused causal conv + SiLU + gate projections
__global__ __launch_bounds__(256) void convgates_kernel(const float* __restrict__ up,
        const float* __restrict__ ck, const float* __restrict__ cb,
        const float* __restrict__ wt, const float* __restrict__ big,
        const float* __restrict__ bfg,
        u16* __restrict__ xc16, u16* __restrict__ xu16,
        float* __restrict__ ip, float* __restrict__ fp) {
    int row = blockIdx.x, tid = threadIdx.x;
    int b = row / TT, t = row - b * TT;
    __shared__ float sx[IN];
    int c0 = tid * 4;
    float4 cur = *(const float4*)(up + (size_t)row * (2 * IN) + c0);
    float a0 = cb[c0 + 0] + cur.x * ck[(c0 + 0) * KK + 3];
    float a1 = cb[c0 + 1] + cur.y * ck[(c0 + 1) * KK + 3];
    float a2 = cb[c0 + 2] + cur.z * ck[(c0 + 2) * KK + 3];
    float a3 = cb[c0 + 3] + cur.w * ck[(c0 + 3) * KK + 3];
#pragma unroll
    for (int j = 0; j < KK - 1; j++) {
        int tt2 = t - (KK - 1) + j;
        if (tt2 >= 0) {
            float4 pv = *(const float4*)(up + ((size_t)(b * TT + tt2)) * (2 * IN) + c0);
            a0 += pv.x * ck[(c0 + 0) * KK + j];
            a1 += pv.y * ck[(c0 + 1) * KK + j];
            a2 += pv.z * ck[(c0 + 2) * KK + j];
            a3 += pv.w * ck[(c0 + 3) * KK + j];
        }
    }
    float s0 = siluf(a0), s1v = siluf(a1), s2v = siluf(a2), s3v = siluf(a3);
    *(float4*)&sx[c0] = make_float4(s0, s1v, s2v, s3v);
    ushort4v xc4 = {f2bf(s0), f2bf(s1v), f2bf(s2v), f2bf(s3v)};
    *(ushort4v*)&xc16[(size_t)row * IN + c0] = xc4;
    ushort4v xu4 = {f2bf(cur.x), f2bf(cur.y), f2bf(cur.z), f2bf(cur.w)};
    *(ushort4v*)&xu16[(size_t)row * IN + c0] = xu4;
    __syncthreads();

    int g = tid >> 4, l = tid & 15;
    const float* wrow = wt + g * IN;
    float acc = 0.f;
#pragma unroll
    for (int j = 0; j < 16; j++) {
        int k = j * 64 + l * 4;
        float4 w4 = *(const float4*)(wrow + k);
        float4 x4 = *(const float4*)&sx[k];
        acc += w4.x * x4.x + w4.y * x4.y + w4.z * x4.z + w4.w * x4.w;
    }
#pragma unroll
    for (int o = 8; o > 0; o >>= 1) acc += __shfl_down(acc, o, 16);
    if (l == 0) {
        if (g < 8) ip[(size_t)row * NHh + g] = acc + big[g];
        else       fp[(size_t)row * NHh + (g - 8)] = acc + bfg[g - 8];
    }
}

// ---------------------------------------------------------------- chunkwise mLSTM
// Kernel B1: fused gate scan + per-chunk local state via MFMA. P stored bf16 [e][d].
// Wave 0 of each block recomputes the chain's gate scan (cheap, 4KB reads);
// the c==0 block publishes gG/gM/gMb/gDec for chunk_out / combine.
__global__ __launch_bounds__(256, 2) void chunk_state_kernel(const u16* __restrict__ kk,
        const u16* __restrict__ vv, const float* __restrict__ ip,
        const float* __restrict__ fp, float* __restrict__ gG, float* __restrict__ gM,
        float* __restrict__ gMb, float* __restrict__ gDec,
        u16* __restrict__ P16, float* __restrict__ nP) {
    int c = blockIdx.x, chain = blockIdx.y;
    int b = chain >> 3, h = chain & 7;
    int t0 = c * 64;
    int nvalid = min(64, TT - t0);
    __shared__ __align__(16) u16 sWv[128][72];   // [e][j] = w_j * V[j][e]
    __shared__ __align__(16) u16 sKt[128][72];   // [d][j] = K[j][d]
    __shared__ float sw[64];
    __shared__ float sGf[TT];
    __shared__ float sMbl[NCH];
    int tid = threadIdx.x;

    // ---- wave 0: full-chain gate scan (identical to old gate_scan_kernel)
    if (tid < 64) {
        constexpr int PER = 9;
        int lane = tid;
        int tbase = lane * PER;
        float lcs[PER], gi[PER];
        float csum = 0.f;
#pragma unroll
        for (int i = 0; i < PER; i++) {
            int t = tbase + i;
            float fpv = 0.f, ipv = 0.f;
            if (t < TT) {
                size_t gidx = (size_t)(b * TT + t) * NHh + h;
                fpv = fp[gidx]; ipv = ip[gidx];
            }
            float flv = (fpv >= 0.f) ? -log1pf(__expf(-fpv)) : (fpv - log1pf(__expf(fpv)));
            if (t >= TT) flv = 0.f;
            csum += flv;
            lcs[i] = csum;
            gi[i] = ipv;
        }
        float ps = csum;
#pragma unroll
        for (int o = 1; o < 64; o <<= 1) {
            float v = __shfl_up(ps, o);
            if (lane >= o) ps += v;
        }
        float Fexcl = ps - csum;
        float G[PER];
        float cmax = -1e30f;
#pragma unroll
        for (int i = 0; i < PER; i++) {
            int t = tbase + i;
            G[i] = (t < TT) ? (gi[i] - (Fexcl + lcs[i])) : -1e30f;
            cmax = fmaxf(cmax, G[i]);
            lcs[i] = cmax;
        }
        float pm = cmax;
#pragma unroll
        for (int o = 1; o < 64; o <<= 1) {
            float v = __shfl_up(pm, o);
            if (lane >= o) pm = fmaxf(pm, v);
        }
        float Me = __shfl_up(pm, 1);
        if (lane == 0) Me = -1e30f;
#pragma unroll
        for (int i = 0; i < PER; i++) {
            int t = tbase + i;
            if (t < TT) {
                float Mt = fmaxf(0.f, fmaxf(Me, lcs[i]));
                sGf[t] = G[i];
                if (c == 0) { gG[chain * TT + t] = G[i]; gM[chain * TT + t] = Mt; }
                if (((t & 63) == 63) || t == TT - 1) sMbl[t >> 6] = Mt;
            }
        }
    }
    __syncthreads();
    if (c == 0 && tid < NCH) {
        float Mbv = sMbl[tid];
        float Mbp = (tid == 0) ? 0.f : sMbl[tid - 1];
        gMb[chain * NCH + tid] = Mbv;
        gDec[chain * NCH + tid] = __expf(Mbp - Mbv);
    }
    if (tid < 64) {
        float Mb = sMbl[c];
        sw[tid] = (tid < nvalid) ? __expf(sGf[t0 + tid] - Mb) : 0.f;
    }
    __syncthreads();

    // ---- stage transposed bf16 tiles
    {
        int j = tid >> 2, d0 = (tid & 3) * 32;
        bool val = j < nvalid;
        float wj = sw[j];
        size_t gb = ((size_t)(b * TT + t0 + j)) * IN + h * DHd + d0;
        ushort8v z8 = {0,0,0,0,0,0,0,0};
#pragma unroll
        for (int i = 0; i < 4; i++) {
            ushort8v k8 = val ? *(const ushort8v*)(kk + gb + i * 8) : z8;
            ushort8v v8 = val ? *(const ushort8v*)(vv + gb + i * 8) : z8;
#pragma unroll
            for (int e = 0; e < 8; e++) {
                int dd = d0 + i * 8 + e;
                int jc = j ^ (((dd >> 5) & 3) << 4);       // column swizzle
                sKt[dd][jc] = k8[e];
                sWv[dd][jc] = f2bf(bfu(v8[e]) * wj);
            }
        }
    }
    __syncthreads();

    int wave = tid >> 6, lane = tid & 63;
    int lrow = lane & 15, lquad = lane >> 4;
    int wm = (wave >> 1) * 64, wn = (wave & 1) * 64;
    f32x4 acc[4][4];
#pragma unroll
    for (int mt = 0; mt < 4; mt++)
#pragma unroll
        for (int nt = 0; nt < 4; nt++)
#pragma unroll
            for (int r = 0; r < 4; r++) acc[mt][nt][r] = 0.f;

#pragma unroll
    for (int ks = 0; ks < 2; ks++) {
        bf16x8 af[4], bfr[4];
#pragma unroll
        for (int mt = 0; mt < 4; mt++) {
            int r = wm + mt * 16 + lrow;
            int g = (ks * 4 + lquad) ^ (((r >> 5) & 3) << 1);
            af[mt] = *(const bf16x8*)&sWv[r][g * 8];
        }
#pragma unroll
        for (int nt = 0; nt < 4; nt++) {
            int r = wn + nt * 16 + lrow;
            int g = (ks * 4 + lquad) ^ (((r >> 5) & 3) << 1);
            bfr[nt] = *(const bf16x8*)&sKt[r][g * 8];
        }
#pragma unroll
        for (int mt = 0; mt < 4; mt++)
#pragma unroll
            for (int nt = 0; nt < 4; nt++)
                acc[mt][nt] = __builtin_amdgcn_mfma_f32_16x16x32_bf16(
                    af[mt], bfr[nt], acc[mt][nt], 0, 0, 0);
    }

    u16* Pbase = P16 + (((size_t)(c * 32 + chain)) << 14);
#pragma unroll
    for (int mt = 0; mt < 4; mt++)
#pragma unroll
        for (int r = 0; r < 4; r++) {
            int e = wm + mt * 16 + lquad * 4 + r;
#pragma unroll
            for (int nt = 0; nt < 4; nt++) {
                int d = wn + nt * 16 + lrow;
                Pbase[(size_t)e * 128 + d] = f2bf(acc[mt][nt][r]);
            }
        }

    {
        int d = tid >> 1, jh = (tid & 1) * 32;
        int swz = ((d >> 5) & 3) << 4;
        float an = 0.f;
#pragma unroll
        for (int j = 0; j < 32; j++) {
            int jj = jh + j;
            an += sw[jj] * bfu(sKt[d][jj ^ swz]);
        }
        an += __shfl_xor(an, 1);
        if ((tid & 1) == 0) nP[(size_t)(c * 32 + chain) * 128 + d] = an;
    }
}

// Kernel B2: exclusive combine over chunks (bf16 P -> bf16 CB); nP scan in seg 0.
__global__ __launch_bounds__(256) void chunk_combine_kernel(const u16* __restrict__ P16,
        u16* __restrict__ CB, float* __restrict__ nP, const float* __restrict__ gDec) {
    int chain = blockIdx.x >> 6;
    int seg = blockIdx.x & 63;
    int idx = seg * 256 + threadIdx.x;
    float run = 0.f;
    for (int c = 0; c < NCH; c++) {
        size_t a = (((size_t)(c * 32 + chain)) << 14) + idx;
        float tmp = bfu(P16[a]);
        CB[a] = f2bf(run);
        run = run * gDec[chain * NCH + c] + tmp;
    }
    if (seg == 0 && threadIdx.x < 128) {
        int d = threadIdx.x;
        float rn = 0.f;
        for (int c = 0; c < NCH; c++) {
            size_t a = (size_t)(c * 32 + chain) * 128 + d;
            float tmp = nP[a];
            nP[a] = rn;
            rn = rn * gDec[chain * NCH + c] + tmp;
        }
    }
}

// Kernel C: MFMA chunk outputs + fused per-head norm * hn_s * silu(z) -> bf16.
__global__ __launch_bounds__(512, 2) void chunk_out_kernel(const u16* __restrict__ qq,
        const u16* __restrict__ kk, const u16* __restrict__ vv,
        const float* __restrict__ gG, const float* __restrict__ gM,
        const float* __restrict__ gMb, const u16* __restrict__ CB,
        const float* __restrict__ nP, const float* __restrict__ hn,
        const float* __restrict__ up, u16* __restrict__ out16) {
    int c = blockIdx.x, chain = blockIdx.y;
    int b = chain >> 3, h = chain & 7;
    int t0 = c * 64;
    int nvalid = min(64, TT - t0);
    __shared__ __align__(16) u16 smem[30720];   // 61.4 KB arena
    __shared__ float sG[64], sM[64], sWr[64], sInv[64], sNb[128], sRS[2][64];
    u16* sQ  = smem;            // [64][136] bf16   (phases 0-2)
    u16* sCB = smem + 8704;     // [128][136] bf16  (phase 0)
    u16* sK  = smem + 8704;     // [64][136] bf16   (phase 1, overlays sCB)
    u16* sVt = smem;            // [128][72] bf16   (phase 3, overlays sQ)
    u16* sD  = smem + 26112;    // [64][72] bf16    (phase 1 write, 3 read)
    float* hv = (float*)smem;   // [64][132] f32    (epilogue, overlays sQ/sVt)
    int tid = threadIdx.x;
    int wave = tid >> 6, lane = tid & 63;
    int lrow = lane & 15, lquad = lane >> 4;
    int mq = wave >> 1, nh = wave & 1;

    float Mbprev = (c > 0) ? gMb[chain * NCH + c - 1] : 0.f;
    if (tid < 64) {
        bool val = tid < nvalid;
        sG[tid] = val ? gG[chain * TT + t0 + tid] : -1e30f;
        float Mv = val ? gM[chain * TT + t0 + tid] : 1e30f;
        sM[tid] = Mv;
        sWr[tid] = val ? __expf(Mbprev - Mv) : 0.f;
    }
    if (tid >= 128 && tid < 256) sNb[tid - 128] = nP[(size_t)(c * 32 + chain) * 128 + (tid - 128)];

    ushort8v z8 = {0,0,0,0,0,0,0,0};
    // ---- stage sQ [64][136]
    {
        int lr = tid >> 3, c0 = (tid & 7) * 16;
        bool val = lr < nvalid;
        size_t gb = ((size_t)(b * TT + t0 + lr)) * IN + h * DHd + c0;
#pragma unroll
        for (int i = 0; i < 2; i++)
            *(ushort8v*)&sQ[lr * 136 + c0 + i * 8] =
                val ? *(const ushort8v*)(qq + gb + i * 8) : z8;
    }
    // ---- stage sCB [128][136] from bf16 CB[e][d]
    {
        const u16* CBbase = CB + (((size_t)(c * 32 + chain)) << 14);
        int e = tid >> 2, d0 = (tid & 3) * 32;
#pragma unroll
        for (int i = 0; i < 4; i++)
            *(ushort8v*)&sCB[e * 136 + d0 + i * 8] =
                *(const ushort8v*)(CBbase + (size_t)e * 128 + d0 + i * 8);
    }
    __syncthreads();

    // ---- phase 0: inter = Q @ CB, C-layout acc; then scale by wr
    f32x4 acc[4];
#pragma unroll
    for (int tt = 0; tt < 4; tt++)
#pragma unroll
        for (int r = 0; r < 4; r++) acc[tt][r] = 0.f;
#pragma unroll 1
    for (int ks = 0; ks < 4; ks++) {
        bf16x8 af = *(const bf16x8*)&sQ[(mq * 16 + lrow) * 136 + ks * 32 + lquad * 8];
#pragma unroll
        for (int tt = 0; tt < 4; tt++) {
            bf16x8 bf = *(const bf16x8*)&sCB[(nh * 64 + tt * 16 + lrow) * 136 + ks * 32 + lquad * 8];
            acc[tt] = __builtin_amdgcn_mfma_f32_16x16x32_bf16(af, bf, acc[tt], 0, 0, 0);
        }
    }
#pragma unroll
    for (int tt = 0; tt < 4; tt++)
#pragma unroll
        for (int r = 0; r < 4; r++) acc[tt][r] *= sWr[mq * 16 + lquad * 4 + r];
    __syncthreads();

    // ---- stage sK (overlays sCB)
    {
        int lr = tid >> 3, c0 = (tid & 7) * 16;
        bool val = lr < nvalid;
        size_t gb = ((size_t)(b * TT + t0 + lr)) * IN + h * DHd + c0;
#pragma unroll
        for (int i = 0; i < 2; i++)
            *(ushort8v*)&sK[lr * 136 + c0 + i * 8] =
                val ? *(const ushort8v*)(kk + gb + i * 8) : z8;
    }
    __syncthreads();

    // ---- phase 1: S = Q K^T (2 n-tiles/wave), weights, sD bf16, in-reg rowsums
    {
        f32x4 accS[2];
#pragma unroll
        for (int tt = 0; tt < 2; tt++)
#pragma unroll
            for (int r = 0; r < 4; r++) accS[tt][r] = 0.f;
#pragma unroll 1
        for (int ks = 0; ks < 4; ks++) {
            bf16x8 af = *(const bf16x8*)&sQ[(mq * 16 + lrow) * 136 + ks * 32 + lquad * 8];
#pragma unroll
            for (int tt = 0; tt < 2; tt++) {
                bf16x8 bf = *(const bf16x8*)&sK[((nh * 2 + tt) * 16 + lrow) * 136 + ks * 32 + lquad * 8];
                accS[tt] = __builtin_amdgcn_mfma_f32_16x16x32_bf16(af, bf, accS[tt], 0, 0, 0);
            }
        }
        float rsum[4] = {0.f, 0.f, 0.f, 0.f};
#pragma unroll
        for (int tt = 0; tt < 2; tt++) {
            int j = (nh * 2 + tt) * 16 + lrow;
            float Gj = sG[j];
#pragma unroll
            for (int r = 0; r < 4; r++) {
                int t = mq * 16 + lquad * 4 + r;
                float w = (j <= t) ? __expf(Gj - sM[t]) : 0.f;
                float wD = accS[tt][r] * w;
                rsum[r] += wD;
                sD[t * 72 + j] = f2bf(wD);
            }
        }
#pragma unroll
        for (int r = 0; r < 4; r++) {
#pragma unroll
            for (int msk = 1; msk < 16; msk <<= 1) rsum[r] += __shfl_xor(rsum[r], msk);
        }
        if (lrow == 0) {
#pragma unroll
            for (int r = 0; r < 4; r++) sRS[nh][mq * 16 + lquad * 4 + r] = rsum[r];
        }
    }
    __syncthreads();

    // ---- phase 2: denominators (tid<64); qnb from bf16 sQ
    if (tid < 64) {
        float qn = 0.f;
#pragma unroll 1
        for (int d4 = 0; d4 < 32; d4++) {
            ushort4v q4 = *(const ushort4v*)&sQ[tid * 136 + d4 * 4];
            float4 nb = *(const float4*)&sNb[d4 * 4];
            qn += bfu(q4.x) * nb.x + bfu(q4.y) * nb.y + bfu(q4.z) * nb.z + bfu(q4.w) * nb.w;
        }
        float den = sRS[0][tid] + sRS[1][tid] + sWr[tid] * qn;
        sInv[tid] = 1.f / fmaxf(fabsf(den), 1.f);
    }
    __syncthreads();

    // ---- stage sVt [128][72] = V^T bf16 (overlays sQ)
    {
        int e = tid & 127, tg = (tid >> 7) * 16;
#pragma unroll 1
        for (int i = 0; i < 16; i++) {
            int t = tg + i;
            sVt[e * 72 + t] = (t < nvalid) ? vv[((size_t)(b * TT + t0 + t)) * IN + h * DHd + e]
                                           : (u16)0;
        }
    }
    __syncthreads();

    // ---- phase 3: acc += D @ V
#pragma unroll 1
    for (int ks = 0; ks < 2; ks++) {
        bf16x8 af = *(const bf16x8*)&sD[(mq * 16 + lrow) * 72 + ks * 32 + lquad * 8];
#pragma unroll
        for (int tt = 0; tt < 4; tt++) {
            bf16x8 bf = *(const bf16x8*)&sVt[(nh * 64 + tt * 16 + lrow) * 72 + ks * 32 + lquad * 8];
            acc[tt] = __builtin_amdgcn_mfma_f32_16x16x32_bf16(af, bf, acc[tt], 0, 0, 0);
        }
    }

    // ---- epilogue: h rows -> LDS, fused head-norm * hn * silu(z) -> bf16 out
    __syncthreads();   // all waves done reading sVt/sD before overlay
#pragma unroll
    for (int tt = 0; tt < 4; tt++) {
#pragma unroll
        for (int r = 0; r < 4; r++) {
            int t = mq * 16 + lquad * 4 + r;
            int e = nh * 64 + tt * 16 + lrow;
            hv[t * 132 + e] = acc[tt][r] * sInv[t];
        }
    }
    __syncthreads();
    {
        int t = tid >> 3, s = tid & 7;
        float vals[16];
        float sum = 0.f, sq = 0.f;
#pragma unroll
        for (int i = 0; i < 16; i++) {
            float v = hv[t * 132 + s * 16 + i];
            vals[i] = v; sum += v; sq += v * v;
        }
#pragma unroll
        for (int m = 1; m < 8; m <<= 1) { sum += __shfl_xor(sum, m); sq += __shfl_xor(sq, m); }
        float mu = sum / DHd, var = sq / DHd - mu * mu, inv2 = rsqrtf(var + EPSV);
        if (t < nvalid) {
            size_t bt = (size_t)(b * TT + t0 + t);
            const float* zp = up + bt * (2 * IN) + IN + h * DHd + s * 16;
            u16* op = out16 + bt * IN + h * DHd + s * 16;
#pragma unroll
            for (int i = 0; i < 16; i++) {
                float hnv = hn[h * DHd + s * 16 + i];
                op[i] = f2bf((vals[i] - mu) * inv2 * hnv * siluf(zp[i]));
            }
        }
    }
}

// ---------------------------------------------------------------- head: fused cls LN+ReLU + FC
__global__ __launch_bounds__(256) void fc_kernel(const float* __restrict__ hbuf,
                                                 const float* __restrict__ fcls,
                                                 const float* __restrict__ fclb,
                                                 const float* __restrict__ fw,
                                                 const float* __restrict__ fb,
                                                 float* __restrict__ out) {
    __shared__ float svc[Bsz][Dm];
    __shared__ float sred[4][256];
    int tid = threadIdx.x;
    int j0 = blockIdx.x * 64;
    {
        int r = tid >> 6, lane = tid & 63;
        const float* hrow = hbuf + ((size_t)r * TT + TT - 1) * Dm;
        float v[8];
        float sum = 0.f, sq = 0.f;
#pragma unroll
        for (int k = 0; k < 8; k++) {
            v[k] = hrow[lane + k * 64];
            sum += v[k]; sq += v[k] * v[k];
        }
#pragma unroll
        for (int o = 32; o > 0; o >>= 1) { sum += __shfl_xor(sum, o); sq += __shfl_xor(sq, o); }
        float mu = sum / Dm, var = sq / Dm - mu * mu, inv = rsqrtf(var + EPSV);
#pragma unroll
        for (int k = 0; k < 8; k++) {
            int e = lane + k * 64;
            svc[r][e] = fmaxf((v[k] - mu) * inv * fcls[e] + fclb[e], 0.f);
        }
    }
    __syncthreads();
    int j = j0 + (tid & 63);
    int chunk = tid >> 6;
    int kbase = chunk * 128;
    float a0 = 0.f, a1 = 0.f, a2 = 0.f, a3 = 0.f;
    if (j < NCc) {
        const float* fwp = fw + (size_t)kbase * NCc + j;
#pragma unroll 4
        for (int kk = 0; kk < 128; kk++) {
            float w = fwp[(size_t)kk * NCc];
            a0 += svc[0][kbase + kk] * w;
            a1 += svc[1][kbase + kk] * w;
            a2 += svc[2][kbase + kk] * w;
            a3 += svc[3][kbase + kk] * w;
        }
    }
    int jl = tid & 63;
    sred[chunk][jl * 4 + 0] = a0;
    sred[chunk][jl * 4 + 1] = a1;
    sred[chunk][jl * 4 + 2] = a2;
    sred[chunk][jl * 4 + 3] = a3;
    __syncthreads();
    if (tid < 64) {
        int jj = j0 + tid;
        if (jj < NCc) {
            float bias = fb[jj];
#pragma unroll
            for (int b = 0; b < Bsz; b++) {
                float v = sred[0][tid * 4 + b] + sred[1][tid * 4 + b]
                        + sred[2][tid * 4 + b] + sred[3][tid * 4 + b];
                out[b * NCc + jj] = v + bias;
            }
        }
    }
}

// ---------------------------------------------------------------- launch
extern "C" void kernel_launch(void* const* d_in, const int* in_sizes, int n_in,
                              void* d_out, int out_size, void* d_ws, size_t ws_size,
                              hipStream_t stream) {
    const float* x      = (const float*)d_in[0];
    const float* cls    = (const float*)d_in[1];
    const float* ln_s   = (const float*)d_in[2];
    const float* ln_b   = (const float*)d_in[3];
    const float* w_up   = (const float*)d_in[4];
    const float* b_up   = (const float*)d_in[5];
    const float* conv_k = (const float*)d_in[6];
    const float* conv_b = (const float*)d_in[7];
    const float* w_q    = (const float*)d_in[8];
    const float* w_k    = (const float*)d_in[9];
    const float* w_v    = (const float*)d_in[10];
    const float* w_ig   = (const float*)d_in[11];
    const float* b_ig   = (const float*)d_in[12];
    const float* w_fg   = (const float*)d_in[13];
    const float* b_fg   = (const float*)d_in[14];
    const float* hn_s   = (const float*)d_in[15];
    const float* w_down = (const float*)d_in[16];
    const float* b_down = (const float*)d_in[17];
    const float* fcls   = (const float*)d_in[18];
    const float* fclb   = (const float*)d_in[19];
    const float* fc_w   = (const float*)d_in[20];
    const float* fc_b   = (const float*)d_in[21];
    float* out = (float*)d_out;

    float* ws = (float*)d_ws;
    size_t off = 0;
    float* f_h  = ws + off; off += (size_t)ROWS * Dm;
    float* f_up = ws + off; off += (size_t)ROWS * 2 * IN;
    float* f_ip = ws + off; off += (size_t)ROWS * NHh;
    float* f_fp = ws + off; off += (size_t)ROWS * NHh;
    float* g_G  = ws + off; off += 32 * TT;
    float* g_M  = ws + off; off += 32 * TT;
    float* g_Mb = ws + off; off += 32 * NCH;
    float* g_De = ws + off; off += 32 * NCH;
    float* g_nP = ws + off; off += (size_t)NCH * 32 * DHd;
    float* g_wt = ws + off; off += 2 * 16 * IN;
    u16* g_P16 = (u16*)(ws + off); off += ((size_t)NCH * 32 * DHd * DHd + 1) / 2;
    u16* g_CB  = (u16*)(ws + off); off += ((size_t)NCH * 32 * DHd * DHd + 1) / 2;
    u16* g_Wt  = (u16*)(ws + off); off += (2 * WT_STRIDE + 1) / 2;
    // padded bf16 staging (MPAD rows; pad rows read as garbage, outputs guarded)
    u16* f_xn16 = (u16*)(ws + off); off += ((size_t)MPAD * Dm) / 2;
    u16* f_xc16 = (u16*)(ws + off); off += ((size_t)MPAD * IN) / 2;
    u16* f_xu16 = (u16*)(ws + off); off += ((size_t)MPAD * IN) / 2;
    u16* f_xg16 = (u16*)(ws + off); off += ((size_t)ROWS * IN + 1) / 2;
    u16* f_q16  = (u16*)(ws + off); off += ((size_t)ROWS * IN + 1) / 2;
    u16* f_k16  = (u16*)(ws + off); off += ((size_t)ROWS * IN + 1) / 2;
    u16* f_v16  = (u16*)(ws + off); off += ((size_t)ROWS * IN + 1) / 2;

    const float kscale = 0.08838834764831845f; // DH^-0.5
    const int MB = (ROWS + 127) / 128;         // 17
    const int MB64 = (ROWS + 63) / 64;         // 33

    w_transpose_kernel<<<dim3(1024, 12), 256, 0, stream>>>(
        w_up, w_q, w_k, w_v, w_down, w_ig, w_fg, g_Wt, g_wt);

    for (int blk = 0; blk < 2; blk++) {
        const float* p_ln_s = ln_s + blk * Dm;
        const float* p_ln_b = ln_b + blk * Dm;
        const float* p_bup  = b_up + (size_t)blk * 2 * IN;
        const float* p_ck   = conv_k + (size_t)blk * IN * KK;
        const float* p_cb   = conv_b + (size_t)blk * IN;
        const float* p_big  = b_ig + (size_t)blk * NHh;
        const float* p_bfg  = b_fg + (size_t)blk * NHh;
        const float* p_hns  = hn_s + (size_t)blk * NHh * DHd;
        const float* p_bd   = b_down + (size_t)blk * Dm;
        const u16*   p_wt   = g_Wt + (size_t)blk * WT_STRIDE;

        if (blk == 0)
            ln_kernel<true><<<ROWS, 256, 0, stream>>>(nullptr, x, cls, p_ln_s, p_ln_b,
                                                      f_h, f_xn16);
        else
            ln_kernel<false><<<ROWS, 256, 0, stream>>>(f_h, nullptr, nullptr, p_ln_s, p_ln_b,
                                                       nullptr, f_xn16);

        up_gl_kernel<<<dim3(2 * IN / 128, MB), 256, 0, stream>>>(
            f_xn16, p_wt + WT_UP, p_bup, f_up);

        convgates_kernel<<<ROWS, 256, 0, stream>>>(
            f_up, p_ck, p_cb, g_wt + blk * 16 * IN, p_big, p_bfg,
            f_xc16, f_xu16, f_ip, f_fp);

        qkv_gl_kernel<<<dim3(24, MB), 256, 0, stream>>>(
            f_xc16, f_xu16, p_wt, f_q16, f_k16, f_v16, kscale);

        // chunkwise-parallel mLSTM (gate scan fused into chunk_state wave 0)
        chunk_state_kernel<<<dim3(NCH, 32), 256, 0, stream>>>(
            f_k16, f_v16, f_ip, f_fp, g_G, g_M, g_Mb, g_De, g_P16, g_nP);
        chunk_combine_kernel<<<32 * 64, 256, 0, stream>>>(g_P16, g_CB, g_nP, g_De);
        chunk_out_kernel<<<dim3(NCH, 32), 512, 0, stream>>>(f_q16, f_k16, f_v16, g_G, g_M, g_Mb,
                                                            g_CB, g_nP, p_hns, f_up, f_xg16);

        gemm_mfma_kernel<64, 64><<<dim3(Dm / 64, MB64), 256, 0, stream>>>(
            f_xg16, IN, p_wt + WT_DN, IN, p_bd, f_h, Dm, f_h, Dm, ROWS, 1.f);
    }

    fc_kernel<<<(NCc + 63) / 64, 256, 0, stream>>>(f_h, fcls, fclb, fc_w, fc_b, out);
}

// Round 6
// 402.012 us; speedup vs baseline: 1.2963x; 1.0081x over previous
//
#include <hip/hip_runtime.h>

// ---------------------------------------------------------------- constants
#define EPSV 1e-5f
constexpr int Bsz = 4, T0 = 512, Dm = 512, NHh = 8, KK = 4;
constexpr int TT = 513;
constexpr int IN = 1024, DHd = 128, NCc = 1000;
constexpr int ROWS = Bsz * TT; // 2052
constexpr int MPAD = 2176;     // 17*128 padded staging rows for gload GEMMs
constexpr int NCH = 9;         // chunks of 64: 8*64 + 1 = 513

// bf16 k-major weight buffer offsets (u16 elements), per transformer block
constexpr size_t WT_UP = 0;                      // [2048][512]
constexpr size_t WT_Q  = WT_UP + 2048 * 512;     // [1024][1024]
constexpr size_t WT_K  = WT_Q + 1024 * 1024;
constexpr size_t WT_V  = WT_K + 1024 * 1024;
constexpr size_t WT_DN = WT_V + 1024 * 1024;     // [512][1024]
constexpr size_t WT_STRIDE = WT_DN + 512 * 1024; // 4,718,592 u16

typedef __attribute__((ext_vector_type(8))) short bf16x8;
typedef __attribute__((ext_vector_type(4))) float f32x4;
typedef __attribute__((ext_vector_type(4))) unsigned short ushort4v;
typedef __attribute__((ext_vector_type(8))) unsigned short ushort8v;
typedef unsigned short u16;

__device__ __forceinline__ float siluf(float x) { return x / (1.f + __expf(-x)); }
__device__ __forceinline__ u16 f2bf(float f) {
    unsigned int u = __float_as_uint(f);
    u = (u + 0x7FFFu + ((u >> 16) & 1u)) >> 16;
    return (u16)u;
}
__device__ __forceinline__ float bfu(u16 u) {
    return __uint_as_float(((unsigned int)u) << 16);
}
// async global->LDS, 16 bytes per lane; LDS dest is wave-uniform base + lane*16
__device__ __forceinline__ void gload16(const u16* g, u16* l) {
    __builtin_amdgcn_global_load_lds(
        (const __attribute__((address_space(1))) void*)g,
        (__attribute__((address_space(3))) void*)l, 16, 0, 0);
}

// ---------------------------------------------------------------- LayerNorm rows of D=512 -> bf16
// CAT=true: read from x/cls (concat fused), also materialize f_h.
template<bool CAT>
__global__ __launch_bounds__(256) void ln_kernel(const float* __restrict__ in,
                                                 const float* __restrict__ x,
                                                 const float* __restrict__ cls,
                                                 const float* __restrict__ s,
                                                 const float* __restrict__ bb,
                                                 float* __restrict__ hout,
                                                 u16* __restrict__ out16) {
    int row = blockIdx.x, tid = threadIdx.x;
    float x0, x1;
    if (CAT) {
        int b = row / TT, t = row - b * TT;
        const float* src = (t < T0) ? (x + ((size_t)(b * T0 + t)) * Dm) : cls;
        x0 = src[tid]; x1 = src[tid + 256];
        hout[(size_t)row * Dm + tid] = x0;
        hout[(size_t)row * Dm + tid + 256] = x1;
    } else {
        const float* r = in + (size_t)row * Dm;
        x0 = r[tid]; x1 = r[tid + 256];
    }
    __shared__ float s1[4], s2[4];
    float sum = x0 + x1, sq = x0 * x0 + x1 * x1;
#pragma unroll
    for (int o = 32; o > 0; o >>= 1) { sum += __shfl_xor(sum, o); sq += __shfl_xor(sq, o); }
    if ((tid & 63) == 0) { s1[tid >> 6] = sum; s2[tid >> 6] = sq; }
    __syncthreads();
    sum = s1[0] + s1[1] + s1[2] + s1[3];
    sq  = s2[0] + s2[1] + s2[2] + s2[3];
    float mu = sum / Dm, var = sq / Dm - mu * mu, inv = rsqrtf(var + EPSV);
    out16[(size_t)row * Dm + tid]       = f2bf((x0 - mu) * inv * s[tid] + bb[tid]);
    out16[(size_t)row * Dm + tid + 256] = f2bf((x1 - mu) * inv * s[tid + 256] + bb[tid + 256]);
}

// ---------------------------------------------------------------- weight transpose f32 KxN -> bf16 [N][K]
// y in [0,12): 0..9 = matmul weights, 10..11 = gate weight transpose for blk 0/1.
__global__ __launch_bounds__(256) void w_transpose_kernel(const float* __restrict__ wup,
        const float* __restrict__ wq, const float* __restrict__ wk,
        const float* __restrict__ wv, const float* __restrict__ wdn,
        const float* __restrict__ wig, const float* __restrict__ wfg,
        u16* __restrict__ wt, float* __restrict__ gwt) {
    int y = blockIdx.y;
    if (y >= 10) {
        int blk = y - 10;
        int idx = blockIdx.x * 256 + threadIdx.x;
        if (idx < 16 * IN) {
            int k = idx & 1023;
            int g = (idx >> 10) & 15;
            const float* w = (g < 8) ? (wig + (size_t)blk * IN * NHh)
                                     : (wfg + (size_t)blk * IN * NHh);
            gwt[(size_t)blk * 16 * IN + idx] = w[k * NHh + (g & 7)];
        }
        return;
    }
    int blk = y / 5, sel = y - blk * 5;
    int Kd, N; const float* src; size_t doff;
    if (sel == 0)      { Kd = 512;  N = 2048; src = wup + (size_t)blk * 512 * 2048; doff = WT_UP; }
    else if (sel == 1) { Kd = 1024; N = 1024; src = wq  + (size_t)blk * 1024 * 1024; doff = WT_Q; }
    else if (sel == 2) { Kd = 1024; N = 1024; src = wk  + (size_t)blk * 1024 * 1024; doff = WT_K; }
    else if (sel == 3) { Kd = 1024; N = 1024; src = wv  + (size_t)blk * 1024 * 1024; doff = WT_V; }
    else               { Kd = 1024; N = 512;  src = wdn + (size_t)blk * 1024 * 512;  doff = WT_DN; }
    u16* dst = wt + (size_t)blk * WT_STRIDE + doff;
    int ntx = N >> 5;
    int ntiles = ntx * (Kd >> 5);
    int ti = blockIdx.x;
    if (ti >= ntiles) return;
    int tk = ti / ntx, tn = ti - tk * ntx;
    __shared__ u16 s[32][33];
    int tx = threadIdx.x & 31, ty = threadIdx.x >> 5;
#pragma unroll
    for (int i = 0; i < 4; i++) {
        int k = tk * 32 + ty + i * 8;
        s[ty + i * 8][tx] = f2bf(src[(size_t)k * N + tn * 32 + tx]);
    }
    __syncthreads();
#pragma unroll
    for (int i = 0; i < 4; i++) {
        int n = tn * 32 + ty + i * 8;
        dst[(size_t)n * Kd + tk * 32 + tx] = s[tx][ty + i * 8];
    }
}

// ---------------------------------------------------------------- XCD-aware block swizzle (bijective; nwg % 8 == 0)
__device__ __forceinline__ void xcd_swz(int& bx, int& by) {
    int nx = gridDim.x;
    int nwg = nx * gridDim.y;
    int bid = by * nx + bx;
    int q = nwg >> 3;
    int sw = (bid & 7) * q + (bid >> 3);
    bx = sw % nx;
    by = sw / nx;
}

// ---------------------------------------------------------------- legacy MFMA GEMM (down-proj)
template<int BM, int BN>
__device__ __forceinline__ void gemm_tile_body(const u16* __restrict__ A, int lda,
                                               const u16* __restrict__ Wt, int Kd,
                                               const float* __restrict__ bias,
                                               const float* __restrict__ resid, int ldr,
                                               float* __restrict__ Cout, int ldc,
                                               int M, float scale, int m0, int n0,
                                               u16 (*As)[BM][40], u16 (*Bs)[BN][40]) {
    constexpr int MT = BM / 32;
    constexpr int NT = BN / 32;
    constexpr int ANV = BM / 64;
    constexpr int BNV = BN / 64;
    int tid = threadIdx.x;
    int wave = tid >> 6, lane = tid & 63;
    int wm = (wave >> 1) * (BM / 2), wn = (wave & 1) * (BN / 2);
    int lrow = lane & 15, lquad = lane >> 4;

    f32x4 acc[MT][NT];
#pragma unroll
    for (int i = 0; i < MT; i++)
#pragma unroll
        for (int j = 0; j < NT; j++)
#pragma unroll
            for (int r = 0; r < 4; r++) acc[i][j][r] = 0.f;

    int am, ak, bn, bk;
    if (BM == 128) { am = tid >> 1; ak = (tid & 1) * 16; }
    else           { am = tid >> 2; ak = (tid & 3) * 8; }
    if (BN == 128) { bn = tid & 127; bk = (tid >> 7) * 16; }
    else           { bn = tid & 63;  bk = (tid >> 6) * 8; }
    int gm = m0 + am;
    const u16* arow = A + (size_t)(gm < M ? gm : 0) * lda + ak;
    bool avalid = gm < M;
    const u16* wrow = Wt + (size_t)(n0 + bn) * Kd + bk;

    ushort8v areg[ANV];
    ushort8v breg[BNV];

    auto load_tile = [&](int k0) {
        if (avalid) {
#pragma unroll
            for (int i = 0; i < ANV; i++) areg[i] = *(const ushort8v*)(arow + k0 + i * 8);
        } else {
#pragma unroll
            for (int i = 0; i < ANV; i++) areg[i] = (ushort8v){0,0,0,0,0,0,0,0};
        }
#pragma unroll
        for (int i = 0; i < BNV; i++) breg[i] = *(const ushort8v*)(wrow + k0 + i * 8);
    };
    auto store_tile = [&](int buf) {
#pragma unroll
        for (int i = 0; i < ANV; i++)
            *(ushort8v*)&As[buf][am][ak + i * 8] = areg[i];
#pragma unroll
        for (int i = 0; i < BNV; i++)
            *(ushort8v*)&Bs[buf][bn][bk + i * 8] = breg[i];
    };

    load_tile(0);
    store_tile(0);
    __syncthreads();

    int nk = Kd >> 5;
#pragma unroll 1
    for (int it = 0; it < nk; it++) {
        int cur = it & 1;
        bool more = (it + 1 < nk);
        if (more) load_tile((it + 1) << 5);
        bf16x8 afr[MT], bfr[NT];
#pragma unroll
        for (int mt = 0; mt < MT; mt++)
            afr[mt] = *(const bf16x8*)&As[cur][wm + mt * 16 + lrow][lquad * 8];
#pragma unroll
        for (int nt = 0; nt < NT; nt++)
            bfr[nt] = *(const bf16x8*)&Bs[cur][wn + nt * 16 + lrow][lquad * 8];
#pragma unroll
        for (int mt = 0; mt < MT; mt++)
#pragma unroll
            for (int nt = 0; nt < NT; nt++)
                acc[mt][nt] = __builtin_amdgcn_mfma_f32_16x16x32_bf16(
                    afr[mt], bfr[nt], acc[mt][nt], 0, 0, 0);
        if (more) store_tile(cur ^ 1);
        __syncthreads();
    }

#pragma unroll
    for (int mt = 0; mt < MT; mt++) {
#pragma unroll
        for (int r = 0; r < 4; r++) {
            int gmr = m0 + wm + mt * 16 + lquad * 4 + r;
            if (gmr >= M) continue;
#pragma unroll
            for (int nt = 0; nt < NT; nt++) {
                int gn = n0 + wn + nt * 16 + lrow;
                float v = acc[mt][nt][r] * scale;
                if (bias) v += bias[gn];
                if (resid) v += resid[(size_t)gmr * ldr + gn];
                Cout[(size_t)gmr * ldc + gn] = v;
            }
        }
    }
}

template<int BM, int BN>
__global__ __launch_bounds__(256, 2) void gemm_mfma_kernel(const u16* __restrict__ A, int lda,
                                                           const u16* __restrict__ Wt, int Kd,
                                                           const float* __restrict__ bias,
                                                           const float* __restrict__ resid, int ldr,
                                                           float* __restrict__ Cout, int ldc,
                                                           int M, float scale) {
    __shared__ __align__(16) u16 As[2][BM][40];
    __shared__ __align__(16) u16 Bs[2][BN][40];
    int bx = blockIdx.x, by = blockIdx.y;
    xcd_swz(bx, by);
    gemm_tile_body<BM, BN>(A, lda, Wt, Kd, bias, resid, ldr, Cout, ldc, M, scale,
                           by * BM, bx * BN, As, Bs);
}

// ---------------------------------------------------------------- m97-style 128x128 gload GEMM
template<bool OUT16>
__device__ __forceinline__ void gemm128_body(const u16* __restrict__ A, int lda,
                                             const u16* __restrict__ Wt, int Kd,
                                             const float* __restrict__ bias,
                                             void* __restrict__ Cout, int ldc,
                                             int M, float scale, int m0, int n0,
                                             u16* As, u16* Bs) {
    int tid = threadIdx.x;
    int wave = tid >> 6, lane = tid & 63;
    int lrow = lane & 15, lquad = lane >> 4;
    int wm = (wave >> 1) * 64, wn = (wave & 1) * 64;

    const u16* ag0 = A + (size_t)(m0 + wave * 16 + (lane >> 2)) * lda + (lane & 3) * 8;
    const u16* ag1 = ag0 + (size_t)64 * lda;
    const u16* bg0 = Wt + (size_t)(n0 + wave * 16 + (lane >> 2)) * Kd + (lane & 3) * 8;
    const u16* bg1 = bg0 + (size_t)64 * Kd;

    auto stage = [&](int buf, int k0) {
        u16* a = As + buf * 4096 + wave * 512;
        u16* bb = Bs + buf * 4096 + wave * 512;
        gload16(ag0 + k0, a);
        gload16(ag1 + k0, a + 2048);
        gload16(bg0 + k0, bb);
        gload16(bg1 + k0, bb + 2048);
    };

    f32x4 acc[4][4];
#pragma unroll
    for (int i = 0; i < 4; i++)
#pragma unroll
        for (int j = 0; j < 4; j++)
#pragma unroll
            for (int r = 0; r < 4; r++) acc[i][j][r] = 0.f;

    int nk = Kd >> 5;
    stage(0, 0);
    __syncthreads();
#pragma unroll 1
    for (int it = 0; it < nk; it++) {
        int cur = it & 1;
        if (it + 1 < nk) stage(cur ^ 1, (it + 1) << 5);   // prefetch overlaps MFMA
        const u16* Ac = As + cur * 4096;
        const u16* Bc = Bs + cur * 4096;
        bf16x8 afr[4], bfr[4];
#pragma unroll
        for (int mt = 0; mt < 4; mt++)
            afr[mt] = *(const bf16x8*)&Ac[(wm + mt * 16 + lrow) * 32 + lquad * 8];
#pragma unroll
        for (int nt = 0; nt < 4; nt++)
            bfr[nt] = *(const bf16x8*)&Bc[(wn + nt * 16 + lrow) * 32 + lquad * 8];
#pragma unroll
        for (int mt = 0; mt < 4; mt++)
#pragma unroll
            for (int nt = 0; nt < 4; nt++)
                acc[mt][nt] = __builtin_amdgcn_mfma_f32_16x16x32_bf16(
                    afr[mt], bfr[nt], acc[mt][nt], 0, 0, 0);
        __syncthreads();
    }

#pragma unroll
    for (int mt = 0; mt < 4; mt++) {
#pragma unroll
        for (int r = 0; r < 4; r++) {
            int gmr = m0 + wm + mt * 16 + lquad * 4 + r;
            if (gmr >= M) continue;
#pragma unroll
            for (int nt = 0; nt < 4; nt++) {
                int gn = n0 + wn + nt * 16 + lrow;
                float v = acc[mt][nt][r] * scale;
                if (bias) v += bias[gn];
                if (OUT16) ((u16*)Cout)[(size_t)gmr * ldc + gn] = f2bf(v);
                else       ((float*)Cout)[(size_t)gmr * ldc + gn] = v;
            }
        }
    }
}

__global__ __launch_bounds__(256, 2) void up_gl_kernel(const u16* __restrict__ A,
        const u16* __restrict__ Wt, const float* __restrict__ bias, float* __restrict__ C) {
    __shared__ __align__(16) u16 As[2 * 4096];
    __shared__ __align__(16) u16 Bs[2 * 4096];
    int bx = blockIdx.x, by = blockIdx.y;
    xcd_swz(bx, by);
    gemm128_body<false>(A, Dm, Wt, Dm, bias, C, 2 * IN, ROWS, 1.f,
                        by * 128, bx * 128, As, Bs);
}

__global__ __launch_bounds__(256, 2) void qkv_gl_kernel(const u16* __restrict__ xc16,
                                                        const u16* __restrict__ xu16,
                                                        const u16* __restrict__ wtblk,
                                                        u16* __restrict__ fq,
                                                        u16* __restrict__ fk,
                                                        u16* __restrict__ fv,
                                                        float kscale) {
    __shared__ __align__(16) u16 As[2 * 4096];
    __shared__ __align__(16) u16 Bs[2 * 4096];
    int bx = blockIdx.x, by = blockIdx.y;
    xcd_swz(bx, by);
    int sel = bx >> 3, nx = bx & 7;
    const u16* A = (sel == 2) ? xu16 : xc16;
    const u16* Wt = wtblk + ((sel == 0) ? WT_Q : (sel == 1) ? WT_K : WT_V);
    u16* C = (sel == 0) ? fq : (sel == 1) ? fk : fv;
    float scale = (sel == 1) ? kscale : 1.f;
    gemm128_body<true>(A, IN, Wt, IN, nullptr, C, IN, ROWS, scale,
                       by * 128, nx * 128, As, Bs);
}

// ---------------------------------------------------------------- fused causal conv + SiLU + gate projections
__global__ __launch_bounds__(256) void convgates_kernel(const float* __restrict__ up,
        const float* __restrict__ ck, const float* __restrict__ cb,
        const float* __restrict__ wt, const float* __restrict__ big,
        const float* __restrict__ bfg,
        u16* __restrict__ xc16, u16* __restrict__ xu16,
        float* __restrict__ ip, float* __restrict__ fp) {
    int row = blockIdx.x, tid = threadIdx.x;
    int b = row / TT, t = row - b * TT;
    __shared__ float sx[IN];
    int c0 = tid * 4;
    float4 cur = *(const float4*)(up + (size_t)row * (2 * IN) + c0);
    float a0 = cb[c0 + 0] + cur.x * ck[(c0 + 0) * KK + 3];
    float a1 = cb[c0 + 1] + cur.y * ck[(c0 + 1) * KK + 3];
    float a2 = cb[c0 + 2] + cur.z * ck[(c0 + 2) * KK + 3];
    float a3 = cb[c0 + 3] + cur.w * ck[(c0 + 3) * KK + 3];
#pragma unroll
    for (int j = 0; j < KK - 1; j++) {
        int tt2 = t - (KK - 1) + j;
        if (tt2 >= 0) {
            float4 pv = *(const float4*)(up + ((size_t)(b * TT + tt2)) * (2 * IN) + c0);
            a0 += pv.x * ck[(c0 + 0) * KK + j];
            a1 += pv.y * ck[(c0 + 1) * KK + j];
            a2 += pv.z * ck[(c0 + 2) * KK + j];
            a3 += pv.w * ck[(c0 + 3) * KK + j];
        }
    }
    float s0 = siluf(a0), s1v = siluf(a1), s2v = siluf(a2), s3v = siluf(a3);
    *(float4*)&sx[c0] = make_float4(s0, s1v, s2v, s3v);
    ushort4v xc4 = {f2bf(s0), f2bf(s1v), f2bf(s2v), f2bf(s3v)};
    *(ushort4v*)&xc16[(size_t)row * IN + c0] = xc4;
    ushort4v xu4 = {f2bf(cur.x), f2bf(cur.y), f2bf(cur.z), f2bf(cur.w)};
    *(ushort4v*)&xu16[(size_t)row * IN + c0] = xu4;
    __syncthreads();

    int g = tid >> 4, l = tid & 15;
    const float* wrow = wt + g * IN;
    float acc = 0.f;
#pragma unroll
    for (int j = 0; j < 16; j++) {
        int k = j * 64 + l * 4;
        float4 w4 = *(const float4*)(wrow + k);
        float4 x4 = *(const float4*)&sx[k];
        acc += w4.x * x4.x + w4.y * x4.y + w4.z * x4.z + w4.w * x4.w;
    }
#pragma unroll
    for (int o = 8; o > 0; o >>= 1) acc += __shfl_down(acc, o, 16);
    if (l == 0) {
        if (g < 8) ip[(size_t)row * NHh + g] = acc + big[g];
        else       fp[(size_t)row * NHh + (g - 8)] = acc + bfg[g - 8];
    }
}

// ---------------------------------------------------------------- chunkwise mLSTM
// Kernel B1: fused gate scan + per-chunk local state via MFMA. P stored bf16 [e][d].
__global__ __launch_bounds__(256, 2) void chunk_state_kernel(const u16* __restrict__ kk,
        const u16* __restrict__ vv, const float* __restrict__ ip,
        const float* __restrict__ fp, float* __restrict__ gG, float* __restrict__ gM,
        float* __restrict__ gMb, float* __restrict__ gDec,
        u16* __restrict__ P16, float* __restrict__ nP) {
    int c = blockIdx.x, chain = blockIdx.y;
    int b = chain >> 3, h = chain & 7;
    int t0 = c * 64;
    int nvalid = min(64, TT - t0);
    __shared__ __align__(16) u16 sWv[128][72];   // [e][j] = w_j * V[j][e]
    __shared__ __align__(16) u16 sKt[128][72];   // [d][j] = K[j][d]
    __shared__ float sw[64];
    __shared__ float sGf[TT];
    __shared__ float sMbl[NCH];
    int tid = threadIdx.x;

    // ---- wave 0: full-chain gate scan
    if (tid < 64) {
        constexpr int PER = 9;
        int lane = tid;
        int tbase = lane * PER;
        float lcs[PER], gi[PER];
        float csum = 0.f;
#pragma unroll
        for (int i = 0; i < PER; i++) {
            int t = tbase + i;
            float fpv = 0.f, ipv = 0.f;
            if (t < TT) {
                size_t gidx = (size_t)(b * TT + t) * NHh + h;
                fpv = fp[gidx]; ipv = ip[gidx];
            }
            float flv = (fpv >= 0.f) ? -log1pf(__expf(-fpv)) : (fpv - log1pf(__expf(fpv)));
            if (t >= TT) flv = 0.f;
            csum += flv;
            lcs[i] = csum;
            gi[i] = ipv;
        }
        float ps = csum;
#pragma unroll
        for (int o = 1; o < 64; o <<= 1) {
            float v = __shfl_up(ps, o);
            if (lane >= o) ps += v;
        }
        float Fexcl = ps - csum;
        float G[PER];
        float cmax = -1e30f;
#pragma unroll
        for (int i = 0; i < PER; i++) {
            int t = tbase + i;
            G[i] = (t < TT) ? (gi[i] - (Fexcl + lcs[i])) : -1e30f;
            cmax = fmaxf(cmax, G[i]);
            lcs[i] = cmax;
        }
        float pm = cmax;
#pragma unroll
        for (int o = 1; o < 64; o <<= 1) {
            float v = __shfl_up(pm, o);
            if (lane >= o) pm = fmaxf(pm, v);
        }
        float Me = __shfl_up(pm, 1);
        if (lane == 0) Me = -1e30f;
#pragma unroll
        for (int i = 0; i < PER; i++) {
            int t = tbase + i;
            if (t < TT) {
                float Mt = fmaxf(0.f, fmaxf(Me, lcs[i]));
                sGf[t] = G[i];
                if (c == 0) { gG[chain * TT + t] = G[i]; gM[chain * TT + t] = Mt; }
                if (((t & 63) == 63) || t == TT - 1) sMbl[t >> 6] = Mt;
            }
        }
    }
    __syncthreads();
    if (c == 0 && tid < NCH) {
        float Mbv = sMbl[tid];
        float Mbp = (tid == 0) ? 0.f : sMbl[tid - 1];
        gMb[chain * NCH + tid] = Mbv;
        gDec[chain * NCH + tid] = __expf(Mbp - Mbv);
    }
    if (tid < 64) {
        float Mb = sMbl[c];
        sw[tid] = (tid < nvalid) ? __expf(sGf[t0 + tid] - Mb) : 0.f;
    }
    __syncthreads();

    // ---- stage transposed bf16 tiles
    {
        int j = tid >> 2, d0 = (tid & 3) * 32;
        bool val = j < nvalid;
        float wj = sw[j];
        size_t gb = ((size_t)(b * TT + t0 + j)) * IN + h * DHd + d0;
        ushort8v z8 = {0,0,0,0,0,0,0,0};
#pragma unroll
        for (int i = 0; i < 4; i++) {
            ushort8v k8 = val ? *(const ushort8v*)(kk + gb + i * 8) : z8;
            ushort8v v8 = val ? *(const ushort8v*)(vv + gb + i * 8) : z8;
#pragma unroll
            for (int e = 0; e < 8; e++) {
                int dd = d0 + i * 8 + e;
                int jc = j ^ (((dd >> 5) & 3) << 4);       // column swizzle
                sKt[dd][jc] = k8[e];
                sWv[dd][jc] = f2bf(bfu(v8[e]) * wj);
            }
        }
    }
    __syncthreads();

    int wave = tid >> 6, lane = tid & 63;
    int lrow = lane & 15, lquad = lane >> 4;
    int wm = (wave >> 1) * 64, wn = (wave & 1) * 64;
    f32x4 acc[4][4];
#pragma unroll
    for (int mt = 0; mt < 4; mt++)
#pragma unroll
        for (int nt = 0; nt < 4; nt++)
#pragma unroll
            for (int r = 0; r < 4; r++) acc[mt][nt][r] = 0.f;

#pragma unroll
    for (int ks = 0; ks < 2; ks++) {
        bf16x8 af[4], bfr[4];
#pragma unroll
        for (int mt = 0; mt < 4; mt++) {
            int r = wm + mt * 16 + lrow;
            int g = (ks * 4 + lquad) ^ (((r >> 5) & 3) << 1);
            af[mt] = *(const bf16x8*)&sWv[r][g * 8];
        }
#pragma unroll
        for (int nt = 0; nt < 4; nt++) {
            int r = wn + nt * 16 + lrow;
            int g = (ks * 4 + lquad) ^ (((r >> 5) & 3) << 1);
            bfr[nt] = *(const bf16x8*)&sKt[r][g * 8];
        }
#pragma unroll
        for (int mt = 0; mt < 4; mt++)
#pragma unroll
            for (int nt = 0; nt < 4; nt++)
                acc[mt][nt] = __builtin_amdgcn_mfma_f32_16x16x32_bf16(
                    af[mt], bfr[nt], acc[mt][nt], 0, 0, 0);
    }

    u16* Pbase = P16 + (((size_t)(c * 32 + chain)) << 14);
#pragma unroll
    for (int mt = 0; mt < 4; mt++)
#pragma unroll
        for (int r = 0; r < 4; r++) {
            int e = wm + mt * 16 + lquad * 4 + r;
#pragma unroll
            for (int nt = 0; nt < 4; nt++) {
                int d = wn + nt * 16 + lrow;
                Pbase[(size_t)e * 128 + d] = f2bf(acc[mt][nt][r]);
            }
        }

    {
        int d = tid >> 1, jh = (tid & 1) * 32;
        int swz = ((d >> 5) & 3) << 4;
        float an = 0.f;
#pragma unroll
        for (int j = 0; j < 32; j++) {
            int jj = jh + j;
            an += sw[jj] * bfu(sKt[d][jj ^ swz]);
        }
        an += __shfl_xor(an, 1);
        if ((tid & 1) == 0) nP[(size_t)(c * 32 + chain) * 128 + d] = an;
    }
}

// Kernel B2: exclusive combine over chunks (bf16 P -> bf16 CB); nP scan in seg 0.
__global__ __launch_bounds__(256) void chunk_combine_kernel(const u16* __restrict__ P16,
        u16* __restrict__ CB, float* __restrict__ nP, const float* __restrict__ gDec) {
    int chain = blockIdx.x >> 6;
    int seg = blockIdx.x & 63;
    int idx = seg * 256 + threadIdx.x;
    float run = 0.f;
    for (int c = 0; c < NCH; c++) {
        size_t a = (((size_t)(c * 32 + chain)) << 14) + idx;
        float tmp = bfu(P16[a]);
        CB[a] = f2bf(run);
        run = run * gDec[chain * NCH + c] + tmp;
    }
    if (seg == 0 && threadIdx.x < 128) {
        int d = threadIdx.x;
        float rn = 0.f;
        for (int c = 0; c < NCH; c++) {
            size_t a = (size_t)(c * 32 + chain) * 128 + d;
            float tmp = nP[a];
            nP[a] = rn;
            rn = rn * gDec[chain * NCH + c] + tmp;
        }
    }
}

// Kernel C: MFMA chunk outputs + fused per-head norm * hn_s * silu(z) -> bf16.
// 2 blocks/CU (LDS 2x63.7KB = 127KB): avoids the 2-round makespan at 288 blocks.
__global__ __launch_bounds__(512, 4) void chunk_out_kernel(const u16* __restrict__ qq,
        const u16* __restrict__ kk, const u16* __restrict__ vv,
        const float* __restrict__ gG, const float* __restrict__ gM,
        const float* __restrict__ gMb, const u16* __restrict__ CB,
        const float* __restrict__ nP, const float* __restrict__ hn,
        const float* __restrict__ up, u16* __restrict__ out16) {
    int c = blockIdx.x, chain = blockIdx.y;
    int b = chain >> 3, h = chain & 7;
    int t0 = c * 64;
    int nvalid = min(64, TT - t0);
    __shared__ __align__(16) u16 smem[30720];   // 61.4 KB arena
    __shared__ float sG[64], sM[64], sWr[64], sInv[64], sNb[128], sRS[2][64], sQn[64];
    u16* sQ  = smem;            // [64][136] bf16   (phases 0-2)
    u16* sCB = smem + 8704;     // [128][136] bf16  (phase 0)
    u16* sK  = smem + 8704;     // [64][136] bf16   (phase 1, overlays sCB)
    u16* sVt = smem;            // [128][72] bf16   (phase 3, overlays sQ)
    u16* sD  = smem + 26112;    // [64][72] bf16    (phase 1 write, 3 read)
    float* hv = (float*)smem;   // [64][132] f32    (epilogue, overlays sQ/sVt)
    int tid = threadIdx.x;
    int wave = tid >> 6, lane = tid & 63;
    int lrow = lane & 15, lquad = lane >> 4;
    int mq = wave >> 1, nh = wave & 1;

    float Mbprev = (c > 0) ? gMb[chain * NCH + c - 1] : 0.f;
    if (tid < 64) {
        bool val = tid < nvalid;
        sG[tid] = val ? gG[chain * TT + t0 + tid] : -1e30f;
        float Mv = val ? gM[chain * TT + t0 + tid] : 1e30f;
        sM[tid] = Mv;
        sWr[tid] = val ? __expf(Mbprev - Mv) : 0.f;
    }
    if (tid >= 128 && tid < 256) sNb[tid - 128] = nP[(size_t)(c * 32 + chain) * 128 + (tid - 128)];

    ushort8v z8 = {0,0,0,0,0,0,0,0};
    // ---- stage sQ [64][136]
    {
        int lr = tid >> 3, c0 = (tid & 7) * 16;
        bool val = lr < nvalid;
        size_t gb = ((size_t)(b * TT + t0 + lr)) * IN + h * DHd + c0;
#pragma unroll
        for (int i = 0; i < 2; i++)
            *(ushort8v*)&sQ[lr * 136 + c0 + i * 8] =
                val ? *(const ushort8v*)(qq + gb + i * 8) : z8;
    }
    // ---- stage sCB [128][136] from bf16 CB[e][d]
    {
        const u16* CBbase = CB + (((size_t)(c * 32 + chain)) << 14);
        int e = tid >> 2, d0 = (tid & 3) * 32;
#pragma unroll
        for (int i = 0; i < 4; i++)
            *(ushort8v*)&sCB[e * 136 + d0 + i * 8] =
                *(const ushort8v*)(CBbase + (size_t)e * 128 + d0 + i * 8);
    }
    __syncthreads();

    // ---- qn[t] = Q[t] . nb (8 threads per row, shfl-reduce) -> sQn
    {
        int t = tid >> 3, s = tid & 7;
        float qn = 0.f;
#pragma unroll
        for (int i = 0; i < 4; i++) {
            ushort4v q4 = *(const ushort4v*)&sQ[t * 136 + s * 16 + i * 4];
            float4 nb = *(const float4*)&sNb[s * 16 + i * 4];
            qn += bfu(q4.x) * nb.x + bfu(q4.y) * nb.y + bfu(q4.z) * nb.z + bfu(q4.w) * nb.w;
        }
#pragma unroll
        for (int m = 1; m < 8; m <<= 1) qn += __shfl_xor(qn, m);
        if (s == 0) sQn[t] = qn;
    }

    // ---- phase 0: inter = Q @ CB, C-layout acc; then scale by wr
    f32x4 acc[4];
#pragma unroll
    for (int tt = 0; tt < 4; tt++)
#pragma unroll
        for (int r = 0; r < 4; r++) acc[tt][r] = 0.f;
#pragma unroll 1
    for (int ks = 0; ks < 4; ks++) {
        bf16x8 af = *(const bf16x8*)&sQ[(mq * 16 + lrow) * 136 + ks * 32 + lquad * 8];
#pragma unroll
        for (int tt = 0; tt < 4; tt++) {
            bf16x8 bf = *(const bf16x8*)&sCB[(nh * 64 + tt * 16 + lrow) * 136 + ks * 32 + lquad * 8];
            acc[tt] = __builtin_amdgcn_mfma_f32_16x16x32_bf16(af, bf, acc[tt], 0, 0, 0);
        }
    }
#pragma unroll
    for (int tt = 0; tt < 4; tt++)
#pragma unroll
        for (int r = 0; r < 4; r++) acc[tt][r] *= sWr[mq * 16 + lquad * 4 + r];
    __syncthreads();

    // ---- stage sK (overlays sCB)
    {
        int lr = tid >> 3, c0 = (tid & 7) * 16;
        bool val = lr < nvalid;
        size_t gb = ((size_t)(b * TT + t0 + lr)) * IN + h * DHd + c0;
#pragma unroll
        for (int i = 0; i < 2; i++)
            *(ushort8v*)&sK[lr * 136 + c0 + i * 8] =
                val ? *(const ushort8v*)(kk + gb + i * 8) : z8;
    }
    __syncthreads();

    // ---- phase 1: S = Q K^T (2 n-tiles/wave), weights, sD bf16, in-reg rowsums
    {
        f32x4 accS[2];
#pragma unroll
        for (int tt = 0; tt < 2; tt++)
#pragma unroll
            for (int r = 0; r < 4; r++) accS[tt][r] = 0.f;
#pragma unroll 1
        for (int ks = 0; ks < 4; ks++) {
            bf16x8 af = *(const bf16x8*)&sQ[(mq * 16 + lrow) * 136 + ks * 32 + lquad * 8];
#pragma unroll
            for (int tt = 0; tt < 2; tt++) {
                bf16x8 bf = *(const bf16x8*)&sK[((nh * 2 + tt) * 16 + lrow) * 136 + ks * 32 + lquad * 8];
                accS[tt] = __builtin_amdgcn_mfma_f32_16x16x32_bf16(af, bf, accS[tt], 0, 0, 0);
            }
        }
        float rsum[4] = {0.f, 0.f, 0.f, 0.f};
#pragma unroll
        for (int tt = 0; tt < 2; tt++) {
            int j = (nh * 2 + tt) * 16 + lrow;
            float Gj = sG[j];
#pragma unroll
            for (int r = 0; r < 4; r++) {
                int t = mq * 16 + lquad * 4 + r;
                float w = (j <= t) ? __expf(Gj - sM[t]) : 0.f;
                float wD = accS[tt][r] * w;
                rsum[r] += wD;
                sD[t * 72 + j] = f2bf(wD);
            }
        }
#pragma unroll
        for (int r = 0; r < 4; r++) {
#pragma unroll
            for (int msk = 1; msk < 16; msk <<= 1) rsum[r] += __shfl_xor(rsum[r], msk);
        }
        if (lrow == 0) {
#pragma unroll
            for (int r = 0; r < 4; r++) sRS[nh][mq * 16 + lquad * 4 + r] = rsum[r];
        }
    }
    __syncthreads();

    // ---- phase 2 (lite) + stage sVt [128][72] = V^T bf16 (overlays sQ)
    if (tid < 64) {
        float den = sRS[0][tid] + sRS[1][tid] + sWr[tid] * sQn[tid];
        sInv[tid] = 1.f / fmaxf(fabsf(den), 1.f);
    }
    {
        int e = tid & 127, tg = (tid >> 7) * 16;
#pragma unroll 1
        for (int i = 0; i < 16; i++) {
            int t = tg + i;
            sVt[e * 72 + t] = (t < nvalid) ? vv[((size_t)(b * TT + t0 + t)) * IN + h * DHd + e]
                                           : (u16)0;
        }
    }
    __syncthreads();

    // ---- phase 3: acc += D @ V
#pragma unroll 1
    for (int ks = 0; ks < 2; ks++) {
        bf16x8 af = *(const bf16x8*)&sD[(mq * 16 + lrow) * 72 + ks * 32 + lquad * 8];
#pragma unroll
        for (int tt = 0; tt < 4; tt++) {
            bf16x8 bf = *(const bf16x8*)&sVt[(nh * 64 + tt * 16 + lrow) * 72 + ks * 32 + lquad * 8];
            acc[tt] = __builtin_amdgcn_mfma_f32_16x16x32_bf16(af, bf, acc[tt], 0, 0, 0);
        }
    }

    // ---- epilogue: h rows -> LDS, fused head-norm * hn * silu(z) -> bf16 out
    __syncthreads();   // all waves done reading sVt/sD before overlay
#pragma unroll
    for (int tt = 0; tt < 4; tt++) {
#pragma unroll
        for (int r = 0; r < 4; r++) {
            int t = mq * 16 + lquad * 4 + r;
            int e = nh * 64 + tt * 16 + lrow;
            hv[t * 132 + e] = acc[tt][r] * sInv[t];
        }
    }
    __syncthreads();
    {
        int t = tid >> 3, s = tid & 7;
        float vals[16];
        float sum = 0.f, sq = 0.f;
#pragma unroll
        for (int i = 0; i < 16; i++) {
            float v = hv[t * 132 + s * 16 + i];
            vals[i] = v; sum += v; sq += v * v;
        }
#pragma unroll
        for (int m = 1; m < 8; m <<= 1) { sum += __shfl_xor(sum, m); sq += __shfl_xor(sq, m); }
        float mu = sum / DHd, var = sq / DHd - mu * mu, inv2 = rsqrtf(var + EPSV);
        if (t < nvalid) {
            size_t bt = (size_t)(b * TT + t0 + t);
            const float* zp = up + bt * (2 * IN) + IN + h * DHd + s * 16;
            u16* op = out16 + bt * IN + h * DHd + s * 16;
#pragma unroll
            for (int i = 0; i < 16; i++) {
                float hnv = hn[h * DHd + s * 16 + i];
                op[i] = f2bf((vals[i] - mu) * inv2 * hnv * siluf(zp[i]));
            }
        }
    }
}

// ---------------------------------------------------------------- head: fused cls LN+ReLU + FC
__global__ __launch_bounds__(256) void fc_kernel(const float* __restrict__ hbuf,
                                                 const float* __restrict__ fcls,
                                                 const float* __restrict__ fclb,
                                                 const float* __restrict__ fw,
                                                 const float* __restrict__ fb,
                                                 float* __restrict__ out) {
    __shared__ float svc[Bsz][Dm];
    __shared__ float sred[4][256];
    int tid = threadIdx.x;
    int j0 = blockIdx.x * 64;
    {
        int r = tid >> 6, lane = tid & 63;
        const float* hrow = hbuf + ((size_t)r * TT + TT - 1) * Dm;
        float v[8];
        float sum = 0.f, sq = 0.f;
#pragma unroll
        for (int k = 0; k < 8; k++) {
            v[k] = hrow[lane + k * 64];
            sum += v[k]; sq += v[k] * v[k];
        }
#pragma unroll
        for (int o = 32; o > 0; o >>= 1) { sum += __shfl_xor(sum, o); sq += __shfl_xor(sq, o); }
        float mu = sum / Dm, var = sq / Dm - mu * mu, inv = rsqrtf(var + EPSV);
#pragma unroll
        for (int k = 0; k < 8; k++) {
            int e = lane + k * 64;
            svc[r][e] = fmaxf((v[k] - mu) * inv * fcls[e] + fclb[e], 0.f);
        }
    }
    __syncthreads();
    int j = j0 + (tid & 63);
    int chunk = tid >> 6;
    int kbase = chunk * 128;
    float a0 = 0.f, a1 = 0.f, a2 = 0.f, a3 = 0.f;
    if (j < NCc) {
        const float* fwp = fw + (size_t)kbase * NCc + j;
#pragma unroll 4
        for (int kk = 0; kk < 128; kk++) {
            float w = fwp[(size_t)kk * NCc];
            a0 += svc[0][kbase + kk] * w;
            a1 += svc[1][kbase + kk] * w;
            a2 += svc[2][kbase + kk] * w;
            a3 += svc[3][kbase + kk] * w;
        }
    }
    int jl = tid & 63;
    sred[chunk][jl * 4 + 0] = a0;
    sred[chunk][jl * 4 + 1] = a1;
    sred[chunk][jl * 4 + 2] = a2;
    sred[chunk][jl * 4 + 3] = a3;
    __syncthreads();
    if (tid < 64) {
        int jj = j0 + tid;
        if (jj < NCc) {
            float bias = fb[jj];
#pragma unroll
            for (int b = 0; b < Bsz; b++) {
                float v = sred[0][tid * 4 + b] + sred[1][tid * 4 + b]
                        + sred[2][tid * 4 + b] + sred[3][tid * 4 + b];
                out[b * NCc + jj] = v + bias;
            }
        }
    }
}

// ---------------------------------------------------------------- launch
extern "C" void kernel_launch(void* const* d_in, const int* in_sizes, int n_in,
                              void* d_out, int out_size, void* d_ws, size_t ws_size,
                              hipStream_t stream) {
    const float* x      = (const float*)d_in[0];
    const float* cls    = (const float*)d_in[1];
    const float* ln_s   = (const float*)d_in[2];
    const float* ln_b   = (const float*)d_in[3];
    const float* w_up   = (const float*)d_in[4];
    const float* b_up   = (const float*)d_in[5];
    const float* conv_k = (const float*)d_in[6];
    const float* conv_b = (const float*)d_in[7];
    const float* w_q    = (const float*)d_in[8];
    const float* w_k    = (const float*)d_in[9];
    const float* w_v    = (const float*)d_in[10];
    const float* w_ig   = (const float*)d_in[11];
    const float* b_ig   = (const float*)d_in[12];
    const float* w_fg   = (const float*)d_in[13];
    const float* b_fg   = (const float*)d_in[14];
    const float* hn_s   = (const float*)d_in[15];
    const float* w_down = (const float*)d_in[16];
    const float* b_down = (const float*)d_in[17];
    const float* fcls   = (const float*)d_in[18];
    const float* fclb   = (const float*)d_in[19];
    const float* fc_w   = (const float*)d_in[20];
    const float* fc_b   = (const float*)d_in[21];
    float* out = (float*)d_out;

    float* ws = (float*)d_ws;
    size_t off = 0;
    float* f_h  = ws + off; off += (size_t)ROWS * Dm;
    float* f_up = ws + off; off += (size_t)ROWS * 2 * IN;
    float* f_ip = ws + off; off += (size_t)ROWS * NHh;
    float* f_fp = ws + off; off += (size_t)ROWS * NHh;
    float* g_G  = ws + off; off += 32 * TT;
    float* g_M  = ws + off; off += 32 * TT;
    float* g_Mb = ws + off; off += 32 * NCH;
    float* g_De = ws + off; off += 32 * NCH;
    float* g_nP = ws + off; off += (size_t)NCH * 32 * DHd;
    float* g_wt = ws + off; off += 2 * 16 * IN;
    u16* g_P16 = (u16*)(ws + off); off += ((size_t)NCH * 32 * DHd * DHd + 1) / 2;
    u16* g_CB  = (u16*)(ws + off); off += ((size_t)NCH * 32 * DHd * DHd + 1) / 2;
    u16* g_Wt  = (u16*)(ws + off); off += (2 * WT_STRIDE + 1) / 2;
    // padded bf16 staging (MPAD rows; pad rows read as garbage, outputs guarded)
    u16* f_xn16 = (u16*)(ws + off); off += ((size_t)MPAD * Dm) / 2;
    u16* f_xc16 = (u16*)(ws + off); off += ((size_t)MPAD * IN) / 2;
    u16* f_xu16 = (u16*)(ws + off); off += ((size_t)MPAD * IN) / 2;
    u16* f_xg16 = (u16*)(ws + off); off += ((size_t)ROWS * IN + 1) / 2;
    u16* f_q16  = (u16*)(ws + off); off += ((size_t)ROWS * IN + 1) / 2;
    u16* f_k16  = (u16*)(ws + off); off += ((size_t)ROWS * IN + 1) / 2;
    u16* f_v16  = (u16*)(ws + off); off += ((size_t)ROWS * IN + 1) / 2;

    const float kscale = 0.08838834764831845f; // DH^-0.5
    const int MB = (ROWS + 127) / 128;         // 17
    const int MB64 = (ROWS + 63) / 64;         // 33

    w_transpose_kernel<<<dim3(1024, 12), 256, 0, stream>>>(
        w_up, w_q, w_k, w_v, w_down, w_ig, w_fg, g_Wt, g_wt);

    for (int blk = 0; blk < 2; blk++) {
        const float* p_ln_s = ln_s + blk * Dm;
        const float* p_ln_b = ln_b + blk * Dm;
        const float* p_bup  = b_up + (size_t)blk * 2 * IN;
        const float* p_ck   = conv_k + (size_t)blk * IN * KK;
        const float* p_cb   = conv_b + (size_t)blk * IN;
        const float* p_big  = b_ig + (size_t)blk * NHh;
        const float* p_bfg  = b_fg + (size_t)blk * NHh;
        const float* p_hns  = hn_s + (size_t)blk * NHh * DHd;
        const float* p_bd   = b_down + (size_t)blk * Dm;
        const u16*   p_wt   = g_Wt + (size_t)blk * WT_STRIDE;

        if (blk == 0)
            ln_kernel<true><<<ROWS, 256, 0, stream>>>(nullptr, x, cls, p_ln_s, p_ln_b,
                                                      f_h, f_xn16);
        else
            ln_kernel<false><<<ROWS, 256, 0, stream>>>(f_h, nullptr, nullptr, p_ln_s, p_ln_b,
                                                       nullptr, f_xn16);

        up_gl_kernel<<<dim3(2 * IN / 128, MB), 256, 0, stream>>>(
            f_xn16, p_wt + WT_UP, p_bup, f_up);

        convgates_kernel<<<ROWS, 256, 0, stream>>>(
            f_up, p_ck, p_cb, g_wt + blk * 16 * IN, p_big, p_bfg,
            f_xc16, f_xu16, f_ip, f_fp);

        qkv_gl_kernel<<<dim3(24, MB), 256, 0, stream>>>(
            f_xc16, f_xu16, p_wt, f_q16, f_k16, f_v16, kscale);

        // chunkwise-parallel mLSTM (gate scan fused into chunk_state wave 0)
        chunk_state_kernel<<<dim3(NCH, 32), 256, 0, stream>>>(
            f_k16, f_v16, f_ip, f_fp, g_G, g_M, g_Mb, g_De, g_P16, g_nP);
        chunk_combine_kernel<<<32 * 64, 256, 0, stream>>>(g_P16, g_CB, g_nP, g_De);
        chunk_out_kernel<<<dim3(NCH, 32), 512, 0, stream>>>(f_q16, f_k16, f_v16, g_G, g_M, g_Mb,
                                                            g_CB, g_nP, p_hns, f_up, f_xg16);

        gemm_mfma_kernel<64, 64><<<dim3(Dm / 64, MB64), 256, 0, stream>>>(
            f_xg16, IN, p_wt + WT_DN, IN, p_bd, f_h, Dm, f_h, Dm, ROWS, 1.f);
    }

    fc_kernel<<<(NCc + 63) / 64, 256, 0, stream>>>(f_h, fcls, fclb, fc_w, fc_b, out);
}